// Round 13
// baseline (824.410 us; speedup 1.0000x reference)
//
#include <hip/hip_runtime.h>

typedef unsigned long long ull;
typedef __bf16 bf16x8 __attribute__((ext_vector_type(8)));
typedef float f32x4 __attribute__((ext_vector_type(4)));

__device__ __forceinline__ float bf2f(unsigned short u) {
  union { unsigned int i; float f; } c; c.i = ((unsigned int)u) << 16; return c.f;
}
__device__ __forceinline__ unsigned short f2bf(float f) {
  union { float f; unsigned int i; } c; c.f = f;
  unsigned int u = c.i;
  u += 0x7fffu + ((u >> 16) & 1u);
  return (unsigned short)(u >> 16);
}

// ---- pack 4x [256,K] fp32 weights -> bf16 B-FRAGMENT-ORDER + bias concat --
// Layout: Wcat[colt][ks][rg][lane][kj]  (fragment index OUTSIDE lane, so
// each 16B load instruction in gemm is lane-contiguous: 64x16B = 1KB burst).
__global__ __launch_bounds__(256) void pack_weights(
    const float* __restrict__ wq, const float* __restrict__ wk,
    const float* __restrict__ wv, const float* __restrict__ ws,
    const float* __restrict__ bq, const float* __restrict__ bk,
    const float* __restrict__ bv, const float* __restrict__ bs,
    unsigned short* __restrict__ Wcat, float* __restrict__ bcat, int logK) {
  int idx = blockIdx.x * 256 + threadIdx.x;
  if (idx < 1024) {
    int rr = idx >> 8, cc = idx & 255;
    const float* bp = (rr == 0) ? bq : (rr == 1) ? bk : (rr == 2) ? bv : bs;
    bcat[idx] = bp[cc];
  }
  int K = 1 << logK;
  if (idx >= (1024 << logK)) return;
  int kj = idx & 7;
  int lane = (idx >> 3) & 63;
  int rg = (idx >> 9) & 3;
  int ksbits = logK - 5;
  int ks = (idx >> 11) & ((1 << ksbits) - 1);
  int colt = idx >> (11 + ksbits);
  int quad = lane >> 4, lm = lane & 15;
  int o = colt * 64 + rg * 16 + lm;
  int k = ks * 32 + quad * 8 + kj;
  int rr = o >> 8, oo = o & 255;
  const float* wp = (rr == 0) ? wq : (rr == 1) ? wk : (rr == 2) ? wv : ws;
  Wcat[idx] = f2bf(wp[oo * K + k]);
}

// ---- embedding gather -> A-FRAGMENT-ORDER xbf (K=512) ---------------------
// Layout: xbf[grp32][ks][half][lane][kj] (32-row groups; independent of
// gemm block size).
__global__ __launch_bounds__(256) void embed_gather(
    const int* __restrict__ x_idx, const float* __restrict__ emb,
    unsigned short* __restrict__ xbf, int total) {
  int idx = blockIdx.x * 256 + threadIdx.x;
  if (idx >= total) return;
  int n = idx >> 9, d = idx & 511, f = d >> 6, j = d & 63;
  int vi = x_idx[n * 8 + f];
  int n32 = n >> 5, lm = n & 15, half = (n >> 4) & 1;
  int ks = d >> 5, quad = (d >> 3) & 3, kj = d & 7;
  size_t a = (((size_t)(n32 * 16 + ks)) * 2 + half) * 512 + (quad * 16 + lm) * 8 + kj;
  xbf[a] = f2bf(emb[vi * 64 + j]);
}

// ---- CSR build ------------------------------------------------------------
__global__ __launch_bounds__(256) void count_dst(const int* __restrict__ dst,
                                                 int* __restrict__ counts, int E_) {
  int i = blockIdx.x * 256 + threadIdx.x;
  if (i < E_) atomicAdd(&counts[dst[i]], 1);
}

// NOTE: bases assigned by atomicAdd in arbitrary wave order -> row_start is
// a VALID CSR (disjoint, correct offsets) but NOT sorted by node index.
// No consumer may assume monotonicity (R11 bug).
__global__ __launch_bounds__(256) void alloc_rows(const int* __restrict__ counts,
                                                  int* __restrict__ row_start,
                                                  int* __restrict__ cursor,
                                                  int* __restrict__ total, int n) {
  int i = blockIdx.x * 256 + threadIdx.x;
  int lane = threadIdx.x & 63;
  int c = (i < n) ? counts[i] : 0;
  int incl = c;
#pragma unroll
  for (int off = 1; off < 64; off <<= 1) {
    int t = __shfl_up(incl, off, 64);
    if (lane >= off) incl += t;
  }
  int base = 0;
  if (lane == 63) base = atomicAdd(total, incl);
  base = __shfl(base, 63, 64);
  int st = base + incl - c;
  if (i < n) { row_start[i] = st; cursor[i] = st; }
}

// scatter edges into CSR order; materialize permuted src/dst ids and attrs
__global__ __launch_bounds__(256) void scatter_edges(
    const int* __restrict__ dst, const int* __restrict__ srcA,
    const float* __restrict__ eattr, int* __restrict__ cursor,
    int* __restrict__ srcs, int* __restrict__ dsts,
    float* __restrict__ ea_perm, int E_) {
  int i = blockIdx.x * 256 + threadIdx.x;
  if (i >= E_) return;
  int d = dst[i];
  int p = atomicAdd(&cursor[d], 1);
  srcs[p] = srcA[i];
  dsts[p] = d;
  const float* ea = eattr + (size_t)i * 6;
  float* eo = ea_perm + (size_t)p * 6;
  eo[0] = ea[0]; eo[1] = ea[1]; eo[2] = ea[2];
  eo[3] = ea[3]; eo[4] = ea[4]; eo[5] = ea[5];
}

// ---- fused QKVS GEMM, 64x64 per-wave tiles --------------------------------
// Block = 256 rows x 64 cols (4 waves stacked by row). Per wave per K-step:
// 4 A-frags + 4 B-frags (128 lines) feed 16 MFMA -> 8 lines/MFMA (was 12).
// All loads lane-contiguous 1KB bursts. XCD remap kept.
template <int K>
__global__ __launch_bounds__(256) void gemm_qkvs(
    const unsigned short* __restrict__ X, const unsigned short* __restrict__ W,
    const float* __restrict__ bcat,
    unsigned short* __restrict__ qout, unsigned short* __restrict__ kout,
    unsigned short* __restrict__ vout, float* __restrict__ sout,
    int Nn, int nrb) {
  const int l = blockIdx.x;
  const int xcd = l & 7, j = l >> 3;
  const int q = nrb >> 3, r = nrb & 7;
  const int cnt = q + (xcd < r ? 1 : 0);
  const int lrb = j >> 4, colt = j & 15;
  if (lrb >= cnt) return;
  const int m_blk = xcd * q + min(xcd, r) + lrb;   // 256-row block index

  const int wid = threadIdx.x >> 6;
  const int lane = threadIdx.x & 63;
  const int quad = lane >> 4, lm = lane & 15;
  const int m_base = m_blk * 256 + wid * 64;       // wave's 64 rows
  const int n_base = colt * 64;
  const int rg0 = m_blk * 8 + wid * 2;             // two 32-row groups
  const size_t a0base = (size_t)rg0 * (K >> 5) * 1024 + lane * 8;
  const size_t a2base = (size_t)(rg0 + 1) * (K >> 5) * 1024 + lane * 8;
  const size_t bbase  = (size_t)colt * (K >> 5) * 2048 + lane * 8;
  f32x4 acc[4][4] = {};
#pragma unroll 4
  for (int ks = 0; ks < (K >> 5); ks++) {
    const unsigned short* ap0 = X + a0base + (size_t)ks * 1024;
    const unsigned short* ap2 = X + a2base + (size_t)ks * 1024;
    const unsigned short* bp  = W + bbase  + (size_t)ks * 2048;
    bf16x8 a0 = *(const bf16x8*)(ap0);
    bf16x8 a1 = *(const bf16x8*)(ap0 + 512);
    bf16x8 a2 = *(const bf16x8*)(ap2);
    bf16x8 a3 = *(const bf16x8*)(ap2 + 512);
    bf16x8 b0 = *(const bf16x8*)(bp);
    bf16x8 b1 = *(const bf16x8*)(bp + 512);
    bf16x8 b2 = *(const bf16x8*)(bp + 1024);
    bf16x8 b3 = *(const bf16x8*)(bp + 1536);
    acc[0][0] = __builtin_amdgcn_mfma_f32_16x16x32_bf16(a0, b0, acc[0][0], 0, 0, 0);
    acc[0][1] = __builtin_amdgcn_mfma_f32_16x16x32_bf16(a0, b1, acc[0][1], 0, 0, 0);
    acc[0][2] = __builtin_amdgcn_mfma_f32_16x16x32_bf16(a0, b2, acc[0][2], 0, 0, 0);
    acc[0][3] = __builtin_amdgcn_mfma_f32_16x16x32_bf16(a0, b3, acc[0][3], 0, 0, 0);
    acc[1][0] = __builtin_amdgcn_mfma_f32_16x16x32_bf16(a1, b0, acc[1][0], 0, 0, 0);
    acc[1][1] = __builtin_amdgcn_mfma_f32_16x16x32_bf16(a1, b1, acc[1][1], 0, 0, 0);
    acc[1][2] = __builtin_amdgcn_mfma_f32_16x16x32_bf16(a1, b2, acc[1][2], 0, 0, 0);
    acc[1][3] = __builtin_amdgcn_mfma_f32_16x16x32_bf16(a1, b3, acc[1][3], 0, 0, 0);
    acc[2][0] = __builtin_amdgcn_mfma_f32_16x16x32_bf16(a2, b0, acc[2][0], 0, 0, 0);
    acc[2][1] = __builtin_amdgcn_mfma_f32_16x16x32_bf16(a2, b1, acc[2][1], 0, 0, 0);
    acc[2][2] = __builtin_amdgcn_mfma_f32_16x16x32_bf16(a2, b2, acc[2][2], 0, 0, 0);
    acc[2][3] = __builtin_amdgcn_mfma_f32_16x16x32_bf16(a2, b3, acc[2][3], 0, 0, 0);
    acc[3][0] = __builtin_amdgcn_mfma_f32_16x16x32_bf16(a3, b0, acc[3][0], 0, 0, 0);
    acc[3][1] = __builtin_amdgcn_mfma_f32_16x16x32_bf16(a3, b1, acc[3][1], 0, 0, 0);
    acc[3][2] = __builtin_amdgcn_mfma_f32_16x16x32_bf16(a3, b2, acc[3][2], 0, 0, 0);
    acc[3][3] = __builtin_amdgcn_mfma_f32_16x16x32_bf16(a3, b3, acc[3][3], 0, 0, 0);
  }
#pragma unroll
  for (int f = 0; f < 4; f++) {
#pragma unroll
    for (int r2 = 0; r2 < 4; r2++) {
      int row = m_base + f * 16 + quad * 4 + r2;
      if (row >= Nn) continue;
      size_t rb = (size_t)row * 256;
#pragma unroll
      for (int ni = 0; ni < 4; ni++) {
        int col = n_base + ni * 16 + lm;
        float v = acc[f][ni][r2] + bcat[col];
        int reg = col >> 8, c = col & 255;
        if (reg == 0)       qout[rb + c] = f2bf(v * 0.0625f);
        else if (reg == 1)  kout[rb + c] = f2bf(v);
        else if (reg == 2)  vout[rb + c] = f2bf(v);
        else                sout[rb + c] = v;
      }
    }
  }
}

// ---- node_prep: z[n] = We^T q[n] (6), c[n] = q[n].be -> zc[n][8] ----------
__global__ __launch_bounds__(256) void node_prep(
    const unsigned short* __restrict__ qv,
    const float* __restrict__ we, const float* __restrict__ be,
    float* __restrict__ zc, int Nn) {
  __shared__ float we_s[1536];
  __shared__ float be_s[256];
  for (int i = threadIdx.x; i < 1536; i += 256) we_s[i] = we[i];
  be_s[threadIdx.x] = be[threadIdx.x];
  __syncthreads();
  int wid = threadIdx.x >> 6, lane = threadIdx.x & 63;
  int n = blockIdx.x * 4 + wid;
  if (n >= Nn) return;
  int j0 = lane * 4;
  ull uq = *(const ull*)(qv + (size_t)n * 256 + j0);
  float q0 = bf2f((unsigned short)uq), q1 = bf2f((unsigned short)(uq >> 16));
  float q2 = bf2f((unsigned short)(uq >> 32)), q3 = bf2f((unsigned short)(uq >> 48));
  float part[7];
#pragma unroll
  for (int t = 0; t < 6; t++) {
    part[t] = we_s[(j0 + 0) * 6 + t] * q0 + we_s[(j0 + 1) * 6 + t] * q1
            + we_s[(j0 + 2) * 6 + t] * q2 + we_s[(j0 + 3) * 6 + t] * q3;
  }
  part[6] = be_s[j0] * q0 + be_s[j0 + 1] * q1 + be_s[j0 + 2] * q2 + be_s[j0 + 3] * q3;
#pragma unroll
  for (int off = 32; off > 0; off >>= 1) {
#pragma unroll
    for (int t = 0; t < 7; t++) part[t] += __shfl_xor(part[t], off, 64);
  }
  if (lane == 0) {
    float* zp = zc + (size_t)n * 8;
#pragma unroll
    for (int t = 0; t < 7; t++) zp[t] = part[t];
    zp[7] = 0.f;
  }
}

__device__ __forceinline__ float dot4(ull uq, ull uk) {
  return bf2f((unsigned short)uq) * bf2f((unsigned short)uk)
       + bf2f((unsigned short)(uq >> 16)) * bf2f((unsigned short)(uk >> 16))
       + bf2f((unsigned short)(uq >> 32)) * bf2f((unsigned short)(uk >> 32))
       + bf2f((unsigned short)(uq >> 48)) * bf2f((unsigned short)(uk >> 48));
}

#define SEL8_I(a, t) ((t)==0?(a)[0]:(t)==1?(a)[1]:(t)==2?(a)[2]:(t)==3?(a)[3]:(t)==4?(a)[4]:(t)==5?(a)[5]:(t)==6?(a)[6]:(a)[7])

// ---- P1: edge-parallel logits = q[dst].k[src] + z[dst].u + c[dst] ---------
__global__ __launch_bounds__(256) void edge_logits(
    const int* __restrict__ srcs, const int* __restrict__ dsts,
    const float* __restrict__ ea_perm,
    const unsigned short* __restrict__ qv, const unsigned short* __restrict__ kv,
    const float* __restrict__ zc, int E_, float* __restrict__ logits) {
  int wid = threadIdx.x >> 6, lane = threadIdx.x & 63;
  int p0 = (blockIdx.x * 4 + wid) * 8;
  if (p0 >= E_) return;
  int j0 = lane * 4;
  int s_[8], d_[8];
  if (p0 + 8 <= E_) {
    int4 sa = *(const int4*)(srcs + p0), sb = *(const int4*)(srcs + p0 + 4);
    int4 da = *(const int4*)(dsts + p0), db = *(const int4*)(dsts + p0 + 4);
    s_[0] = sa.x; s_[1] = sa.y; s_[2] = sa.z; s_[3] = sa.w;
    s_[4] = sb.x; s_[5] = sb.y; s_[6] = sb.z; s_[7] = sb.w;
    d_[0] = da.x; d_[1] = da.y; d_[2] = da.z; d_[3] = da.w;
    d_[4] = db.x; d_[5] = db.y; d_[6] = db.z; d_[7] = db.w;
  } else {
#pragma unroll
    for (int t = 0; t < 8; t++) {
      int pp = min(p0 + t, E_ - 1);
      s_[t] = srcs[pp]; d_[t] = dsts[pp];
    }
  }
  ull uk[8], uq[8];
#pragma unroll
  for (int t = 0; t < 8; t++) uk[t] = *(const ull*)(kv + (size_t)s_[t] * 256 + j0);
#pragma unroll
  for (int t = 0; t < 8; t++) uq[t] = *(const ull*)(qv + (size_t)d_[t] * 256 + j0);
  float pv[8];
#pragma unroll
  for (int t = 0; t < 8; t++) pv[t] = dot4(uq[t], uk[t]);
#pragma unroll
  for (int off = 32; off > 0; off >>= 1) {
#pragma unroll
    for (int t = 0; t < 8; t++) pv[t] += __shfl_xor(pv[t], off, 64);
  }
  // lane t (t<8) finalizes edge t: + z[dst].u + c[dst]
  if (lane < 8 && p0 + lane < E_) {
    int t = lane;
    int dd = SEL8_I(d_, t);
    float pvt = SEL8_I(pv, t);
    const float* zp = zc + (size_t)dd * 8;
    const float* u = ea_perm + (size_t)(p0 + t) * 6;
    float zd = zp[0] * u[0] + zp[1] * u[1] + zp[2] * u[2]
             + zp[3] * u[3] + zp[4] * u[4] + zp[5] * u[5] + zp[6];
    logits[p0 + t] = pvt + zd;
  }
}

// ---- P2: per-node softmax; overwrite logits with weights; also ubar -------
__global__ __launch_bounds__(256) void node_softmax(
    const int* __restrict__ row_start, const int* __restrict__ counts,
    const float* __restrict__ ea_perm,
    float* __restrict__ logits, float* __restrict__ ubar, int Nn) {
  int wid = threadIdx.x >> 6, lane = threadIdx.x & 63;
  int n = blockIdx.x * 4 + wid;
  if (n >= Nn) return;
  int beg = row_start[n], cnt = counts[n];
  if (cnt == 0) return;
  float lm = -INFINITY;
  for (int b = lane; b < cnt; b += 64) lm = fmaxf(lm, logits[beg + b]);
#pragma unroll
  for (int off = 32; off > 0; off >>= 1) lm = fmaxf(lm, __shfl_xor(lm, off, 64));
  float se = 0.f;
  for (int b = lane; b < cnt; b += 64) se += __expf(logits[beg + b] - lm);
#pragma unroll
  for (int off = 32; off > 0; off >>= 1) se += __shfl_xor(se, off, 64);
  float inv = 1.f / se;
  float u0 = 0.f, u1 = 0.f, u2 = 0.f, u3 = 0.f, u4 = 0.f, u5 = 0.f;
  for (int b = lane; b < cnt; b += 64) {
    int p = beg + b;
    float w = __expf(logits[p] - lm) * inv;
    logits[p] = w;
    const float* up = ea_perm + (size_t)p * 6;
    u0 += w * up[0]; u1 += w * up[1]; u2 += w * up[2];
    u3 += w * up[3]; u4 += w * up[4]; u5 += w * up[5];
  }
#pragma unroll
  for (int off = 32; off > 0; off >>= 1) {
    u0 += __shfl_xor(u0, off, 64); u1 += __shfl_xor(u1, off, 64);
    u2 += __shfl_xor(u2, off, 64); u3 += __shfl_xor(u3, off, 64);
    u4 += __shfl_xor(u4, off, 64); u5 += __shfl_xor(u5, off, 64);
  }
  if (lane == 0) {
    float* up = ubar + (size_t)n * 8;
    up[0] = u0; up[1] = u1; up[2] = u2; up[3] = u3; up[4] = u4; up[5] = u5;
  }
}

// ---- P3: ATOMIC-FREE node-owned weighted v-sum ----------------------------
// Wave w owns nodes [8w, 8w+8) by NODE INDEX (no sortedness assumption on
// row_start). Each cnt>0 node gets exactly ONE direct float4 store.
#define NPW 8
__global__ __launch_bounds__(256) void edge_seg(
    const int* __restrict__ srcs, const int* __restrict__ row_start,
    const int* __restrict__ counts, const float* __restrict__ wgt,
    const unsigned short* __restrict__ vv, int Nn,
    float* __restrict__ h_acc) {
  int wave = blockIdx.x * 4 + (threadIdx.x >> 6);
  int lane = threadIdx.x & 63;
  int n0 = wave * NPW;
  if (n0 >= Nn) return;
  int n1 = min(n0 + NPW, Nn);
  int j0 = lane * 4;
  for (int n = n0; n < n1; n++) {
    int cnt = counts[n];
    if (cnt == 0) continue;
    int beg = row_start[n];
    float a0 = 0.f, a1 = 0.f, a2 = 0.f, a3 = 0.f;
    for (int i0 = 0; i0 < cnt; i0 += 8) {
      int m = cnt - i0; if (m > 8) m = 8;
      float w8[8];
      int s8[8];
#pragma unroll
      for (int t = 0; t < 8; t++) {
        int pp = beg + i0 + ((t < m) ? t : (m - 1));
        w8[t] = (t < m) ? wgt[pp] : 0.f;
        s8[t] = srcs[pp];
      }
      ull uv[8];
#pragma unroll
      for (int t = 0; t < 8; t++)
        uv[t] = *(const ull*)(vv + (size_t)s8[t] * 256 + j0);
#pragma unroll
      for (int t = 0; t < 8; t++) {
        float ww = w8[t];
        a0 += ww * bf2f((unsigned short)uv[t]);
        a1 += ww * bf2f((unsigned short)(uv[t] >> 16));
        a2 += ww * bf2f((unsigned short)(uv[t] >> 32));
        a3 += ww * bf2f((unsigned short)(uv[t] >> 48));
      }
    }
    float4 o; o.x = a0; o.y = a1; o.z = a2; o.w = a3;
    *(float4*)(h_acc + (size_t)n * 256 + j0) = o;
  }
}

// ---- P4: streaming finalize: h = relu(h_acc + We*ubar + be*[cnt>0] + skip)
// cnt==0 rows of h_acc are NEVER read (stale garbage allowed -> no memset).
// mode 0: write h bf16 to hout in A-FRAGMENT-ORDER (K=256, gemm2 input).
// mode 1: write h fp32 IN PLACE into h_acc (pool_reduce consumes).
__global__ __launch_bounds__(256) void node_finalize(
    float* __restrict__ h_acc, const float* __restrict__ ubar,
    const int* __restrict__ counts, const float* __restrict__ skipv,
    const float* __restrict__ we, const float* __restrict__ be,
    int Nn, int mode,
    unsigned short* __restrict__ hout) {
  __shared__ float we_s[1536];
  __shared__ float be_s[256];
  for (int i = threadIdx.x; i < 1536; i += 256) we_s[i] = we[i];
  be_s[threadIdx.x] = be[threadIdx.x];
  __syncthreads();
  int wid = threadIdx.x >> 6, lane = threadIdx.x & 63;
  int n = blockIdx.x * 4 + wid;
  if (n >= Nn) return;
  int j0 = lane * 4;
  int cnt = counts[n];
  float4 skv = *(const float4*)(skipv + (size_t)n * 256 + j0);
  float4 ha = make_float4(0.f, 0.f, 0.f, 0.f);
  float e[4] = {0.f, 0.f, 0.f, 0.f};
  if (cnt > 0) {
    ha = *(const float4*)(h_acc + (size_t)n * 256 + j0);
    float4 u0 = *(const float4*)(ubar + (size_t)n * 8);
    float4 u1 = *(const float4*)(ubar + (size_t)n * 8 + 4);
#pragma unroll
    for (int r = 0; r < 4; r++) {
      int d = j0 + r;
      e[r] = be_s[d]
           + we_s[d * 6 + 0] * u0.x + we_s[d * 6 + 1] * u0.y + we_s[d * 6 + 2] * u0.z
           + we_s[d * 6 + 3] * u0.w + we_s[d * 6 + 4] * u1.x + we_s[d * 6 + 5] * u1.y;
    }
  }
  float h0 = fmaxf(ha.x + e[0] + skv.x, 0.f);
  float h1 = fmaxf(ha.y + e[1] + skv.y, 0.f);
  float h2 = fmaxf(ha.z + e[2] + skv.z, 0.f);
  float h3 = fmaxf(ha.w + e[3] + skv.w, 0.f);
  if (mode == 0) {
    ull hv = (ull)f2bf(h0) | ((ull)f2bf(h1) << 16) | ((ull)f2bf(h2) << 32) | ((ull)f2bf(h3) << 48);
    // A-frag-order address (K=256)
    int n32 = n >> 5, lmn = n & 15, halfn = (n >> 4) & 1;
    int ks = lane >> 3, quadc = (lane >> 1) & 3, kjc = (lane & 1) * 4;
    size_t a = (((size_t)(n32 * 8 + ks)) * 2 + halfn) * 512 + (quadc * 16 + lmn) * 8 + kjc;
    *(ull*)(hout + a) = hv;
  } else {
    float4 o; o.x = h0; o.y = h1; o.z = h2; o.w = h3;
    *(float4*)(h_acc + (size_t)n * 256 + j0) = o;
  }
}

// ---- P5: segmented pooling over sorted batch (contiguous node ranges) -----
__global__ __launch_bounds__(256) void pool_reduce(
    const float* __restrict__ hfin, const int* __restrict__ batch, int Nn,
    float* __restrict__ gap, unsigned int* __restrict__ gmp) {
  int g = blockIdx.x, s = blockIdx.y, t = threadIdx.x;
  __shared__ int st_s, en_s;
  if (t == 0) {
    int lo = 0, hi = Nn;
    while (lo < hi) { int mid = (lo + hi) >> 1; if (batch[mid] < g) lo = mid + 1; else hi = mid; }
    st_s = lo;
    lo = 0; hi = Nn;
    while (lo < hi) { int mid = (lo + hi) >> 1; if (batch[mid] < g + 1) lo = mid + 1; else hi = mid; }
    en_s = lo;
  }
  __syncthreads();
  int st = st_s, en = en_s;
  int len = en - st;
  if (len <= 0) return;
  int nsplit = gridDim.y;
  int chunk = (len + nsplit - 1) / nsplit;
  int a = st + s * chunk;
  int b = min(a + chunk, en);
  if (a >= b) return;
  float acc = 0.f, mx = 0.f;  // h >= 0 (relu)
  for (int n = a; n < b; n++) {
    float v = hfin[(size_t)n * 256 + t];
    acc += v;
    mx = fmaxf(mx, v);
  }
  atomicAdd(&gap[(size_t)g * 256 + t], acc);
  atomicMax(&gmp[(size_t)g * 256 + t], __float_as_uint(mx));
}

// ---- per-graph pooling finalize + 3-layer MLP + sigmoid -------------------
__global__ __launch_bounds__(256) void pool_mlp(
    const float* __restrict__ gap, const unsigned int* __restrict__ gmp,
    const int* __restrict__ batch, int Nn,
    const float* __restrict__ w1, const float* __restrict__ b1,
    const float* __restrict__ w2, const float* __restrict__ b2,
    const float* __restrict__ w3, const float* __restrict__ b3,
    float* __restrict__ out) {
  int g = blockIdx.x, t = threadIdx.x;
  __shared__ float r[512];
  __shared__ float o1[256];
  __shared__ float o2[128];
  __shared__ float red[256];
  __shared__ int cnt_s;
  if (t == 0) {
    int lo = 0, hi = Nn;
    while (lo < hi) { int mid = (lo + hi) >> 1; if (batch[mid] < g) lo = mid + 1; else hi = mid; }
    int st = lo;
    lo = 0; hi = Nn;
    while (lo < hi) { int mid = (lo + hi) >> 1; if (batch[mid] < g + 1) lo = mid + 1; else hi = mid; }
    cnt_s = lo - st;
  }
  __syncthreads();
  float inv = 1.f / fmaxf((float)cnt_s, 1.f);
  r[t] = gap[(size_t)g * 256 + t] * inv;
  r[256 + t] = __uint_as_float(gmp[(size_t)g * 256 + t]);
  __syncthreads();
  {
    float a = b1[t];
    const float* wr = w1 + (size_t)t * 512;
    for (int k = 0; k < 512; k++) a += wr[k] * r[k];
    o1[t] = fmaxf(a, 0.f);
  }
  __syncthreads();
  if (t < 128) {
    float a = b2[t];
    const float* wr = w2 + (size_t)t * 256;
    for (int k = 0; k < 256; k++) a += wr[k] * o1[k];
    o2[t] = fmaxf(a, 0.f);
  }
  __syncthreads();
  red[t] = (t < 128) ? w3[t] * o2[t] : 0.f;
  __syncthreads();
  for (int s = 128; s > 0; s >>= 1) {
    if (t < s) red[t] += red[t + s];
    __syncthreads();
  }
  if (t == 0) out[g] = 1.f / (1.f + expf(-(red[0] + b3[0])));
}

// ---------------------------------------------------------------------------
extern "C" void kernel_launch(void* const* d_in, const int* in_sizes, int n_in,
                              void* d_out, int out_size, void* d_ws, size_t ws_size,
                              hipStream_t stream) {
  const int* x_idx      = (const int*)d_in[0];
  const int* edge_index = (const int*)d_in[1];
  const float* eattr    = (const float*)d_in[2];
  const int* batch      = (const int*)d_in[3];
  const float* emb      = (const float*)d_in[4];
  const float* c1_wq = (const float*)d_in[5],  *c1_bq = (const float*)d_in[6];
  const float* c1_wk = (const float*)d_in[7],  *c1_bk = (const float*)d_in[8];
  const float* c1_wv = (const float*)d_in[9],  *c1_bv = (const float*)d_in[10];
  const float* c1_we = (const float*)d_in[11], *c1_be = (const float*)d_in[12];
  const float* c1_ws = (const float*)d_in[13], *c1_bs = (const float*)d_in[14];
  const float* c2_wq = (const float*)d_in[15], *c2_bq = (const float*)d_in[16];
  const float* c2_wk = (const float*)d_in[17], *c2_bk = (const float*)d_in[18];
  const float* c2_wv = (const float*)d_in[19], *c2_bv = (const float*)d_in[20];
  const float* c2_we = (const float*)d_in[21], *c2_be = (const float*)d_in[22];
  const float* c2_ws = (const float*)d_in[23], *c2_bs = (const float*)d_in[24];
  const float* w1 = (const float*)d_in[25], *b1 = (const float*)d_in[26];
  const float* w2 = (const float*)d_in[27], *b2 = (const float*)d_in[28];
  const float* w3 = (const float*)d_in[29], *b3 = (const float*)d_in[30];

  const int Nn = in_sizes[3];        // 50000
  const int Ee = in_sizes[1] / 2;    // 300000
  const int nrb = (Nn + 255) / 256;  // 196 x 256-row blocks (gemm + padding)

  char* ws = (char*)d_ws;
  size_t off = 0;
  auto alloc = [&](size_t bytes) -> void* {
    void* p = ws + off;
    off += (bytes + 255) & ~(size_t)255;
    return p;
  };
  // xbf/h1bf padded to whole 256-row blocks (frag-order reads go to nrb*256)
  unsigned short* xbf   = (unsigned short*)alloc((size_t)nrb * 256 * 512 * 2);
  unsigned short* qbf   = (unsigned short*)alloc((size_t)Nn * 256 * 2);
  unsigned short* kbf   = (unsigned short*)alloc((size_t)Nn * 256 * 2);
  unsigned short* vbf   = (unsigned short*)alloc((size_t)Nn * 256 * 2);
  float*          skipf = (float*)alloc((size_t)Nn * 256 * 4);
  unsigned short* h1bf  = (unsigned short*)alloc((size_t)nrb * 256 * 256 * 2);
  unsigned short* Wcat1 = (unsigned short*)alloc((size_t)1024 * 512 * 2);
  float*          bcat1 = (float*)alloc(1024 * 4);
  unsigned short* Wcat2 = (unsigned short*)alloc((size_t)1024 * 256 * 2);
  float*          bcat2 = (float*)alloc(1024 * 4);
  int*            counts    = (int*)alloc((size_t)Nn * 4);
  int*            row_start = (int*)alloc((size_t)Nn * 4);
  int*            cursor    = (int*)alloc((size_t)Nn * 4);
  int*            srcs      = (int*)alloc((size_t)Ee * 4);
  int*            dsts      = (int*)alloc((size_t)Ee * 4);
  float*          ea_perm   = (float*)alloc((size_t)Ee * 6 * 4);
  float*          logits    = (float*)alloc((size_t)Ee * 4);   // becomes weights
  float*          zc        = (float*)alloc((size_t)Nn * 8 * 4);
  float*          ubar      = (float*)alloc((size_t)Nn * 8 * 4);
  int*            total     = (int*)alloc(256);
  float*          gap       = (float*)alloc((size_t)64 * 256 * 4);
  unsigned int*   gmp       = (unsigned int*)alloc((size_t)64 * 256 * 4);
  // h_acc (50k x 256 fp32 = 51.2 MB) ALIASES xbf (51.4 MB padded): xbf is
  // dead after gemm1; h_acc first touched after it. ~221 MB total.
  float* h_acc = (float*)xbf;

  const int* srcA = edge_index;
  const int* dstA = edge_index + Ee;

  hipMemsetAsync(counts, 0, (size_t)Nn * 4, stream);
  hipMemsetAsync(total, 0, 4, stream);
  hipMemsetAsync(gap, 0, (size_t)64 * 256 * 4, stream);
  hipMemsetAsync(gmp, 0, (size_t)64 * 256 * 4, stream);

  pack_weights<<<(1024 * 512 + 255) / 256, 256, 0, stream>>>(
      c1_wq, c1_wk, c1_wv, c1_ws, c1_bq, c1_bk, c1_bv, c1_bs, Wcat1, bcat1, 9);
  pack_weights<<<(1024 * 256 + 255) / 256, 256, 0, stream>>>(
      c2_wq, c2_wk, c2_wv, c2_ws, c2_bq, c2_bk, c2_bv, c2_bs, Wcat2, bcat2, 8);
  embed_gather<<<((Nn * 512) + 255) / 256, 256, 0, stream>>>(x_idx, emb, xbf, Nn * 512);
  count_dst<<<(Ee + 255) / 256, 256, 0, stream>>>(dstA, counts, Ee);
  alloc_rows<<<(Nn + 255) / 256, 256, 0, stream>>>(counts, row_start, cursor, total, Nn);
  scatter_edges<<<(Ee + 255) / 256, 256, 0, stream>>>(dstA, srcA, eattr, cursor,
                                                      srcs, dsts, ea_perm, Ee);

  // XCD-aware gemm grid: 8 XCD groups x max-row-blocks-per-XCD x 16 col-tiles
  const int rbmax = nrb / 8 + ((nrb % 8) ? 1 : 0);
  const int ggrid = 8 * rbmax * 16;
  const int egrid = (Ee + 31) / 32;
  const int sgrid = (Nn + NPW * 4 - 1) / (NPW * 4);  // node-owned edge_seg
  const int ngrid = (Nn + 3) / 4;

  // layer 1
  gemm_qkvs<512><<<ggrid, 256, 0, stream>>>(xbf, Wcat1, bcat1, qbf, kbf, vbf,
                                            skipf, Nn, nrb);
  node_prep<<<ngrid, 256, 0, stream>>>(qbf, c1_we, c1_be, zc, Nn);
  edge_logits<<<egrid, 256, 0, stream>>>(srcs, dsts, ea_perm, qbf, kbf, zc, Ee, logits);
  node_softmax<<<ngrid, 256, 0, stream>>>(row_start, counts, ea_perm, logits, ubar, Nn);
  edge_seg<<<sgrid, 256, 0, stream>>>(srcs, row_start, counts, logits, vbf,
                                      Nn, h_acc);
  node_finalize<<<ngrid, 256, 0, stream>>>(h_acc, ubar, counts, skipf,
                                           c1_we, c1_be, Nn, 0, h1bf);

  // layer 2
  gemm_qkvs<256><<<ggrid, 256, 0, stream>>>(h1bf, Wcat2, bcat2, qbf, kbf, vbf,
                                            skipf, Nn, nrb);
  node_prep<<<ngrid, 256, 0, stream>>>(qbf, c2_we, c2_be, zc, Nn);
  edge_logits<<<egrid, 256, 0, stream>>>(srcs, dsts, ea_perm, qbf, kbf, zc, Ee, logits);
  node_softmax<<<ngrid, 256, 0, stream>>>(row_start, counts, ea_perm, logits, ubar, Nn);
  edge_seg<<<sgrid, 256, 0, stream>>>(srcs, row_start, counts, logits, vbf,
                                      Nn, h_acc);
  node_finalize<<<ngrid, 256, 0, stream>>>(h_acc, ubar, counts, skipf,
                                           c2_we, c2_be, Nn, 1, nullptr);

  // segmented pooling (batch sorted -> contiguous ranges), then MLP
  dim3 pg(64, 16);
  pool_reduce<<<pg, 256, 0, stream>>>(h_acc, batch, Nn, gap, gmp);
  pool_mlp<<<64, 256, 0, stream>>>(gap, gmp, batch, Nn, w1, b1, w2, b2, w3, b3,
                                   (float*)d_out);
}

// Round 14
// 768.780 us; speedup vs baseline: 1.0724x; 1.0724x over previous
//
#include <hip/hip_runtime.h>

typedef unsigned long long ull;
typedef __bf16 bf16x8 __attribute__((ext_vector_type(8)));
typedef float f32x4 __attribute__((ext_vector_type(4)));

__device__ __forceinline__ float bf2f(unsigned short u) {
  union { unsigned int i; float f; } c; c.i = ((unsigned int)u) << 16; return c.f;
}
__device__ __forceinline__ unsigned short f2bf(float f) {
  union { float f; unsigned int i; } c; c.f = f;
  unsigned int u = c.i;
  u += 0x7fffu + ((u >> 16) & 1u);
  return (unsigned short)(u >> 16);
}

// ---- pack 4x [256,K] fp32 weights -> bf16 B-FRAGMENT-ORDER + bias concat --
// Layout: Wcat[colt][ks][rg][lane][kj]  (fragment index OUTSIDE lane, so
// each 16B load instruction in gemm is lane-contiguous: 64x16B = 1KB burst).
__global__ __launch_bounds__(256) void pack_weights(
    const float* __restrict__ wq, const float* __restrict__ wk,
    const float* __restrict__ wv, const float* __restrict__ ws,
    const float* __restrict__ bq, const float* __restrict__ bk,
    const float* __restrict__ bv, const float* __restrict__ bs,
    unsigned short* __restrict__ Wcat, float* __restrict__ bcat, int logK) {
  int idx = blockIdx.x * 256 + threadIdx.x;
  if (idx < 1024) {
    int rr = idx >> 8, cc = idx & 255;
    const float* bp = (rr == 0) ? bq : (rr == 1) ? bk : (rr == 2) ? bv : bs;
    bcat[idx] = bp[cc];
  }
  int K = 1 << logK;
  if (idx >= (1024 << logK)) return;
  int kj = idx & 7;
  int lane = (idx >> 3) & 63;
  int rg = (idx >> 9) & 3;
  int ksbits = logK - 5;
  int ks = (idx >> 11) & ((1 << ksbits) - 1);
  int colt = idx >> (11 + ksbits);
  int quad = lane >> 4, lm = lane & 15;
  int o = colt * 64 + rg * 16 + lm;
  int k = ks * 32 + quad * 8 + kj;
  int rr = o >> 8, oo = o & 255;
  const float* wp = (rr == 0) ? wq : (rr == 1) ? wk : (rr == 2) ? wv : ws;
  Wcat[idx] = f2bf(wp[oo * K + k]);
}

// ---- embedding gather -> A-FRAGMENT-ORDER xbf (K=512) ---------------------
// Layout: xbf[grp32][ks][half][lane][kj] (32-row groups).
__global__ __launch_bounds__(256) void embed_gather(
    const int* __restrict__ x_idx, const float* __restrict__ emb,
    unsigned short* __restrict__ xbf, int total) {
  int idx = blockIdx.x * 256 + threadIdx.x;
  if (idx >= total) return;
  int n = idx >> 9, d = idx & 511, f = d >> 6, j = d & 63;
  int vi = x_idx[n * 8 + f];
  int n32 = n >> 5, lm = n & 15, half = (n >> 4) & 1;
  int ks = d >> 5, quad = (d >> 3) & 3, kj = d & 7;
  size_t a = (((size_t)(n32 * 16 + ks)) * 2 + half) * 512 + (quad * 16 + lm) * 8 + kj;
  xbf[a] = f2bf(emb[vi * 64 + j]);
}

// ---- CSR build ------------------------------------------------------------
__global__ __launch_bounds__(256) void count_dst(const int* __restrict__ dst,
                                                 int* __restrict__ counts, int E_) {
  int i = blockIdx.x * 256 + threadIdx.x;
  if (i < E_) atomicAdd(&counts[dst[i]], 1);
}

// NOTE: bases assigned by atomicAdd in arbitrary wave order -> row_start is
// a VALID CSR (disjoint, correct offsets) but NOT sorted by node index.
// No consumer may assume monotonicity (R11 bug).
__global__ __launch_bounds__(256) void alloc_rows(const int* __restrict__ counts,
                                                  int* __restrict__ row_start,
                                                  int* __restrict__ cursor,
                                                  int* __restrict__ total, int n) {
  int i = blockIdx.x * 256 + threadIdx.x;
  int lane = threadIdx.x & 63;
  int c = (i < n) ? counts[i] : 0;
  int incl = c;
#pragma unroll
  for (int off = 1; off < 64; off <<= 1) {
    int t = __shfl_up(incl, off, 64);
    if (lane >= off) incl += t;
  }
  int base = 0;
  if (lane == 63) base = atomicAdd(total, incl);
  base = __shfl(base, 63, 64);
  int st = base + incl - c;
  if (i < n) { row_start[i] = st; cursor[i] = st; }
}

// scatter edges into CSR order; materialize permuted src/dst ids and attrs
__global__ __launch_bounds__(256) void scatter_edges(
    const int* __restrict__ dst, const int* __restrict__ srcA,
    const float* __restrict__ eattr, int* __restrict__ cursor,
    int* __restrict__ srcs, int* __restrict__ dsts,
    float* __restrict__ ea_perm, int E_) {
  int i = blockIdx.x * 256 + threadIdx.x;
  if (i >= E_) return;
  int d = dst[i];
  int p = atomicAdd(&cursor[d], 1);
  srcs[p] = srcA[i];
  dsts[p] = d;
  const float* ea = eattr + (size_t)i * 6;
  float* eo = ea_perm + (size_t)p * 6;
  eo[0] = ea[0]; eo[1] = ea[1]; eo[2] = ea[2];
  eo[3] = ea[3]; eo[4] = ea[4]; eo[5] = ea[5];
}

// ---- fused QKVS GEMM (R12-proven config: 128-row blocks, 32x64/wave) ------
// Every A/B load instruction is a lane-contiguous 1KB burst. XCD remap kept.
template <int K>
__global__ __launch_bounds__(256) void gemm_qkvs(
    const unsigned short* __restrict__ X, const unsigned short* __restrict__ W,
    const float* __restrict__ bcat,
    unsigned short* __restrict__ qout, unsigned short* __restrict__ kout,
    unsigned short* __restrict__ vout, float* __restrict__ sout,
    int Nn, int nrb) {
  const int l = blockIdx.x;
  const int xcd = l & 7, j = l >> 3;
  const int q = nrb >> 3, r = nrb & 7;
  const int cnt = q + (xcd < r ? 1 : 0);
  const int lrb = j >> 4, colt = j & 15;
  if (lrb >= cnt) return;
  const int m_blk = xcd * q + min(xcd, r) + lrb;

  const int wid = threadIdx.x >> 6;
  const int lane = threadIdx.x & 63;
  const int quad = lane >> 4, lm = lane & 15;
  const int m_base = m_blk * 128 + wid * 32;
  const int n_base = colt * 64;
  const size_t abase = (size_t)(m_blk * 4 + wid) * (K >> 5) * 1024 + lane * 8;
  const size_t bbase = (size_t)colt * (K >> 5) * 2048 + lane * 8;
  f32x4 acc[2][4] = {};
#pragma unroll 4
  for (int ks = 0; ks < (K >> 5); ks++) {
    const unsigned short* ap = X + abase + (size_t)ks * 1024;
    const unsigned short* bp = W + bbase + (size_t)ks * 2048;
    bf16x8 a0 = *(const bf16x8*)(ap);
    bf16x8 a1 = *(const bf16x8*)(ap + 512);
    bf16x8 b0 = *(const bf16x8*)(bp);
    bf16x8 b1 = *(const bf16x8*)(bp + 512);
    bf16x8 b2 = *(const bf16x8*)(bp + 1024);
    bf16x8 b3 = *(const bf16x8*)(bp + 1536);
    acc[0][0] = __builtin_amdgcn_mfma_f32_16x16x32_bf16(a0, b0, acc[0][0], 0, 0, 0);
    acc[0][1] = __builtin_amdgcn_mfma_f32_16x16x32_bf16(a0, b1, acc[0][1], 0, 0, 0);
    acc[0][2] = __builtin_amdgcn_mfma_f32_16x16x32_bf16(a0, b2, acc[0][2], 0, 0, 0);
    acc[0][3] = __builtin_amdgcn_mfma_f32_16x16x32_bf16(a0, b3, acc[0][3], 0, 0, 0);
    acc[1][0] = __builtin_amdgcn_mfma_f32_16x16x32_bf16(a1, b0, acc[1][0], 0, 0, 0);
    acc[1][1] = __builtin_amdgcn_mfma_f32_16x16x32_bf16(a1, b1, acc[1][1], 0, 0, 0);
    acc[1][2] = __builtin_amdgcn_mfma_f32_16x16x32_bf16(a1, b2, acc[1][2], 0, 0, 0);
    acc[1][3] = __builtin_amdgcn_mfma_f32_16x16x32_bf16(a1, b3, acc[1][3], 0, 0, 0);
  }
#pragma unroll
  for (int mi = 0; mi < 2; mi++) {
#pragma unroll
    for (int r2 = 0; r2 < 4; r2++) {
      int row = m_base + mi * 16 + quad * 4 + r2;
      if (row >= Nn) continue;
      size_t rb = (size_t)row * 256;
#pragma unroll
      for (int ni = 0; ni < 4; ni++) {
        int col = n_base + ni * 16 + lm;
        float v = acc[mi][ni][r2] + bcat[col];
        int reg = col >> 8, c = col & 255;
        if (reg == 0)       qout[rb + c] = f2bf(v * 0.0625f);
        else if (reg == 1)  kout[rb + c] = f2bf(v);
        else if (reg == 2)  vout[rb + c] = f2bf(v);
        else                sout[rb + c] = v;
      }
    }
  }
}

// ---- node_prep: z[n] = We^T q[n] (6), c[n] = q[n].be -> zc[n][8] ----------
__global__ __launch_bounds__(256) void node_prep(
    const unsigned short* __restrict__ qv,
    const float* __restrict__ we, const float* __restrict__ be,
    float* __restrict__ zc, int Nn) {
  __shared__ float we_s[1536];
  __shared__ float be_s[256];
  for (int i = threadIdx.x; i < 1536; i += 256) we_s[i] = we[i];
  be_s[threadIdx.x] = be[threadIdx.x];
  __syncthreads();
  int wid = threadIdx.x >> 6, lane = threadIdx.x & 63;
  int n = blockIdx.x * 4 + wid;
  if (n >= Nn) return;
  int j0 = lane * 4;
  ull uq = *(const ull*)(qv + (size_t)n * 256 + j0);
  float q0 = bf2f((unsigned short)uq), q1 = bf2f((unsigned short)(uq >> 16));
  float q2 = bf2f((unsigned short)(uq >> 32)), q3 = bf2f((unsigned short)(uq >> 48));
  float part[7];
#pragma unroll
  for (int t = 0; t < 6; t++) {
    part[t] = we_s[(j0 + 0) * 6 + t] * q0 + we_s[(j0 + 1) * 6 + t] * q1
            + we_s[(j0 + 2) * 6 + t] * q2 + we_s[(j0 + 3) * 6 + t] * q3;
  }
  part[6] = be_s[j0] * q0 + be_s[j0 + 1] * q1 + be_s[j0 + 2] * q2 + be_s[j0 + 3] * q3;
#pragma unroll
  for (int off = 32; off > 0; off >>= 1) {
#pragma unroll
    for (int t = 0; t < 7; t++) part[t] += __shfl_xor(part[t], off, 64);
  }
  if (lane == 0) {
    float* zp = zc + (size_t)n * 8;
#pragma unroll
    for (int t = 0; t < 7; t++) zp[t] = part[t];
    zp[7] = 0.f;
  }
}

__device__ __forceinline__ float dot4(ull uq, ull uk) {
  return bf2f((unsigned short)uq) * bf2f((unsigned short)uk)
       + bf2f((unsigned short)(uq >> 16)) * bf2f((unsigned short)(uk >> 16))
       + bf2f((unsigned short)(uq >> 32)) * bf2f((unsigned short)(uk >> 32))
       + bf2f((unsigned short)(uq >> 48)) * bf2f((unsigned short)(uk >> 48));
}

#define SEL8_I(a, t) ((t)==0?(a)[0]:(t)==1?(a)[1]:(t)==2?(a)[2]:(t)==3?(a)[3]:(t)==4?(a)[4]:(t)==5?(a)[5]:(t)==6?(a)[6]:(a)[7])

// ---- P1: edge-parallel logits = q[dst].k[src] + z[dst].u + c[dst] ---------
__global__ __launch_bounds__(256) void edge_logits(
    const int* __restrict__ srcs, const int* __restrict__ dsts,
    const float* __restrict__ ea_perm,
    const unsigned short* __restrict__ qv, const unsigned short* __restrict__ kv,
    const float* __restrict__ zc, int E_, float* __restrict__ logits) {
  int wid = threadIdx.x >> 6, lane = threadIdx.x & 63;
  int p0 = (blockIdx.x * 4 + wid) * 8;
  if (p0 >= E_) return;
  int j0 = lane * 4;
  int s_[8], d_[8];
  if (p0 + 8 <= E_) {
    int4 sa = *(const int4*)(srcs + p0), sb = *(const int4*)(srcs + p0 + 4);
    int4 da = *(const int4*)(dsts + p0), db = *(const int4*)(dsts + p0 + 4);
    s_[0] = sa.x; s_[1] = sa.y; s_[2] = sa.z; s_[3] = sa.w;
    s_[4] = sb.x; s_[5] = sb.y; s_[6] = sb.z; s_[7] = sb.w;
    d_[0] = da.x; d_[1] = da.y; d_[2] = da.z; d_[3] = da.w;
    d_[4] = db.x; d_[5] = db.y; d_[6] = db.z; d_[7] = db.w;
  } else {
#pragma unroll
    for (int t = 0; t < 8; t++) {
      int pp = min(p0 + t, E_ - 1);
      s_[t] = srcs[pp]; d_[t] = dsts[pp];
    }
  }
  ull uk[8], uq[8];
#pragma unroll
  for (int t = 0; t < 8; t++) uk[t] = *(const ull*)(kv + (size_t)s_[t] * 256 + j0);
#pragma unroll
  for (int t = 0; t < 8; t++) uq[t] = *(const ull*)(qv + (size_t)d_[t] * 256 + j0);
  float pv[8];
#pragma unroll
  for (int t = 0; t < 8; t++) pv[t] = dot4(uq[t], uk[t]);
#pragma unroll
  for (int off = 32; off > 0; off >>= 1) {
#pragma unroll
    for (int t = 0; t < 8; t++) pv[t] += __shfl_xor(pv[t], off, 64);
  }
  // lane t (t<8) finalizes edge t: + z[dst].u + c[dst]
  if (lane < 8 && p0 + lane < E_) {
    int t = lane;
    int dd = SEL8_I(d_, t);
    float pvt = SEL8_I(pv, t);
    const float* zp = zc + (size_t)dd * 8;
    const float* u = ea_perm + (size_t)(p0 + t) * 6;
    float zd = zp[0] * u[0] + zp[1] * u[1] + zp[2] * u[2]
             + zp[3] * u[3] + zp[4] * u[4] + zp[5] * u[5] + zp[6];
    logits[p0 + t] = pvt + zd;
  }
}

// ---- P2: per-node softmax; overwrite logits with weights; also ubar -------
__global__ __launch_bounds__(256) void node_softmax(
    const int* __restrict__ row_start, const int* __restrict__ counts,
    const float* __restrict__ ea_perm,
    float* __restrict__ logits, float* __restrict__ ubar, int Nn) {
  int wid = threadIdx.x >> 6, lane = threadIdx.x & 63;
  int n = blockIdx.x * 4 + wid;
  if (n >= Nn) return;
  int beg = row_start[n], cnt = counts[n];
  if (cnt == 0) return;
  float lm = -INFINITY;
  for (int b = lane; b < cnt; b += 64) lm = fmaxf(lm, logits[beg + b]);
#pragma unroll
  for (int off = 32; off > 0; off >>= 1) lm = fmaxf(lm, __shfl_xor(lm, off, 64));
  float se = 0.f;
  for (int b = lane; b < cnt; b += 64) se += __expf(logits[beg + b] - lm);
#pragma unroll
  for (int off = 32; off > 0; off >>= 1) se += __shfl_xor(se, off, 64);
  float inv = 1.f / se;
  float u0 = 0.f, u1 = 0.f, u2 = 0.f, u3 = 0.f, u4 = 0.f, u5 = 0.f;
  for (int b = lane; b < cnt; b += 64) {
    int p = beg + b;
    float w = __expf(logits[p] - lm) * inv;
    logits[p] = w;
    const float* up = ea_perm + (size_t)p * 6;
    u0 += w * up[0]; u1 += w * up[1]; u2 += w * up[2];
    u3 += w * up[3]; u4 += w * up[4]; u5 += w * up[5];
  }
#pragma unroll
  for (int off = 32; off > 0; off >>= 1) {
    u0 += __shfl_xor(u0, off, 64); u1 += __shfl_xor(u1, off, 64);
    u2 += __shfl_xor(u2, off, 64); u3 += __shfl_xor(u3, off, 64);
    u4 += __shfl_xor(u4, off, 64); u5 += __shfl_xor(u5, off, 64);
  }
  if (lane == 0) {
    float* up = ubar + (size_t)n * 8;
    up[0] = u0; up[1] = u1; up[2] = u2; up[3] = u3; up[4] = u4; up[5] = u5;
  }
}

// ---- P3: FUSED atomic-free aggregation + finalize -------------------------
// Wave w owns nodes [8w, 8w+8) by NODE INDEX. For each owned node: weighted
// v-gather-sum in registers, then IN-REGISTER epilogue
// h = relu(sum + We*ubar + be*[cnt>0] + skip) and ONE direct store.
// Eliminates the h_acc write+read round-trip and the node_finalize kernel.
// mode 0: write h bf16 in A-FRAGMENT-ORDER (gemm2 input).
// mode 1: write h fp32 to h_acc (pool_reduce input). All n<Nn written.
#define NPW 8
__global__ __launch_bounds__(256) void edge_agg_final(
    const int* __restrict__ srcs, const int* __restrict__ row_start,
    const int* __restrict__ counts, const float* __restrict__ wgt,
    const unsigned short* __restrict__ vv,
    const float* __restrict__ ubar, const float* __restrict__ skipv,
    const float* __restrict__ we, const float* __restrict__ be,
    int Nn, int mode,
    unsigned short* __restrict__ hout, float* __restrict__ h_acc) {
  __shared__ float we_s[1536];
  __shared__ float be_s[256];
  for (int i = threadIdx.x; i < 1536; i += 256) we_s[i] = we[i];
  be_s[threadIdx.x] = be[threadIdx.x];
  __syncthreads();
  int wave = blockIdx.x * 4 + (threadIdx.x >> 6);
  int lane = threadIdx.x & 63;
  int n0 = wave * NPW;
  if (n0 >= Nn) return;
  int n1 = min(n0 + NPW, Nn);
  int j0 = lane * 4;
  for (int n = n0; n < n1; n++) {
    int cnt = counts[n];
    float a0 = 0.f, a1 = 0.f, a2 = 0.f, a3 = 0.f;
    float e[4] = {0.f, 0.f, 0.f, 0.f};
    if (cnt > 0) {
      int beg = row_start[n];
      for (int i0 = 0; i0 < cnt; i0 += 8) {
        int m = cnt - i0; if (m > 8) m = 8;
        float w8[8];
        int s8[8];
#pragma unroll
        for (int t = 0; t < 8; t++) {
          int pp = beg + i0 + ((t < m) ? t : (m - 1));
          w8[t] = (t < m) ? wgt[pp] : 0.f;
          s8[t] = srcs[pp];
        }
        ull uv[8];
#pragma unroll
        for (int t = 0; t < 8; t++)
          uv[t] = *(const ull*)(vv + (size_t)s8[t] * 256 + j0);
#pragma unroll
        for (int t = 0; t < 8; t++) {
          float ww = w8[t];
          a0 += ww * bf2f((unsigned short)uv[t]);
          a1 += ww * bf2f((unsigned short)(uv[t] >> 16));
          a2 += ww * bf2f((unsigned short)(uv[t] >> 32));
          a3 += ww * bf2f((unsigned short)(uv[t] >> 48));
        }
      }
      float4 u0 = *(const float4*)(ubar + (size_t)n * 8);
      float4 u1 = *(const float4*)(ubar + (size_t)n * 8 + 4);
#pragma unroll
      for (int r = 0; r < 4; r++) {
        int d = j0 + r;
        e[r] = be_s[d]
             + we_s[d * 6 + 0] * u0.x + we_s[d * 6 + 1] * u0.y + we_s[d * 6 + 2] * u0.z
             + we_s[d * 6 + 3] * u0.w + we_s[d * 6 + 4] * u1.x + we_s[d * 6 + 5] * u1.y;
      }
    }
    float4 skv = *(const float4*)(skipv + (size_t)n * 256 + j0);
    float h0 = fmaxf(a0 + e[0] + skv.x, 0.f);
    float h1 = fmaxf(a1 + e[1] + skv.y, 0.f);
    float h2 = fmaxf(a2 + e[2] + skv.z, 0.f);
    float h3 = fmaxf(a3 + e[3] + skv.w, 0.f);
    if (mode == 0) {
      ull hv = (ull)f2bf(h0) | ((ull)f2bf(h1) << 16) | ((ull)f2bf(h2) << 32) | ((ull)f2bf(h3) << 48);
      // A-frag-order address (K=256): d=lane*4 -> ks=lane>>3, quad=(lane>>1)&3,
      // kj=(lane&1)*4; layout [n32][ks][half][lane'][kj]
      int n32 = n >> 5, lmn = n & 15, halfn = (n >> 4) & 1;
      int ks = lane >> 3, quadc = (lane >> 1) & 3, kjc = (lane & 1) * 4;
      size_t a = (((size_t)(n32 * 8 + ks)) * 2 + halfn) * 512 + (quadc * 16 + lmn) * 8 + kjc;
      *(ull*)(hout + a) = hv;
    } else {
      float4 o; o.x = h0; o.y = h1; o.z = h2; o.w = h3;
      *(float4*)(h_acc + (size_t)n * 256 + j0) = o;
    }
  }
}

// ---- P5: segmented pooling over sorted batch (contiguous node ranges) -----
__global__ __launch_bounds__(256) void pool_reduce(
    const float* __restrict__ hfin, const int* __restrict__ batch, int Nn,
    float* __restrict__ gap, unsigned int* __restrict__ gmp) {
  int g = blockIdx.x, s = blockIdx.y, t = threadIdx.x;
  __shared__ int st_s, en_s;
  if (t == 0) {
    int lo = 0, hi = Nn;
    while (lo < hi) { int mid = (lo + hi) >> 1; if (batch[mid] < g) lo = mid + 1; else hi = mid; }
    st_s = lo;
    lo = 0; hi = Nn;
    while (lo < hi) { int mid = (lo + hi) >> 1; if (batch[mid] < g + 1) lo = mid + 1; else hi = mid; }
    en_s = lo;
  }
  __syncthreads();
  int st = st_s, en = en_s;
  int len = en - st;
  if (len <= 0) return;
  int nsplit = gridDim.y;
  int chunk = (len + nsplit - 1) / nsplit;
  int a = st + s * chunk;
  int b = min(a + chunk, en);
  if (a >= b) return;
  float acc = 0.f, mx = 0.f;  // h >= 0 (relu)
  for (int n = a; n < b; n++) {
    float v = hfin[(size_t)n * 256 + t];
    acc += v;
    mx = fmaxf(mx, v);
  }
  atomicAdd(&gap[(size_t)g * 256 + t], acc);
  atomicMax(&gmp[(size_t)g * 256 + t], __float_as_uint(mx));
}

// ---- per-graph pooling finalize + 3-layer MLP + sigmoid -------------------
__global__ __launch_bounds__(256) void pool_mlp(
    const float* __restrict__ gap, const unsigned int* __restrict__ gmp,
    const int* __restrict__ batch, int Nn,
    const float* __restrict__ w1, const float* __restrict__ b1,
    const float* __restrict__ w2, const float* __restrict__ b2,
    const float* __restrict__ w3, const float* __restrict__ b3,
    float* __restrict__ out) {
  int g = blockIdx.x, t = threadIdx.x;
  __shared__ float r[512];
  __shared__ float o1[256];
  __shared__ float o2[128];
  __shared__ float red[256];
  __shared__ int cnt_s;
  if (t == 0) {
    int lo = 0, hi = Nn;
    while (lo < hi) { int mid = (lo + hi) >> 1; if (batch[mid] < g) lo = mid + 1; else hi = mid; }
    int st = lo;
    lo = 0; hi = Nn;
    while (lo < hi) { int mid = (lo + hi) >> 1; if (batch[mid] < g + 1) lo = mid + 1; else hi = mid; }
    cnt_s = lo - st;
  }
  __syncthreads();
  float inv = 1.f / fmaxf((float)cnt_s, 1.f);
  r[t] = gap[(size_t)g * 256 + t] * inv;
  r[256 + t] = __uint_as_float(gmp[(size_t)g * 256 + t]);
  __syncthreads();
  {
    float a = b1[t];
    const float* wr = w1 + (size_t)t * 512;
    for (int k = 0; k < 512; k++) a += wr[k] * r[k];
    o1[t] = fmaxf(a, 0.f);
  }
  __syncthreads();
  if (t < 128) {
    float a = b2[t];
    const float* wr = w2 + (size_t)t * 256;
    for (int k = 0; k < 256; k++) a += wr[k] * o1[k];
    o2[t] = fmaxf(a, 0.f);
  }
  __syncthreads();
  red[t] = (t < 128) ? w3[t] * o2[t] : 0.f;
  __syncthreads();
  for (int s = 128; s > 0; s >>= 1) {
    if (t < s) red[t] += red[t + s];
    __syncthreads();
  }
  if (t == 0) out[g] = 1.f / (1.f + expf(-(red[0] + b3[0])));
}

// ---------------------------------------------------------------------------
extern "C" void kernel_launch(void* const* d_in, const int* in_sizes, int n_in,
                              void* d_out, int out_size, void* d_ws, size_t ws_size,
                              hipStream_t stream) {
  const int* x_idx      = (const int*)d_in[0];
  const int* edge_index = (const int*)d_in[1];
  const float* eattr    = (const float*)d_in[2];
  const int* batch      = (const int*)d_in[3];
  const float* emb      = (const float*)d_in[4];
  const float* c1_wq = (const float*)d_in[5],  *c1_bq = (const float*)d_in[6];
  const float* c1_wk = (const float*)d_in[7],  *c1_bk = (const float*)d_in[8];
  const float* c1_wv = (const float*)d_in[9],  *c1_bv = (const float*)d_in[10];
  const float* c1_we = (const float*)d_in[11], *c1_be = (const float*)d_in[12];
  const float* c1_ws = (const float*)d_in[13], *c1_bs = (const float*)d_in[14];
  const float* c2_wq = (const float*)d_in[15], *c2_bq = (const float*)d_in[16];
  const float* c2_wk = (const float*)d_in[17], *c2_bk = (const float*)d_in[18];
  const float* c2_wv = (const float*)d_in[19], *c2_bv = (const float*)d_in[20];
  const float* c2_we = (const float*)d_in[21], *c2_be = (const float*)d_in[22];
  const float* c2_ws = (const float*)d_in[23], *c2_bs = (const float*)d_in[24];
  const float* w1 = (const float*)d_in[25], *b1 = (const float*)d_in[26];
  const float* w2 = (const float*)d_in[27], *b2 = (const float*)d_in[28];
  const float* w3 = (const float*)d_in[29], *b3 = (const float*)d_in[30];

  const int Nn = in_sizes[3];        // 50000
  const int Ee = in_sizes[1] / 2;    // 300000
  const int nrb = (Nn + 127) / 128;  // 391 row-blocks (gemm grid + padding)

  char* ws = (char*)d_ws;
  size_t off = 0;
  auto alloc = [&](size_t bytes) -> void* {
    void* p = ws + off;
    off += (bytes + 255) & ~(size_t)255;
    return p;
  };
  // xbf/h1bf padded to whole 128-row blocks (frag-order reads go to nrb*128)
  unsigned short* xbf   = (unsigned short*)alloc((size_t)nrb * 128 * 512 * 2);
  unsigned short* qbf   = (unsigned short*)alloc((size_t)Nn * 256 * 2);
  unsigned short* kbf   = (unsigned short*)alloc((size_t)Nn * 256 * 2);
  unsigned short* vbf   = (unsigned short*)alloc((size_t)Nn * 256 * 2);
  float*          skipf = (float*)alloc((size_t)Nn * 256 * 4);
  unsigned short* h1bf  = (unsigned short*)alloc((size_t)nrb * 128 * 256 * 2);
  unsigned short* Wcat1 = (unsigned short*)alloc((size_t)1024 * 512 * 2);
  float*          bcat1 = (float*)alloc(1024 * 4);
  unsigned short* Wcat2 = (unsigned short*)alloc((size_t)1024 * 256 * 2);
  float*          bcat2 = (float*)alloc(1024 * 4);
  int*            counts    = (int*)alloc((size_t)Nn * 4);
  int*            row_start = (int*)alloc((size_t)Nn * 4);
  int*            cursor    = (int*)alloc((size_t)Nn * 4);
  int*            srcs      = (int*)alloc((size_t)Ee * 4);
  int*            dsts      = (int*)alloc((size_t)Ee * 4);
  float*          ea_perm   = (float*)alloc((size_t)Ee * 6 * 4);
  float*          logits    = (float*)alloc((size_t)Ee * 4);   // becomes weights
  float*          zc        = (float*)alloc((size_t)Nn * 8 * 4);
  float*          ubar      = (float*)alloc((size_t)Nn * 8 * 4);
  int*            total     = (int*)alloc(256);
  float*          gap       = (float*)alloc((size_t)64 * 256 * 4);
  unsigned int*   gmp       = (unsigned int*)alloc((size_t)64 * 256 * 4);
  // h_acc (50k x 256 fp32 = 51.2 MB) ALIASES xbf (51.25 MB padded): xbf is
  // dead after gemm1; h_acc first touched by edge_agg_final mode 1.
  float* h_acc = (float*)xbf;

  const int* srcA = edge_index;
  const int* dstA = edge_index + Ee;

  hipMemsetAsync(counts, 0, (size_t)Nn * 4, stream);
  hipMemsetAsync(total, 0, 4, stream);
  hipMemsetAsync(gap, 0, (size_t)64 * 256 * 4, stream);
  hipMemsetAsync(gmp, 0, (size_t)64 * 256 * 4, stream);

  pack_weights<<<(1024 * 512 + 255) / 256, 256, 0, stream>>>(
      c1_wq, c1_wk, c1_wv, c1_ws, c1_bq, c1_bk, c1_bv, c1_bs, Wcat1, bcat1, 9);
  pack_weights<<<(1024 * 256 + 255) / 256, 256, 0, stream>>>(
      c2_wq, c2_wk, c2_wv, c2_ws, c2_bq, c2_bk, c2_bv, c2_bs, Wcat2, bcat2, 8);
  embed_gather<<<((Nn * 512) + 255) / 256, 256, 0, stream>>>(x_idx, emb, xbf, Nn * 512);
  count_dst<<<(Ee + 255) / 256, 256, 0, stream>>>(dstA, counts, Ee);
  alloc_rows<<<(Nn + 255) / 256, 256, 0, stream>>>(counts, row_start, cursor, total, Nn);
  scatter_edges<<<(Ee + 255) / 256, 256, 0, stream>>>(dstA, srcA, eattr, cursor,
                                                      srcs, dsts, ea_perm, Ee);

  // XCD-aware gemm grid: 8 XCD groups x max-row-blocks-per-XCD x 16 col-tiles
  const int rbmax = nrb / 8 + ((nrb % 8) ? 1 : 0);
  const int ggrid = 8 * rbmax * 16;
  const int egrid = (Ee + 31) / 32;
  const int sgrid = (Nn + NPW * 4 - 1) / (NPW * 4);  // node-owned agg waves
  const int ngrid = (Nn + 3) / 4;

  // layer 1
  gemm_qkvs<512><<<ggrid, 256, 0, stream>>>(xbf, Wcat1, bcat1, qbf, kbf, vbf,
                                            skipf, Nn, nrb);
  node_prep<<<ngrid, 256, 0, stream>>>(qbf, c1_we, c1_be, zc, Nn);
  edge_logits<<<egrid, 256, 0, stream>>>(srcs, dsts, ea_perm, qbf, kbf, zc, Ee, logits);
  node_softmax<<<ngrid, 256, 0, stream>>>(row_start, counts, ea_perm, logits, ubar, Nn);
  edge_agg_final<<<sgrid, 256, 0, stream>>>(srcs, row_start, counts, logits, vbf,
                                            ubar, skipf, c1_we, c1_be, Nn, 0,
                                            h1bf, nullptr);

  // layer 2
  gemm_qkvs<256><<<ggrid, 256, 0, stream>>>(h1bf, Wcat2, bcat2, qbf, kbf, vbf,
                                            skipf, Nn, nrb);
  node_prep<<<ngrid, 256, 0, stream>>>(qbf, c2_we, c2_be, zc, Nn);
  edge_logits<<<egrid, 256, 0, stream>>>(srcs, dsts, ea_perm, qbf, kbf, zc, Ee, logits);
  node_softmax<<<ngrid, 256, 0, stream>>>(row_start, counts, ea_perm, logits, ubar, Nn);
  edge_agg_final<<<sgrid, 256, 0, stream>>>(srcs, row_start, counts, logits, vbf,
                                            ubar, skipf, c2_we, c2_be, Nn, 1,
                                            nullptr, h_acc);

  // segmented pooling (batch sorted -> contiguous ranges), then MLP
  dim3 pg(64, 16);
  pool_reduce<<<pg, 256, 0, stream>>>(h_acc, batch, Nn, gap, gmp);
  pool_mlp<<<64, 256, 0, stream>>>(gap, gmp, batch, Nn, w1, b1, w2, b2, w3, b3,
                                   (float*)d_out);
}

// Round 15
// 754.764 us; speedup vs baseline: 1.0923x; 1.0186x over previous
//
#include <hip/hip_runtime.h>

typedef unsigned long long ull;
typedef __bf16 bf16x8 __attribute__((ext_vector_type(8)));
typedef float f32x4 __attribute__((ext_vector_type(4)));

__device__ __forceinline__ float bf2f(unsigned short u) {
  union { unsigned int i; float f; } c; c.i = ((unsigned int)u) << 16; return c.f;
}
__device__ __forceinline__ unsigned short f2bf(float f) {
  union { float f; unsigned int i; } c; c.f = f;
  unsigned int u = c.i;
  u += 0x7fffu + ((u >> 16) & 1u);
  return (unsigned short)(u >> 16);
}

// ---- pack 4x [256,K] fp32 weights -> bf16 B-FRAGMENT-ORDER + bias concat --
// Layout: Wcat[colt][ks][rg][lane][kj]  (fragment index OUTSIDE lane, so
// each 16B load instruction in gemm is lane-contiguous: 64x16B = 1KB burst).
__global__ __launch_bounds__(256) void pack_weights(
    const float* __restrict__ wq, const float* __restrict__ wk,
    const float* __restrict__ wv, const float* __restrict__ ws,
    const float* __restrict__ bq, const float* __restrict__ bk,
    const float* __restrict__ bv, const float* __restrict__ bs,
    unsigned short* __restrict__ Wcat, float* __restrict__ bcat, int logK) {
  int idx = blockIdx.x * 256 + threadIdx.x;
  if (idx < 1024) {
    int rr = idx >> 8, cc = idx & 255;
    const float* bp = (rr == 0) ? bq : (rr == 1) ? bk : (rr == 2) ? bv : bs;
    bcat[idx] = bp[cc];
  }
  int K = 1 << logK;
  if (idx >= (1024 << logK)) return;
  int kj = idx & 7;
  int lane = (idx >> 3) & 63;
  int rg = (idx >> 9) & 3;
  int ksbits = logK - 5;
  int ks = (idx >> 11) & ((1 << ksbits) - 1);
  int colt = idx >> (11 + ksbits);
  int quad = lane >> 4, lm = lane & 15;
  int o = colt * 64 + rg * 16 + lm;
  int k = ks * 32 + quad * 8 + kj;
  int rr = o >> 8, oo = o & 255;
  const float* wp = (rr == 0) ? wq : (rr == 1) ? wk : (rr == 2) ? wv : ws;
  Wcat[idx] = f2bf(wp[oo * K + k]);
}

// ---- embedding gather -> A-FRAGMENT-ORDER xbf (K=512) ---------------------
// Layout: xbf[grp32][ks][half][lane][kj] (32-row groups).
__global__ __launch_bounds__(256) void embed_gather(
    const int* __restrict__ x_idx, const float* __restrict__ emb,
    unsigned short* __restrict__ xbf, int total) {
  int idx = blockIdx.x * 256 + threadIdx.x;
  if (idx >= total) return;
  int n = idx >> 9, d = idx & 511, f = d >> 6, j = d & 63;
  int vi = x_idx[n * 8 + f];
  int n32 = n >> 5, lm = n & 15, half = (n >> 4) & 1;
  int ks = d >> 5, quad = (d >> 3) & 3, kj = d & 7;
  size_t a = (((size_t)(n32 * 16 + ks)) * 2 + half) * 512 + (quad * 16 + lm) * 8 + kj;
  xbf[a] = f2bf(emb[vi * 64 + j]);
}

// ---- CSR build ------------------------------------------------------------
__global__ __launch_bounds__(256) void count_dst(const int* __restrict__ dst,
                                                 int* __restrict__ counts, int E_) {
  int i = blockIdx.x * 256 + threadIdx.x;
  if (i < E_) atomicAdd(&counts[dst[i]], 1);
}

// NOTE: bases assigned by atomicAdd in arbitrary wave order -> row_start is
// a VALID CSR (disjoint, correct offsets) but NOT sorted by node index.
// No consumer may assume monotonicity (R11 bug).
__global__ __launch_bounds__(256) void alloc_rows(const int* __restrict__ counts,
                                                  int* __restrict__ row_start,
                                                  int* __restrict__ cursor,
                                                  int* __restrict__ total, int n) {
  int i = blockIdx.x * 256 + threadIdx.x;
  int lane = threadIdx.x & 63;
  int c = (i < n) ? counts[i] : 0;
  int incl = c;
#pragma unroll
  for (int off = 1; off < 64; off <<= 1) {
    int t = __shfl_up(incl, off, 64);
    if (lane >= off) incl += t;
  }
  int base = 0;
  if (lane == 63) base = atomicAdd(total, incl);
  base = __shfl(base, 63, 64);
  int st = base + incl - c;
  if (i < n) { row_start[i] = st; cursor[i] = st; }
}

// scatter edges into CSR order; materialize permuted src/dst ids and attrs
__global__ __launch_bounds__(256) void scatter_edges(
    const int* __restrict__ dst, const int* __restrict__ srcA,
    const float* __restrict__ eattr, int* __restrict__ cursor,
    int* __restrict__ srcs, int* __restrict__ dsts,
    float* __restrict__ ea_perm, int E_) {
  int i = blockIdx.x * 256 + threadIdx.x;
  if (i >= E_) return;
  int d = dst[i];
  int p = atomicAdd(&cursor[d], 1);
  srcs[p] = srcA[i];
  dsts[p] = d;
  const float* ea = eattr + (size_t)i * 6;
  float* eo = ea_perm + (size_t)p * 6;
  eo[0] = ea[0]; eo[1] = ea[1]; eo[2] = ea[2];
  eo[3] = ea[3]; eo[4] = ea[4]; eo[5] = ea[5];
}

// ---- fused QKVS GEMM: LDS-staged B, async double buffer -------------------
// 128-row blocks, 32x64/wave (R12-proven shape). B per 128-k chunk (16KB) is
// cooperatively staged to LDS (fill: 1KB-contiguous bursts; read:
// ds_read_b128 at the 8-cyc structural floor). Block line-requests halve:
// A 2048 + B 4096 -> A 2048 + fill 1024. One barrier per chunk; next chunk's
// global loads issued into regs BEFORE compute (latency hidden).
template <int K>
__global__ __launch_bounds__(256) void gemm_qkvs(
    const unsigned short* __restrict__ X, const unsigned short* __restrict__ W,
    const float* __restrict__ bcat,
    unsigned short* __restrict__ qout, unsigned short* __restrict__ kout,
    unsigned short* __restrict__ vout, float* __restrict__ sout,
    int Nn, int nrb) {
  __shared__ unsigned short Bs[2][8192];   // 2 x 16KB
  const int l = blockIdx.x;
  const int xcd = l & 7, j = l >> 3;
  const int q = nrb >> 3, r = nrb & 7;
  const int cnt = q + (xcd < r ? 1 : 0);
  const int lrb = j >> 4, colt = j & 15;
  if (lrb >= cnt) return;
  const int m_blk = xcd * q + min(xcd, r) + lrb;

  const int tid = threadIdx.x;
  const int wid = tid >> 6;
  const int lane = tid & 63;
  const int quad = lane >> 4, lm = lane & 15;
  const int m_base = m_blk * 128 + wid * 32;
  const int n_base = colt * 64;
  const size_t abase = (size_t)(m_blk * 4 + wid) * (K >> 5) * 1024 + lane * 8;
  const unsigned short* wchunk = W + (size_t)colt * (K >> 5) * 2048;
  const int nc = (K >> 5) / 4;             // 128-k chunks
  f32x4 acc[2][4] = {};

  // preload chunk 0
  {
    bf16x8 st0 = *(const bf16x8*)(wchunk + 0 * 2048 + tid * 8);
    bf16x8 st1 = *(const bf16x8*)(wchunk + 1 * 2048 + tid * 8);
    bf16x8 st2 = *(const bf16x8*)(wchunk + 2 * 2048 + tid * 8);
    bf16x8 st3 = *(const bf16x8*)(wchunk + 3 * 2048 + tid * 8);
    *(bf16x8*)(&Bs[0][0 * 2048 + tid * 8]) = st0;
    *(bf16x8*)(&Bs[0][1 * 2048 + tid * 8]) = st1;
    *(bf16x8*)(&Bs[0][2 * 2048 + tid * 8]) = st2;
    *(bf16x8*)(&Bs[0][3 * 2048 + tid * 8]) = st3;
  }
  __syncthreads();

  for (int c = 0; c < nc; c++) {
    bf16x8 st0, st1, st2, st3;
    const bool pf = (c + 1 < nc);
    if (pf) {
      const unsigned short* wp = wchunk + (size_t)(c + 1) * 8192;
      st0 = *(const bf16x8*)(wp + 0 * 2048 + tid * 8);
      st1 = *(const bf16x8*)(wp + 1 * 2048 + tid * 8);
      st2 = *(const bf16x8*)(wp + 2 * 2048 + tid * 8);
      st3 = *(const bf16x8*)(wp + 3 * 2048 + tid * 8);
    }
    const unsigned short* bs = &Bs[c & 1][0];
#pragma unroll
    for (int s = 0; s < 4; s++) {
      const int ks = c * 4 + s;
      const unsigned short* ap = X + abase + (size_t)ks * 1024;
      const unsigned short* bp = bs + s * 2048 + lane * 8;
      bf16x8 a0 = *(const bf16x8*)(ap);
      bf16x8 a1 = *(const bf16x8*)(ap + 512);
      bf16x8 b0 = *(const bf16x8*)(bp);
      bf16x8 b1 = *(const bf16x8*)(bp + 512);
      bf16x8 b2 = *(const bf16x8*)(bp + 1024);
      bf16x8 b3 = *(const bf16x8*)(bp + 1536);
      acc[0][0] = __builtin_amdgcn_mfma_f32_16x16x32_bf16(a0, b0, acc[0][0], 0, 0, 0);
      acc[0][1] = __builtin_amdgcn_mfma_f32_16x16x32_bf16(a0, b1, acc[0][1], 0, 0, 0);
      acc[0][2] = __builtin_amdgcn_mfma_f32_16x16x32_bf16(a0, b2, acc[0][2], 0, 0, 0);
      acc[0][3] = __builtin_amdgcn_mfma_f32_16x16x32_bf16(a0, b3, acc[0][3], 0, 0, 0);
      acc[1][0] = __builtin_amdgcn_mfma_f32_16x16x32_bf16(a1, b0, acc[1][0], 0, 0, 0);
      acc[1][1] = __builtin_amdgcn_mfma_f32_16x16x32_bf16(a1, b1, acc[1][1], 0, 0, 0);
      acc[1][2] = __builtin_amdgcn_mfma_f32_16x16x32_bf16(a1, b2, acc[1][2], 0, 0, 0);
      acc[1][3] = __builtin_amdgcn_mfma_f32_16x16x32_bf16(a1, b3, acc[1][3], 0, 0, 0);
    }
    if (pf) {
      unsigned short* bw = &Bs[(c + 1) & 1][0];
      *(bf16x8*)(bw + 0 * 2048 + tid * 8) = st0;
      *(bf16x8*)(bw + 1 * 2048 + tid * 8) = st1;
      *(bf16x8*)(bw + 2 * 2048 + tid * 8) = st2;
      *(bf16x8*)(bw + 3 * 2048 + tid * 8) = st3;
    }
    __syncthreads();
  }
#pragma unroll
  for (int mi = 0; mi < 2; mi++) {
#pragma unroll
    for (int r2 = 0; r2 < 4; r2++) {
      int row = m_base + mi * 16 + quad * 4 + r2;
      if (row >= Nn) continue;
      size_t rb = (size_t)row * 256;
#pragma unroll
      for (int ni = 0; ni < 4; ni++) {
        int col = n_base + ni * 16 + lm;
        float v = acc[mi][ni][r2] + bcat[col];
        int reg = col >> 8, c2 = col & 255;
        if (reg == 0)       qout[rb + c2] = f2bf(v * 0.0625f);
        else if (reg == 1)  kout[rb + c2] = f2bf(v);
        else if (reg == 2)  vout[rb + c2] = f2bf(v);
        else                sout[rb + c2] = v;
      }
    }
  }
}

// ---- node_prep: z[n] = We^T q[n] (6), c[n] = q[n].be -> zc[n][8] ----------
__global__ __launch_bounds__(256) void node_prep(
    const unsigned short* __restrict__ qv,
    const float* __restrict__ we, const float* __restrict__ be,
    float* __restrict__ zc, int Nn) {
  __shared__ float we_s[1536];
  __shared__ float be_s[256];
  for (int i = threadIdx.x; i < 1536; i += 256) we_s[i] = we[i];
  be_s[threadIdx.x] = be[threadIdx.x];
  __syncthreads();
  int wid = threadIdx.x >> 6, lane = threadIdx.x & 63;
  int n = blockIdx.x * 4 + wid;
  if (n >= Nn) return;
  int j0 = lane * 4;
  ull uq = *(const ull*)(qv + (size_t)n * 256 + j0);
  float q0 = bf2f((unsigned short)uq), q1 = bf2f((unsigned short)(uq >> 16));
  float q2 = bf2f((unsigned short)(uq >> 32)), q3 = bf2f((unsigned short)(uq >> 48));
  float part[7];
#pragma unroll
  for (int t = 0; t < 6; t++) {
    part[t] = we_s[(j0 + 0) * 6 + t] * q0 + we_s[(j0 + 1) * 6 + t] * q1
            + we_s[(j0 + 2) * 6 + t] * q2 + we_s[(j0 + 3) * 6 + t] * q3;
  }
  part[6] = be_s[j0] * q0 + be_s[j0 + 1] * q1 + be_s[j0 + 2] * q2 + be_s[j0 + 3] * q3;
#pragma unroll
  for (int off = 32; off > 0; off >>= 1) {
#pragma unroll
    for (int t = 0; t < 7; t++) part[t] += __shfl_xor(part[t], off, 64);
  }
  if (lane == 0) {
    float* zp = zc + (size_t)n * 8;
#pragma unroll
    for (int t = 0; t < 7; t++) zp[t] = part[t];
    zp[7] = 0.f;
  }
}

__device__ __forceinline__ float dot4(ull uq, ull uk) {
  return bf2f((unsigned short)uq) * bf2f((unsigned short)uk)
       + bf2f((unsigned short)(uq >> 16)) * bf2f((unsigned short)(uk >> 16))
       + bf2f((unsigned short)(uq >> 32)) * bf2f((unsigned short)(uk >> 32))
       + bf2f((unsigned short)(uq >> 48)) * bf2f((unsigned short)(uk >> 48));
}

#define SEL8_I(a, t) ((t)==0?(a)[0]:(t)==1?(a)[1]:(t)==2?(a)[2]:(t)==3?(a)[3]:(t)==4?(a)[4]:(t)==5?(a)[5]:(t)==6?(a)[6]:(a)[7])

// ---- P1: edge-parallel logits = q[dst].k[src] + z[dst].u + c[dst] ---------
__global__ __launch_bounds__(256) void edge_logits(
    const int* __restrict__ srcs, const int* __restrict__ dsts,
    const float* __restrict__ ea_perm,
    const unsigned short* __restrict__ qv, const unsigned short* __restrict__ kv,
    const float* __restrict__ zc, int E_, float* __restrict__ logits) {
  int wid = threadIdx.x >> 6, lane = threadIdx.x & 63;
  int p0 = (blockIdx.x * 4 + wid) * 8;
  if (p0 >= E_) return;
  int j0 = lane * 4;
  int s_[8], d_[8];
  if (p0 + 8 <= E_) {
    int4 sa = *(const int4*)(srcs + p0), sb = *(const int4*)(srcs + p0 + 4);
    int4 da = *(const int4*)(dsts + p0), db = *(const int4*)(dsts + p0 + 4);
    s_[0] = sa.x; s_[1] = sa.y; s_[2] = sa.z; s_[3] = sa.w;
    s_[4] = sb.x; s_[5] = sb.y; s_[6] = sb.z; s_[7] = sb.w;
    d_[0] = da.x; d_[1] = da.y; d_[2] = da.z; d_[3] = da.w;
    d_[4] = db.x; d_[5] = db.y; d_[6] = db.z; d_[7] = db.w;
  } else {
#pragma unroll
    for (int t = 0; t < 8; t++) {
      int pp = min(p0 + t, E_ - 1);
      s_[t] = srcs[pp]; d_[t] = dsts[pp];
    }
  }
  ull uk[8], uq[8];
#pragma unroll
  for (int t = 0; t < 8; t++) uk[t] = *(const ull*)(kv + (size_t)s_[t] * 256 + j0);
#pragma unroll
  for (int t = 0; t < 8; t++) uq[t] = *(const ull*)(qv + (size_t)d_[t] * 256 + j0);
  float pv[8];
#pragma unroll
  for (int t = 0; t < 8; t++) pv[t] = dot4(uq[t], uk[t]);
#pragma unroll
  for (int off = 32; off > 0; off >>= 1) {
#pragma unroll
    for (int t = 0; t < 8; t++) pv[t] += __shfl_xor(pv[t], off, 64);
  }
  // lane t (t<8) finalizes edge t: + z[dst].u + c[dst]
  if (lane < 8 && p0 + lane < E_) {
    int t = lane;
    int dd = SEL8_I(d_, t);
    float pvt = SEL8_I(pv, t);
    const float* zp = zc + (size_t)dd * 8;
    const float* u = ea_perm + (size_t)(p0 + t) * 6;
    float zd = zp[0] * u[0] + zp[1] * u[1] + zp[2] * u[2]
             + zp[3] * u[3] + zp[4] * u[4] + zp[5] * u[5] + zp[6];
    logits[p0 + t] = pvt + zd;
  }
}

// ---- P2: per-node softmax; overwrite logits with weights; also ubar -------
__global__ __launch_bounds__(256) void node_softmax(
    const int* __restrict__ row_start, const int* __restrict__ counts,
    const float* __restrict__ ea_perm,
    float* __restrict__ logits, float* __restrict__ ubar, int Nn) {
  int wid = threadIdx.x >> 6, lane = threadIdx.x & 63;
  int n = blockIdx.x * 4 + wid;
  if (n >= Nn) return;
  int beg = row_start[n], cnt = counts[n];
  if (cnt == 0) return;
  float lm = -INFINITY;
  for (int b = lane; b < cnt; b += 64) lm = fmaxf(lm, logits[beg + b]);
#pragma unroll
  for (int off = 32; off > 0; off >>= 1) lm = fmaxf(lm, __shfl_xor(lm, off, 64));
  float se = 0.f;
  for (int b = lane; b < cnt; b += 64) se += __expf(logits[beg + b] - lm);
#pragma unroll
  for (int off = 32; off > 0; off >>= 1) se += __shfl_xor(se, off, 64);
  float inv = 1.f / se;
  float u0 = 0.f, u1 = 0.f, u2 = 0.f, u3 = 0.f, u4 = 0.f, u5 = 0.f;
  for (int b = lane; b < cnt; b += 64) {
    int p = beg + b;
    float w = __expf(logits[p] - lm) * inv;
    logits[p] = w;
    const float* up = ea_perm + (size_t)p * 6;
    u0 += w * up[0]; u1 += w * up[1]; u2 += w * up[2];
    u3 += w * up[3]; u4 += w * up[4]; u5 += w * up[5];
  }
#pragma unroll
  for (int off = 32; off > 0; off >>= 1) {
    u0 += __shfl_xor(u0, off, 64); u1 += __shfl_xor(u1, off, 64);
    u2 += __shfl_xor(u2, off, 64); u3 += __shfl_xor(u3, off, 64);
    u4 += __shfl_xor(u4, off, 64); u5 += __shfl_xor(u5, off, 64);
  }
  if (lane == 0) {
    float* up = ubar + (size_t)n * 8;
    up[0] = u0; up[1] = u1; up[2] = u2; up[3] = u3; up[4] = u4; up[5] = u5;
  }
}

// ---- P3: FUSED atomic-free aggregation + finalize -------------------------
// Wave w owns nodes [8w, 8w+8) by NODE INDEX. For each owned node: weighted
// v-gather-sum in registers, then IN-REGISTER epilogue
// h = relu(sum + We*ubar + be*[cnt>0] + skip) and ONE direct store.
// mode 0: write h bf16 in A-FRAGMENT-ORDER (gemm2 input).
// mode 1: write h fp32 to h_acc (pool_reduce input). All n<Nn written.
#define NPW 8
__global__ __launch_bounds__(256) void edge_agg_final(
    const int* __restrict__ srcs, const int* __restrict__ row_start,
    const int* __restrict__ counts, const float* __restrict__ wgt,
    const unsigned short* __restrict__ vv,
    const float* __restrict__ ubar, const float* __restrict__ skipv,
    const float* __restrict__ we, const float* __restrict__ be,
    int Nn, int mode,
    unsigned short* __restrict__ hout, float* __restrict__ h_acc) {
  __shared__ float we_s[1536];
  __shared__ float be_s[256];
  for (int i = threadIdx.x; i < 1536; i += 256) we_s[i] = we[i];
  be_s[threadIdx.x] = be[threadIdx.x];
  __syncthreads();
  int wave = blockIdx.x * 4 + (threadIdx.x >> 6);
  int lane = threadIdx.x & 63;
  int n0 = wave * NPW;
  if (n0 >= Nn) return;
  int n1 = min(n0 + NPW, Nn);
  int j0 = lane * 4;
  for (int n = n0; n < n1; n++) {
    int cnt = counts[n];
    float a0 = 0.f, a1 = 0.f, a2 = 0.f, a3 = 0.f;
    float e[4] = {0.f, 0.f, 0.f, 0.f};
    if (cnt > 0) {
      int beg = row_start[n];
      for (int i0 = 0; i0 < cnt; i0 += 8) {
        int m = cnt - i0; if (m > 8) m = 8;
        float w8[8];
        int s8[8];
#pragma unroll
        for (int t = 0; t < 8; t++) {
          int pp = beg + i0 + ((t < m) ? t : (m - 1));
          w8[t] = (t < m) ? wgt[pp] : 0.f;
          s8[t] = srcs[pp];
        }
        ull uv[8];
#pragma unroll
        for (int t = 0; t < 8; t++)
          uv[t] = *(const ull*)(vv + (size_t)s8[t] * 256 + j0);
#pragma unroll
        for (int t = 0; t < 8; t++) {
          float ww = w8[t];
          a0 += ww * bf2f((unsigned short)uv[t]);
          a1 += ww * bf2f((unsigned short)(uv[t] >> 16));
          a2 += ww * bf2f((unsigned short)(uv[t] >> 32));
          a3 += ww * bf2f((unsigned short)(uv[t] >> 48));
        }
      }
      float4 u0 = *(const float4*)(ubar + (size_t)n * 8);
      float4 u1 = *(const float4*)(ubar + (size_t)n * 8 + 4);
#pragma unroll
      for (int r = 0; r < 4; r++) {
        int d = j0 + r;
        e[r] = be_s[d]
             + we_s[d * 6 + 0] * u0.x + we_s[d * 6 + 1] * u0.y + we_s[d * 6 + 2] * u0.z
             + we_s[d * 6 + 3] * u0.w + we_s[d * 6 + 4] * u1.x + we_s[d * 6 + 5] * u1.y;
      }
    }
    float4 skv = *(const float4*)(skipv + (size_t)n * 256 + j0);
    float h0 = fmaxf(a0 + e[0] + skv.x, 0.f);
    float h1 = fmaxf(a1 + e[1] + skv.y, 0.f);
    float h2 = fmaxf(a2 + e[2] + skv.z, 0.f);
    float h3 = fmaxf(a3 + e[3] + skv.w, 0.f);
    if (mode == 0) {
      ull hv = (ull)f2bf(h0) | ((ull)f2bf(h1) << 16) | ((ull)f2bf(h2) << 32) | ((ull)f2bf(h3) << 48);
      // A-frag-order address (K=256): d=lane*4 -> ks=lane>>3, quad=(lane>>1)&3,
      // kj=(lane&1)*4; layout [n32][ks][half][lane'][kj]
      int n32 = n >> 5, lmn = n & 15, halfn = (n >> 4) & 1;
      int ks = lane >> 3, quadc = (lane >> 1) & 3, kjc = (lane & 1) * 4;
      size_t a = (((size_t)(n32 * 8 + ks)) * 2 + halfn) * 512 + (quadc * 16 + lmn) * 8 + kjc;
      *(ull*)(hout + a) = hv;
    } else {
      float4 o; o.x = h0; o.y = h1; o.z = h2; o.w = h3;
      *(float4*)(h_acc + (size_t)n * 256 + j0) = o;
    }
  }
}

// ---- P5: segmented pooling over sorted batch (contiguous node ranges) -----
__global__ __launch_bounds__(256) void pool_reduce(
    const float* __restrict__ hfin, const int* __restrict__ batch, int Nn,
    float* __restrict__ gap, unsigned int* __restrict__ gmp) {
  int g = blockIdx.x, s = blockIdx.y, t = threadIdx.x;
  __shared__ int st_s, en_s;
  if (t == 0) {
    int lo = 0, hi = Nn;
    while (lo < hi) { int mid = (lo + hi) >> 1; if (batch[mid] < g) lo = mid + 1; else hi = mid; }
    st_s = lo;
    lo = 0; hi = Nn;
    while (lo < hi) { int mid = (lo + hi) >> 1; if (batch[mid] < g + 1) lo = mid + 1; else hi = mid; }
    en_s = lo;
  }
  __syncthreads();
  int st = st_s, en = en_s;
  int len = en - st;
  if (len <= 0) return;
  int nsplit = gridDim.y;
  int chunk = (len + nsplit - 1) / nsplit;
  int a = st + s * chunk;
  int b = min(a + chunk, en);
  if (a >= b) return;
  float acc = 0.f, mx = 0.f;  // h >= 0 (relu)
  for (int n = a; n < b; n++) {
    float v = hfin[(size_t)n * 256 + t];
    acc += v;
    mx = fmaxf(mx, v);
  }
  atomicAdd(&gap[(size_t)g * 256 + t], acc);
  atomicMax(&gmp[(size_t)g * 256 + t], __float_as_uint(mx));
}

// ---- per-graph pooling finalize + 3-layer MLP + sigmoid -------------------
__global__ __launch_bounds__(256) void pool_mlp(
    const float* __restrict__ gap, const unsigned int* __restrict__ gmp,
    const int* __restrict__ batch, int Nn,
    const float* __restrict__ w1, const float* __restrict__ b1,
    const float* __restrict__ w2, const float* __restrict__ b2,
    const float* __restrict__ w3, const float* __restrict__ b3,
    float* __restrict__ out) {
  int g = blockIdx.x, t = threadIdx.x;
  __shared__ float r[512];
  __shared__ float o1[256];
  __shared__ float o2[128];
  __shared__ float red[256];
  __shared__ int cnt_s;
  if (t == 0) {
    int lo = 0, hi = Nn;
    while (lo < hi) { int mid = (lo + hi) >> 1; if (batch[mid] < g) lo = mid + 1; else hi = mid; }
    int st = lo;
    lo = 0; hi = Nn;
    while (lo < hi) { int mid = (lo + hi) >> 1; if (batch[mid] < g + 1) lo = mid + 1; else hi = mid; }
    cnt_s = lo - st;
  }
  __syncthreads();
  float inv = 1.f / fmaxf((float)cnt_s, 1.f);
  r[t] = gap[(size_t)g * 256 + t] * inv;
  r[256 + t] = __uint_as_float(gmp[(size_t)g * 256 + t]);
  __syncthreads();
  {
    float a = b1[t];
    const float* wr = w1 + (size_t)t * 512;
    for (int k = 0; k < 512; k++) a += wr[k] * r[k];
    o1[t] = fmaxf(a, 0.f);
  }
  __syncthreads();
  if (t < 128) {
    float a = b2[t];
    const float* wr = w2 + (size_t)t * 256;
    for (int k = 0; k < 256; k++) a += wr[k] * o1[k];
    o2[t] = fmaxf(a, 0.f);
  }
  __syncthreads();
  red[t] = (t < 128) ? w3[t] * o2[t] : 0.f;
  __syncthreads();
  for (int s = 128; s > 0; s >>= 1) {
    if (t < s) red[t] += red[t + s];
    __syncthreads();
  }
  if (t == 0) out[g] = 1.f / (1.f + expf(-(red[0] + b3[0])));
}

// ---------------------------------------------------------------------------
extern "C" void kernel_launch(void* const* d_in, const int* in_sizes, int n_in,
                              void* d_out, int out_size, void* d_ws, size_t ws_size,
                              hipStream_t stream) {
  const int* x_idx      = (const int*)d_in[0];
  const int* edge_index = (const int*)d_in[1];
  const float* eattr    = (const float*)d_in[2];
  const int* batch      = (const int*)d_in[3];
  const float* emb      = (const float*)d_in[4];
  const float* c1_wq = (const float*)d_in[5],  *c1_bq = (const float*)d_in[6];
  const float* c1_wk = (const float*)d_in[7],  *c1_bk = (const float*)d_in[8];
  const float* c1_wv = (const float*)d_in[9],  *c1_bv = (const float*)d_in[10];
  const float* c1_we = (const float*)d_in[11], *c1_be = (const float*)d_in[12];
  const float* c1_ws = (const float*)d_in[13], *c1_bs = (const float*)d_in[14];
  const float* c2_wq = (const float*)d_in[15], *c2_bq = (const float*)d_in[16];
  const float* c2_wk = (const float*)d_in[17], *c2_bk = (const float*)d_in[18];
  const float* c2_wv = (const float*)d_in[19], *c2_bv = (const float*)d_in[20];
  const float* c2_we = (const float*)d_in[21], *c2_be = (const float*)d_in[22];
  const float* c2_ws = (const float*)d_in[23], *c2_bs = (const float*)d_in[24];
  const float* w1 = (const float*)d_in[25], *b1 = (const float*)d_in[26];
  const float* w2 = (const float*)d_in[27], *b2 = (const float*)d_in[28];
  const float* w3 = (const float*)d_in[29], *b3 = (const float*)d_in[30];

  const int Nn = in_sizes[3];        // 50000
  const int Ee = in_sizes[1] / 2;    // 300000
  const int nrb = (Nn + 127) / 128;  // 391 row-blocks (gemm grid + padding)

  char* ws = (char*)d_ws;
  size_t off = 0;
  auto alloc = [&](size_t bytes) -> void* {
    void* p = ws + off;
    off += (bytes + 255) & ~(size_t)255;
    return p;
  };
  // xbf/h1bf padded to whole 128-row blocks (frag-order reads go to nrb*128)
  unsigned short* xbf   = (unsigned short*)alloc((size_t)nrb * 128 * 512 * 2);
  unsigned short* qbf   = (unsigned short*)alloc((size_t)Nn * 256 * 2);
  unsigned short* kbf   = (unsigned short*)alloc((size_t)Nn * 256 * 2);
  unsigned short* vbf   = (unsigned short*)alloc((size_t)Nn * 256 * 2);
  float*          skipf = (float*)alloc((size_t)Nn * 256 * 4);
  unsigned short* h1bf  = (unsigned short*)alloc((size_t)nrb * 128 * 256 * 2);
  unsigned short* Wcat1 = (unsigned short*)alloc((size_t)1024 * 512 * 2);
  float*          bcat1 = (float*)alloc(1024 * 4);
  unsigned short* Wcat2 = (unsigned short*)alloc((size_t)1024 * 256 * 2);
  float*          bcat2 = (float*)alloc(1024 * 4);
  int*            counts    = (int*)alloc((size_t)Nn * 4);
  int*            row_start = (int*)alloc((size_t)Nn * 4);
  int*            cursor    = (int*)alloc((size_t)Nn * 4);
  int*            srcs      = (int*)alloc((size_t)Ee * 4);
  int*            dsts      = (int*)alloc((size_t)Ee * 4);
  float*          ea_perm   = (float*)alloc((size_t)Ee * 6 * 4);
  float*          logits    = (float*)alloc((size_t)Ee * 4);   // becomes weights
  float*          zc        = (float*)alloc((size_t)Nn * 8 * 4);
  float*          ubar      = (float*)alloc((size_t)Nn * 8 * 4);
  int*            total     = (int*)alloc(256);
  float*          gap       = (float*)alloc((size_t)64 * 256 * 4);
  unsigned int*   gmp       = (unsigned int*)alloc((size_t)64 * 256 * 4);
  // h_acc (50k x 256 fp32 = 51.2 MB) ALIASES xbf (51.25 MB padded): xbf is
  // dead after gemm1; h_acc first touched by edge_agg_final mode 1.
  float* h_acc = (float*)xbf;

  const int* srcA = edge_index;
  const int* dstA = edge_index + Ee;

  hipMemsetAsync(counts, 0, (size_t)Nn * 4, stream);
  hipMemsetAsync(total, 0, 4, stream);
  hipMemsetAsync(gap, 0, (size_t)64 * 256 * 4, stream);
  hipMemsetAsync(gmp, 0, (size_t)64 * 256 * 4, stream);

  pack_weights<<<(1024 * 512 + 255) / 256, 256, 0, stream>>>(
      c1_wq, c1_wk, c1_wv, c1_ws, c1_bq, c1_bk, c1_bv, c1_bs, Wcat1, bcat1, 9);
  pack_weights<<<(1024 * 256 + 255) / 256, 256, 0, stream>>>(
      c2_wq, c2_wk, c2_wv, c2_ws, c2_bq, c2_bk, c2_bv, c2_bs, Wcat2, bcat2, 8);
  embed_gather<<<((Nn * 512) + 255) / 256, 256, 0, stream>>>(x_idx, emb, xbf, Nn * 512);
  count_dst<<<(Ee + 255) / 256, 256, 0, stream>>>(dstA, counts, Ee);
  alloc_rows<<<(Nn + 255) / 256, 256, 0, stream>>>(counts, row_start, cursor, total, Nn);
  scatter_edges<<<(Ee + 255) / 256, 256, 0, stream>>>(dstA, srcA, eattr, cursor,
                                                      srcs, dsts, ea_perm, Ee);

  // XCD-aware gemm grid: 8 XCD groups x max-row-blocks-per-XCD x 16 col-tiles
  const int rbmax = nrb / 8 + ((nrb % 8) ? 1 : 0);
  const int ggrid = 8 * rbmax * 16;
  const int egrid = (Ee + 31) / 32;
  const int sgrid = (Nn + NPW * 4 - 1) / (NPW * 4);  // node-owned agg waves
  const int ngrid = (Nn + 3) / 4;

  // layer 1
  gemm_qkvs<512><<<ggrid, 256, 0, stream>>>(xbf, Wcat1, bcat1, qbf, kbf, vbf,
                                            skipf, Nn, nrb);
  node_prep<<<ngrid, 256, 0, stream>>>(qbf, c1_we, c1_be, zc, Nn);
  edge_logits<<<egrid, 256, 0, stream>>>(srcs, dsts, ea_perm, qbf, kbf, zc, Ee, logits);
  node_softmax<<<ngrid, 256, 0, stream>>>(row_start, counts, ea_perm, logits, ubar, Nn);
  edge_agg_final<<<sgrid, 256, 0, stream>>>(srcs, row_start, counts, logits, vbf,
                                            ubar, skipf, c1_we, c1_be, Nn, 0,
                                            h1bf, nullptr);

  // layer 2
  gemm_qkvs<256><<<ggrid, 256, 0, stream>>>(h1bf, Wcat2, bcat2, qbf, kbf, vbf,
                                            skipf, Nn, nrb);
  node_prep<<<ngrid, 256, 0, stream>>>(qbf, c2_we, c2_be, zc, Nn);
  edge_logits<<<egrid, 256, 0, stream>>>(srcs, dsts, ea_perm, qbf, kbf, zc, Ee, logits);
  node_softmax<<<ngrid, 256, 0, stream>>>(row_start, counts, ea_perm, logits, ubar, Nn);
  edge_agg_final<<<sgrid, 256, 0, stream>>>(srcs, row_start, counts, logits, vbf,
                                            ubar, skipf, c2_we, c2_be, Nn, 1,
                                            nullptr, h_acc);

  // segmented pooling (batch sorted -> contiguous ranges), then MLP
  dim3 pg(64, 16);
  pool_reduce<<<pg, 256, 0, stream>>>(h_acc, batch, Nn, gap, gmp);
  pool_mlp<<<64, 256, 0, stream>>>(gap, gmp, batch, Nn, w1, b1, w2, b2, w3, b3,
                                   (float*)d_out);
}

// Round 16
// 712.054 us; speedup vs baseline: 1.1578x; 1.0600x over previous
//
#include <hip/hip_runtime.h>

typedef unsigned long long ull;
typedef __bf16 bf16x8 __attribute__((ext_vector_type(8)));
typedef float f32x4 __attribute__((ext_vector_type(4)));

__device__ __forceinline__ float bf2f(unsigned short u) {
  union { unsigned int i; float f; } c; c.i = ((unsigned int)u) << 16; return c.f;
}
__device__ __forceinline__ unsigned short f2bf(float f) {
  union { float f; unsigned int i; } c; c.f = f;
  unsigned int u = c.i;
  u += 0x7fffu + ((u >> 16) & 1u);
  return (unsigned short)(u >> 16);
}

// ---- pack 4x [256,K] fp32 weights -> bf16 B-FRAGMENT-ORDER + bias concat --
// Layout: Wcat[colt][ks][rg][lane][kj]  (fragment index OUTSIDE lane, so
// each 16B load instruction in gemm is lane-contiguous: 64x16B = 1KB burst).
__global__ __launch_bounds__(256) void pack_weights(
    const float* __restrict__ wq, const float* __restrict__ wk,
    const float* __restrict__ wv, const float* __restrict__ ws,
    const float* __restrict__ bq, const float* __restrict__ bk,
    const float* __restrict__ bv, const float* __restrict__ bs,
    unsigned short* __restrict__ Wcat, float* __restrict__ bcat, int logK) {
  int idx = blockIdx.x * 256 + threadIdx.x;
  if (idx < 1024) {
    int rr = idx >> 8, cc = idx & 255;
    const float* bp = (rr == 0) ? bq : (rr == 1) ? bk : (rr == 2) ? bv : bs;
    bcat[idx] = bp[cc];
  }
  int K = 1 << logK;
  if (idx >= (1024 << logK)) return;
  int kj = idx & 7;
  int lane = (idx >> 3) & 63;
  int rg = (idx >> 9) & 3;
  int ksbits = logK - 5;
  int ks = (idx >> 11) & ((1 << ksbits) - 1);
  int colt = idx >> (11 + ksbits);
  int quad = lane >> 4, lm = lane & 15;
  int o = colt * 64 + rg * 16 + lm;
  int k = ks * 32 + quad * 8 + kj;
  int rr = o >> 8, oo = o & 255;
  const float* wp = (rr == 0) ? wq : (rr == 1) ? wk : (rr == 2) ? wv : ws;
  Wcat[idx] = f2bf(wp[oo * K + k]);
}

// ---- embedding gather -> A-FRAGMENT-ORDER xbf (K=512) ---------------------
// Layout: xbf[grp32][ks][half][lane][kj] (32-row groups).
__global__ __launch_bounds__(256) void embed_gather(
    const int* __restrict__ x_idx, const float* __restrict__ emb,
    unsigned short* __restrict__ xbf, int total) {
  int idx = blockIdx.x * 256 + threadIdx.x;
  if (idx >= total) return;
  int n = idx >> 9, d = idx & 511, f = d >> 6, j = d & 63;
  int vi = x_idx[n * 8 + f];
  int n32 = n >> 5, lm = n & 15, half = (n >> 4) & 1;
  int ks = d >> 5, quad = (d >> 3) & 3, kj = d & 7;
  size_t a = (((size_t)(n32 * 16 + ks)) * 2 + half) * 512 + (quad * 16 + lm) * 8 + kj;
  xbf[a] = f2bf(emb[vi * 64 + j]);
}

// ---- CSR build ------------------------------------------------------------
__global__ __launch_bounds__(256) void count_dst(const int* __restrict__ dst,
                                                 int* __restrict__ counts, int E_) {
  int i = blockIdx.x * 256 + threadIdx.x;
  if (i < E_) atomicAdd(&counts[dst[i]], 1);
}

// NOTE: bases assigned by atomicAdd in arbitrary wave order -> row_start is
// a VALID CSR (disjoint, correct offsets) but NOT sorted by node index.
// No consumer may assume monotonicity (R11 bug).
__global__ __launch_bounds__(256) void alloc_rows(const int* __restrict__ counts,
                                                  int* __restrict__ row_start,
                                                  int* __restrict__ cursor,
                                                  int* __restrict__ total, int n) {
  int i = blockIdx.x * 256 + threadIdx.x;
  int lane = threadIdx.x & 63;
  int c = (i < n) ? counts[i] : 0;
  int incl = c;
#pragma unroll
  for (int off = 1; off < 64; off <<= 1) {
    int t = __shfl_up(incl, off, 64);
    if (lane >= off) incl += t;
  }
  int base = 0;
  if (lane == 63) base = atomicAdd(total, incl);
  base = __shfl(base, 63, 64);
  int st = base + incl - c;
  if (i < n) { row_start[i] = st; cursor[i] = st; }
}

// scatter edges into CSR order; materialize permuted src/dst ids and attrs
__global__ __launch_bounds__(256) void scatter_edges(
    const int* __restrict__ dst, const int* __restrict__ srcA,
    const float* __restrict__ eattr, int* __restrict__ cursor,
    int* __restrict__ srcs, int* __restrict__ dsts,
    float* __restrict__ ea_perm, int E_) {
  int i = blockIdx.x * 256 + threadIdx.x;
  if (i >= E_) return;
  int d = dst[i];
  int p = atomicAdd(&cursor[d], 1);
  srcs[p] = srcA[i];
  dsts[p] = d;
  const float* ea = eattr + (size_t)i * 6;
  float* eo = ea_perm + (size_t)p * 6;
  eo[0] = ea[0]; eo[1] = ea[1]; eo[2] = ea[2];
  eo[3] = ea[3]; eo[4] = ea[4]; eo[5] = ea[5];
}

// ---- fused QKVS GEMM: LDS-staged B, 8KB chunks double-buffered ------------
// 128-row blocks, 32x64/wave. Chunk = 2 k-steps (8KB); 2x8KB = 16KB LDS
// (was 32KB -> LDS cap 5 blocks/CU, occ 39%; now cap 10, wave-cap 8).
// Line-requests stay halved vs no-LDS; occupancy restored to R12 level.
template <int K>
__global__ __launch_bounds__(256) void gemm_qkvs(
    const unsigned short* __restrict__ X, const unsigned short* __restrict__ W,
    const float* __restrict__ bcat,
    unsigned short* __restrict__ qout, unsigned short* __restrict__ kout,
    unsigned short* __restrict__ vout, float* __restrict__ sout,
    int Nn, int nrb) {
  __shared__ unsigned short Bs[2][4096];   // 2 x 8KB
  const int l = blockIdx.x;
  const int xcd = l & 7, j = l >> 3;
  const int q = nrb >> 3, r = nrb & 7;
  const int cnt = q + (xcd < r ? 1 : 0);
  const int lrb = j >> 4, colt = j & 15;
  if (lrb >= cnt) return;
  const int m_blk = xcd * q + min(xcd, r) + lrb;

  const int tid = threadIdx.x;
  const int wid = tid >> 6;
  const int lane = tid & 63;
  const int quad = lane >> 4, lm = lane & 15;
  const int m_base = m_blk * 128 + wid * 32;
  const int n_base = colt * 64;
  const size_t abase = (size_t)(m_blk * 4 + wid) * (K >> 5) * 1024 + lane * 8;
  const unsigned short* wchunk = W + (size_t)colt * (K >> 5) * 2048;
  const int nc = (K >> 5) >> 1;            // 64-k chunks (2 k-steps)
  f32x4 acc[2][4] = {};

  // preload chunk 0
  {
    bf16x8 st0 = *(const bf16x8*)(wchunk + 0 * 2048 + tid * 8);
    bf16x8 st1 = *(const bf16x8*)(wchunk + 1 * 2048 + tid * 8);
    *(bf16x8*)(&Bs[0][0 * 2048 + tid * 8]) = st0;
    *(bf16x8*)(&Bs[0][1 * 2048 + tid * 8]) = st1;
  }
  __syncthreads();

  for (int c = 0; c < nc; c++) {
    bf16x8 st0, st1;
    const bool pf = (c + 1 < nc);
    if (pf) {
      const unsigned short* wp = wchunk + (size_t)(c + 1) * 4096;
      st0 = *(const bf16x8*)(wp + 0 * 2048 + tid * 8);
      st1 = *(const bf16x8*)(wp + 1 * 2048 + tid * 8);
    }
    const unsigned short* bs = &Bs[c & 1][0];
#pragma unroll
    for (int s = 0; s < 2; s++) {
      const int ks = c * 2 + s;
      const unsigned short* ap = X + abase + (size_t)ks * 1024;
      const unsigned short* bp = bs + s * 2048 + lane * 8;
      bf16x8 a0 = *(const bf16x8*)(ap);
      bf16x8 a1 = *(const bf16x8*)(ap + 512);
      bf16x8 b0 = *(const bf16x8*)(bp);
      bf16x8 b1 = *(const bf16x8*)(bp + 512);
      bf16x8 b2 = *(const bf16x8*)(bp + 1024);
      bf16x8 b3 = *(const bf16x8*)(bp + 1536);
      acc[0][0] = __builtin_amdgcn_mfma_f32_16x16x32_bf16(a0, b0, acc[0][0], 0, 0, 0);
      acc[0][1] = __builtin_amdgcn_mfma_f32_16x16x32_bf16(a0, b1, acc[0][1], 0, 0, 0);
      acc[0][2] = __builtin_amdgcn_mfma_f32_16x16x32_bf16(a0, b2, acc[0][2], 0, 0, 0);
      acc[0][3] = __builtin_amdgcn_mfma_f32_16x16x32_bf16(a0, b3, acc[0][3], 0, 0, 0);
      acc[1][0] = __builtin_amdgcn_mfma_f32_16x16x32_bf16(a1, b0, acc[1][0], 0, 0, 0);
      acc[1][1] = __builtin_amdgcn_mfma_f32_16x16x32_bf16(a1, b1, acc[1][1], 0, 0, 0);
      acc[1][2] = __builtin_amdgcn_mfma_f32_16x16x32_bf16(a1, b2, acc[1][2], 0, 0, 0);
      acc[1][3] = __builtin_amdgcn_mfma_f32_16x16x32_bf16(a1, b3, acc[1][3], 0, 0, 0);
    }
    if (pf) {
      unsigned short* bw = &Bs[(c + 1) & 1][0];
      *(bf16x8*)(bw + 0 * 2048 + tid * 8) = st0;
      *(bf16x8*)(bw + 1 * 2048 + tid * 8) = st1;
    }
    __syncthreads();
  }
#pragma unroll
  for (int mi = 0; mi < 2; mi++) {
#pragma unroll
    for (int r2 = 0; r2 < 4; r2++) {
      int row = m_base + mi * 16 + quad * 4 + r2;
      if (row >= Nn) continue;
      size_t rb = (size_t)row * 256;
#pragma unroll
      for (int ni = 0; ni < 4; ni++) {
        int col = n_base + ni * 16 + lm;
        float v = acc[mi][ni][r2] + bcat[col];
        int reg = col >> 8, c2 = col & 255;
        if (reg == 0)       qout[rb + c2] = f2bf(v * 0.0625f);
        else if (reg == 1)  kout[rb + c2] = f2bf(v);
        else if (reg == 2)  vout[rb + c2] = f2bf(v);
        else                sout[rb + c2] = v;
      }
    }
  }
}

// ---- node_prep: z[n] = We^T q[n] (6), c[n] = q[n].be -> zc[n][8] ----------
__global__ __launch_bounds__(256) void node_prep(
    const unsigned short* __restrict__ qv,
    const float* __restrict__ we, const float* __restrict__ be,
    float* __restrict__ zc, int Nn) {
  __shared__ float we_s[1536];
  __shared__ float be_s[256];
  for (int i = threadIdx.x; i < 1536; i += 256) we_s[i] = we[i];
  be_s[threadIdx.x] = be[threadIdx.x];
  __syncthreads();
  int wid = threadIdx.x >> 6, lane = threadIdx.x & 63;
  int n = blockIdx.x * 4 + wid;
  if (n >= Nn) return;
  int j0 = lane * 4;
  ull uq = *(const ull*)(qv + (size_t)n * 256 + j0);
  float q0 = bf2f((unsigned short)uq), q1 = bf2f((unsigned short)(uq >> 16));
  float q2 = bf2f((unsigned short)(uq >> 32)), q3 = bf2f((unsigned short)(uq >> 48));
  float part[7];
#pragma unroll
  for (int t = 0; t < 6; t++) {
    part[t] = we_s[(j0 + 0) * 6 + t] * q0 + we_s[(j0 + 1) * 6 + t] * q1
            + we_s[(j0 + 2) * 6 + t] * q2 + we_s[(j0 + 3) * 6 + t] * q3;
  }
  part[6] = be_s[j0] * q0 + be_s[j0 + 1] * q1 + be_s[j0 + 2] * q2 + be_s[j0 + 3] * q3;
#pragma unroll
  for (int off = 32; off > 0; off >>= 1) {
#pragma unroll
    for (int t = 0; t < 7; t++) part[t] += __shfl_xor(part[t], off, 64);
  }
  if (lane == 0) {
    float* zp = zc + (size_t)n * 8;
#pragma unroll
    for (int t = 0; t < 7; t++) zp[t] = part[t];
    zp[7] = 0.f;
  }
}

__device__ __forceinline__ float dot4(ull uq, ull uk) {
  return bf2f((unsigned short)uq) * bf2f((unsigned short)uk)
       + bf2f((unsigned short)(uq >> 16)) * bf2f((unsigned short)(uk >> 16))
       + bf2f((unsigned short)(uq >> 32)) * bf2f((unsigned short)(uk >> 32))
       + bf2f((unsigned short)(uq >> 48)) * bf2f((unsigned short)(uk >> 48));
}

#define SEL8_I(a, t) ((t)==0?(a)[0]:(t)==1?(a)[1]:(t)==2?(a)[2]:(t)==3?(a)[3]:(t)==4?(a)[4]:(t)==5?(a)[5]:(t)==6?(a)[6]:(a)[7])

// ---- P1: edge-parallel logits = q[dst].k[src] + z[dst].u + c[dst] ---------
__global__ __launch_bounds__(256) void edge_logits(
    const int* __restrict__ srcs, const int* __restrict__ dsts,
    const float* __restrict__ ea_perm,
    const unsigned short* __restrict__ qv, const unsigned short* __restrict__ kv,
    const float* __restrict__ zc, int E_, float* __restrict__ logits) {
  int wid = threadIdx.x >> 6, lane = threadIdx.x & 63;
  int p0 = (blockIdx.x * 4 + wid) * 8;
  if (p0 >= E_) return;
  int j0 = lane * 4;
  int s_[8], d_[8];
  if (p0 + 8 <= E_) {
    int4 sa = *(const int4*)(srcs + p0), sb = *(const int4*)(srcs + p0 + 4);
    int4 da = *(const int4*)(dsts + p0), db = *(const int4*)(dsts + p0 + 4);
    s_[0] = sa.x; s_[1] = sa.y; s_[2] = sa.z; s_[3] = sa.w;
    s_[4] = sb.x; s_[5] = sb.y; s_[6] = sb.z; s_[7] = sb.w;
    d_[0] = da.x; d_[1] = da.y; d_[2] = da.z; d_[3] = da.w;
    d_[4] = db.x; d_[5] = db.y; d_[6] = db.z; d_[7] = db.w;
  } else {
#pragma unroll
    for (int t = 0; t < 8; t++) {
      int pp = min(p0 + t, E_ - 1);
      s_[t] = srcs[pp]; d_[t] = dsts[pp];
    }
  }
  ull uk[8], uq[8];
#pragma unroll
  for (int t = 0; t < 8; t++) uk[t] = *(const ull*)(kv + (size_t)s_[t] * 256 + j0);
#pragma unroll
  for (int t = 0; t < 8; t++) uq[t] = *(const ull*)(qv + (size_t)d_[t] * 256 + j0);
  float pv[8];
#pragma unroll
  for (int t = 0; t < 8; t++) pv[t] = dot4(uq[t], uk[t]);
#pragma unroll
  for (int off = 32; off > 0; off >>= 1) {
#pragma unroll
    for (int t = 0; t < 8; t++) pv[t] += __shfl_xor(pv[t], off, 64);
  }
  // lane t (t<8) finalizes edge t: + z[dst].u + c[dst]
  if (lane < 8 && p0 + lane < E_) {
    int t = lane;
    int dd = SEL8_I(d_, t);
    float pvt = SEL8_I(pv, t);
    const float* zp = zc + (size_t)dd * 8;
    const float* u = ea_perm + (size_t)(p0 + t) * 6;
    float zd = zp[0] * u[0] + zp[1] * u[1] + zp[2] * u[2]
             + zp[3] * u[3] + zp[4] * u[4] + zp[5] * u[5] + zp[6];
    logits[p0 + t] = pvt + zd;
  }
}

// ---- P2+P3 FUSED: per-node softmax stats + weighted v-gather + epilogue ---
// Wave w owns nodes [8w, 8w+8) by NODE INDEX. Per owned node:
//   1) max & sum-exp over its contiguous RAW logits (strided + butterfly)
//   2) gather loop: weights recomputed inline (exp(l-m)*inv, lanes 0-7,
//      shuffled), v-rows gathered 8-deep; ubar accumulated in-register
//      (lane t<8 partials, 8-lane butterfly + broadcast)
//   3) in-register epilogue h = relu(sum + We*ubar + be*[cnt>0] + skip)
// Eliminates node_softmax kernel, logits overwrite+reread, ubar buffer.
// mode 0: write h bf16 in A-FRAGMENT-ORDER (gemm2 input).
// mode 1: write h fp32 to h_acc (pool_reduce input). All n<Nn written.
#define NPW 8
__global__ __launch_bounds__(256) void node_agg2(
    const int* __restrict__ srcs, const int* __restrict__ row_start,
    const int* __restrict__ counts, const float* __restrict__ logits,
    const unsigned short* __restrict__ vv, const float* __restrict__ ea_perm,
    const float* __restrict__ skipv,
    const float* __restrict__ we, const float* __restrict__ be,
    int Nn, int mode,
    unsigned short* __restrict__ hout, float* __restrict__ h_acc) {
  __shared__ float we_s[1536];
  __shared__ float be_s[256];
  for (int i = threadIdx.x; i < 1536; i += 256) we_s[i] = we[i];
  be_s[threadIdx.x] = be[threadIdx.x];
  __syncthreads();
  int wave = blockIdx.x * 4 + (threadIdx.x >> 6);
  int lane = threadIdx.x & 63;
  int n0 = wave * NPW;
  if (n0 >= Nn) return;
  int n1 = min(n0 + NPW, Nn);
  int j0 = lane * 4;
  for (int n = n0; n < n1; n++) {
    int cnt = counts[n];
    float a0 = 0.f, a1 = 0.f, a2 = 0.f, a3 = 0.f;
    float e[4] = {0.f, 0.f, 0.f, 0.f};
    if (cnt > 0) {
      int beg = row_start[n];
      // softmax stats over raw logits
      float lmx = -INFINITY;
      for (int b = lane; b < cnt; b += 64) lmx = fmaxf(lmx, logits[beg + b]);
#pragma unroll
      for (int off = 32; off > 0; off >>= 1) lmx = fmaxf(lmx, __shfl_xor(lmx, off, 64));
      float se = 0.f;
      for (int b = lane; b < cnt; b += 64) se += __expf(logits[beg + b] - lmx);
#pragma unroll
      for (int off = 32; off > 0; off >>= 1) se += __shfl_xor(se, off, 64);
      float inv = 1.f / se;
      float ub0 = 0.f, ub1 = 0.f, ub2 = 0.f, ub3 = 0.f, ub4 = 0.f, ub5 = 0.f;
      for (int i0 = 0; i0 < cnt; i0 += 8) {
        int m = cnt - i0; if (m > 8) m = 8;
        // lanes 0-7 compute weights inline; ubar partials
        float wlane = 0.f;
        if (lane < m) {
          int myp = beg + i0 + lane;
          wlane = __expf(logits[myp] - lmx) * inv;
          const float* up = ea_perm + (size_t)myp * 6;
          ub0 += wlane * up[0]; ub1 += wlane * up[1]; ub2 += wlane * up[2];
          ub3 += wlane * up[3]; ub4 += wlane * up[4]; ub5 += wlane * up[5];
        }
        float w8[8];
        int s8[8];
#pragma unroll
        for (int t = 0; t < 8; t++) {
          w8[t] = __shfl(wlane, t, 64);
          int pp = beg + i0 + ((t < m) ? t : (m - 1));
          s8[t] = srcs[pp];
        }
        ull uv[8];
#pragma unroll
        for (int t = 0; t < 8; t++)
          uv[t] = *(const ull*)(vv + (size_t)s8[t] * 256 + j0);
#pragma unroll
        for (int t = 0; t < 8; t++) {
          float ww = w8[t];
          a0 += ww * bf2f((unsigned short)uv[t]);
          a1 += ww * bf2f((unsigned short)(uv[t] >> 16));
          a2 += ww * bf2f((unsigned short)(uv[t] >> 32));
          a3 += ww * bf2f((unsigned short)(uv[t] >> 48));
        }
      }
      // reduce ubar partials (nonzero only in lanes 0-7): 3-stage xor + bcast
#pragma unroll
      for (int off = 1; off < 8; off <<= 1) {
        ub0 += __shfl_xor(ub0, off, 64); ub1 += __shfl_xor(ub1, off, 64);
        ub2 += __shfl_xor(ub2, off, 64); ub3 += __shfl_xor(ub3, off, 64);
        ub4 += __shfl_xor(ub4, off, 64); ub5 += __shfl_xor(ub5, off, 64);
      }
      ub0 = __shfl(ub0, 0, 64); ub1 = __shfl(ub1, 0, 64);
      ub2 = __shfl(ub2, 0, 64); ub3 = __shfl(ub3, 0, 64);
      ub4 = __shfl(ub4, 0, 64); ub5 = __shfl(ub5, 0, 64);
#pragma unroll
      for (int r = 0; r < 4; r++) {
        int d = j0 + r;
        e[r] = be_s[d]
             + we_s[d * 6 + 0] * ub0 + we_s[d * 6 + 1] * ub1 + we_s[d * 6 + 2] * ub2
             + we_s[d * 6 + 3] * ub3 + we_s[d * 6 + 4] * ub4 + we_s[d * 6 + 5] * ub5;
      }
    }
    float4 skv = *(const float4*)(skipv + (size_t)n * 256 + j0);
    float h0 = fmaxf(a0 + e[0] + skv.x, 0.f);
    float h1 = fmaxf(a1 + e[1] + skv.y, 0.f);
    float h2 = fmaxf(a2 + e[2] + skv.z, 0.f);
    float h3 = fmaxf(a3 + e[3] + skv.w, 0.f);
    if (mode == 0) {
      ull hv = (ull)f2bf(h0) | ((ull)f2bf(h1) << 16) | ((ull)f2bf(h2) << 32) | ((ull)f2bf(h3) << 48);
      // A-frag-order address (K=256): d=lane*4 -> ks=lane>>3, quad=(lane>>1)&3,
      // kj=(lane&1)*4; layout [n32][ks][half][lane'][kj]
      int n32 = n >> 5, lmn = n & 15, halfn = (n >> 4) & 1;
      int ks = lane >> 3, quadc = (lane >> 1) & 3, kjc = (lane & 1) * 4;
      size_t a = (((size_t)(n32 * 8 + ks)) * 2 + halfn) * 512 + (quadc * 16 + lmn) * 8 + kjc;
      *(ull*)(hout + a) = hv;
    } else {
      float4 o; o.x = h0; o.y = h1; o.z = h2; o.w = h3;
      *(float4*)(h_acc + (size_t)n * 256 + j0) = o;
    }
  }
}

// ---- P5: segmented pooling over sorted batch (contiguous node ranges) -----
__global__ __launch_bounds__(256) void pool_reduce(
    const float* __restrict__ hfin, const int* __restrict__ batch, int Nn,
    float* __restrict__ gap, unsigned int* __restrict__ gmp) {
  int g = blockIdx.x, s = blockIdx.y, t = threadIdx.x;
  __shared__ int st_s, en_s;
  if (t == 0) {
    int lo = 0, hi = Nn;
    while (lo < hi) { int mid = (lo + hi) >> 1; if (batch[mid] < g) lo = mid + 1; else hi = mid; }
    st_s = lo;
    lo = 0; hi = Nn;
    while (lo < hi) { int mid = (lo + hi) >> 1; if (batch[mid] < g + 1) lo = mid + 1; else hi = mid; }
    en_s = lo;
  }
  __syncthreads();
  int st = st_s, en = en_s;
  int len = en - st;
  if (len <= 0) return;
  int nsplit = gridDim.y;
  int chunk = (len + nsplit - 1) / nsplit;
  int a = st + s * chunk;
  int b = min(a + chunk, en);
  if (a >= b) return;
  float acc = 0.f, mx = 0.f;  // h >= 0 (relu)
  for (int n = a; n < b; n++) {
    float v = hfin[(size_t)n * 256 + t];
    acc += v;
    mx = fmaxf(mx, v);
  }
  atomicAdd(&gap[(size_t)g * 256 + t], acc);
  atomicMax(&gmp[(size_t)g * 256 + t], __float_as_uint(mx));
}

// ---- per-graph pooling finalize + 3-layer MLP + sigmoid -------------------
__global__ __launch_bounds__(256) void pool_mlp(
    const float* __restrict__ gap, const unsigned int* __restrict__ gmp,
    const int* __restrict__ batch, int Nn,
    const float* __restrict__ w1, const float* __restrict__ b1,
    const float* __restrict__ w2, const float* __restrict__ b2,
    const float* __restrict__ w3, const float* __restrict__ b3,
    float* __restrict__ out) {
  int g = blockIdx.x, t = threadIdx.x;
  __shared__ float r[512];
  __shared__ float o1[256];
  __shared__ float o2[128];
  __shared__ float red[256];
  __shared__ int cnt_s;
  if (t == 0) {
    int lo = 0, hi = Nn;
    while (lo < hi) { int mid = (lo + hi) >> 1; if (batch[mid] < g) lo = mid + 1; else hi = mid; }
    int st = lo;
    lo = 0; hi = Nn;
    while (lo < hi) { int mid = (lo + hi) >> 1; if (batch[mid] < g + 1) lo = mid + 1; else hi = mid; }
    cnt_s = lo - st;
  }
  __syncthreads();
  float inv = 1.f / fmaxf((float)cnt_s, 1.f);
  r[t] = gap[(size_t)g * 256 + t] * inv;
  r[256 + t] = __uint_as_float(gmp[(size_t)g * 256 + t]);
  __syncthreads();
  {
    float a = b1[t];
    const float* wr = w1 + (size_t)t * 512;
    for (int k = 0; k < 512; k++) a += wr[k] * r[k];
    o1[t] = fmaxf(a, 0.f);
  }
  __syncthreads();
  if (t < 128) {
    float a = b2[t];
    const float* wr = w2 + (size_t)t * 256;
    for (int k = 0; k < 256; k++) a += wr[k] * o1[k];
    o2[t] = fmaxf(a, 0.f);
  }
  __syncthreads();
  red[t] = (t < 128) ? w3[t] * o2[t] : 0.f;
  __syncthreads();
  for (int s = 128; s > 0; s >>= 1) {
    if (t < s) red[t] += red[t + s];
    __syncthreads();
  }
  if (t == 0) out[g] = 1.f / (1.f + expf(-(red[0] + b3[0])));
}

// ---------------------------------------------------------------------------
extern "C" void kernel_launch(void* const* d_in, const int* in_sizes, int n_in,
                              void* d_out, int out_size, void* d_ws, size_t ws_size,
                              hipStream_t stream) {
  const int* x_idx      = (const int*)d_in[0];
  const int* edge_index = (const int*)d_in[1];
  const float* eattr    = (const float*)d_in[2];
  const int* batch      = (const int*)d_in[3];
  const float* emb      = (const float*)d_in[4];
  const float* c1_wq = (const float*)d_in[5],  *c1_bq = (const float*)d_in[6];
  const float* c1_wk = (const float*)d_in[7],  *c1_bk = (const float*)d_in[8];
  const float* c1_wv = (const float*)d_in[9],  *c1_bv = (const float*)d_in[10];
  const float* c1_we = (const float*)d_in[11], *c1_be = (const float*)d_in[12];
  const float* c1_ws = (const float*)d_in[13], *c1_bs = (const float*)d_in[14];
  const float* c2_wq = (const float*)d_in[15], *c2_bq = (const float*)d_in[16];
  const float* c2_wk = (const float*)d_in[17], *c2_bk = (const float*)d_in[18];
  const float* c2_wv = (const float*)d_in[19], *c2_bv = (const float*)d_in[20];
  const float* c2_we = (const float*)d_in[21], *c2_be = (const float*)d_in[22];
  const float* c2_ws = (const float*)d_in[23], *c2_bs = (const float*)d_in[24];
  const float* w1 = (const float*)d_in[25], *b1 = (const float*)d_in[26];
  const float* w2 = (const float*)d_in[27], *b2 = (const float*)d_in[28];
  const float* w3 = (const float*)d_in[29], *b3 = (const float*)d_in[30];

  const int Nn = in_sizes[3];        // 50000
  const int Ee = in_sizes[1] / 2;    // 300000
  const int nrb = (Nn + 127) / 128;  // 391 row-blocks (gemm grid + padding)

  char* ws = (char*)d_ws;
  size_t off = 0;
  auto alloc = [&](size_t bytes) -> void* {
    void* p = ws + off;
    off += (bytes + 255) & ~(size_t)255;
    return p;
  };
  // xbf/h1bf padded to whole 128-row blocks (frag-order reads go to nrb*128)
  unsigned short* xbf   = (unsigned short*)alloc((size_t)nrb * 128 * 512 * 2);
  unsigned short* qbf   = (unsigned short*)alloc((size_t)Nn * 256 * 2);
  unsigned short* kbf   = (unsigned short*)alloc((size_t)Nn * 256 * 2);
  unsigned short* vbf   = (unsigned short*)alloc((size_t)Nn * 256 * 2);
  float*          skipf = (float*)alloc((size_t)Nn * 256 * 4);
  unsigned short* h1bf  = (unsigned short*)alloc((size_t)nrb * 128 * 256 * 2);
  unsigned short* Wcat1 = (unsigned short*)alloc((size_t)1024 * 512 * 2);
  float*          bcat1 = (float*)alloc(1024 * 4);
  unsigned short* Wcat2 = (unsigned short*)alloc((size_t)1024 * 256 * 2);
  float*          bcat2 = (float*)alloc(1024 * 4);
  int*            counts    = (int*)alloc((size_t)Nn * 4);
  int*            row_start = (int*)alloc((size_t)Nn * 4);
  int*            cursor    = (int*)alloc((size_t)Nn * 4);
  int*            srcs      = (int*)alloc((size_t)Ee * 4);
  int*            dsts      = (int*)alloc((size_t)Ee * 4);
  float*          ea_perm   = (float*)alloc((size_t)Ee * 6 * 4);
  float*          logits    = (float*)alloc((size_t)Ee * 4);   // stays RAW now
  float*          zc        = (float*)alloc((size_t)Nn * 8 * 4);
  int*            total     = (int*)alloc(256);
  float*          gap       = (float*)alloc((size_t)64 * 256 * 4);
  unsigned int*   gmp       = (unsigned int*)alloc((size_t)64 * 256 * 4);
  // h_acc (50k x 256 fp32 = 51.2 MB) ALIASES xbf (51.25 MB padded): xbf is
  // dead after gemm1; h_acc first touched by node_agg2 mode 1.
  float* h_acc = (float*)xbf;

  const int* srcA = edge_index;
  const int* dstA = edge_index + Ee;

  hipMemsetAsync(counts, 0, (size_t)Nn * 4, stream);
  hipMemsetAsync(total, 0, 4, stream);
  hipMemsetAsync(gap, 0, (size_t)64 * 256 * 4, stream);
  hipMemsetAsync(gmp, 0, (size_t)64 * 256 * 4, stream);

  pack_weights<<<(1024 * 512 + 255) / 256, 256, 0, stream>>>(
      c1_wq, c1_wk, c1_wv, c1_ws, c1_bq, c1_bk, c1_bv, c1_bs, Wcat1, bcat1, 9);
  pack_weights<<<(1024 * 256 + 255) / 256, 256, 0, stream>>>(
      c2_wq, c2_wk, c2_wv, c2_ws, c2_bq, c2_bk, c2_bv, c2_bs, Wcat2, bcat2, 8);
  embed_gather<<<((Nn * 512) + 255) / 256, 256, 0, stream>>>(x_idx, emb, xbf, Nn * 512);
  count_dst<<<(Ee + 255) / 256, 256, 0, stream>>>(dstA, counts, Ee);
  alloc_rows<<<(Nn + 255) / 256, 256, 0, stream>>>(counts, row_start, cursor, total, Nn);
  scatter_edges<<<(Ee + 255) / 256, 256, 0, stream>>>(dstA, srcA, eattr, cursor,
                                                      srcs, dsts, ea_perm, Ee);

  // XCD-aware gemm grid: 8 XCD groups x max-row-blocks-per-XCD x 16 col-tiles
  const int rbmax = nrb / 8 + ((nrb % 8) ? 1 : 0);
  const int ggrid = 8 * rbmax * 16;
  const int egrid = (Ee + 31) / 32;
  const int sgrid = (Nn + NPW * 4 - 1) / (NPW * 4);  // node-owned agg waves
  const int ngrid = (Nn + 3) / 4;

  // layer 1
  gemm_qkvs<512><<<ggrid, 256, 0, stream>>>(xbf, Wcat1, bcat1, qbf, kbf, vbf,
                                            skipf, Nn, nrb);
  node_prep<<<ngrid, 256, 0, stream>>>(qbf, c1_we, c1_be, zc, Nn);
  edge_logits<<<egrid, 256, 0, stream>>>(srcs, dsts, ea_perm, qbf, kbf, zc, Ee, logits);
  node_agg2<<<sgrid, 256, 0, stream>>>(srcs, row_start, counts, logits, vbf,
                                       ea_perm, skipf, c1_we, c1_be, Nn, 0,
                                       h1bf, nullptr);

  // layer 2
  gemm_qkvs<256><<<ggrid, 256, 0, stream>>>(h1bf, Wcat2, bcat2, qbf, kbf, vbf,
                                            skipf, Nn, nrb);
  node_prep<<<ngrid, 256, 0, stream>>>(qbf, c2_we, c2_be, zc, Nn);
  edge_logits<<<egrid, 256, 0, stream>>>(srcs, dsts, ea_perm, qbf, kbf, zc, Ee, logits);
  node_agg2<<<sgrid, 256, 0, stream>>>(srcs, row_start, counts, logits, vbf,
                                       ea_perm, skipf, c2_we, c2_be, Nn, 1,
                                       nullptr, h_acc);

  // segmented pooling (batch sorted -> contiguous ranges), then MLP
  dim3 pg(64, 16);
  pool_reduce<<<pg, 256, 0, stream>>>(h_acc, batch, Nn, gap, gmp);
  pool_mlp<<<64, 256, 0, stream>>>(gap, gmp, batch, Nn, w1, b1, w2, b2, w3, b3,
                                   (float*)d_out);
}

// Round 17
// 709.437 us; speedup vs baseline: 1.1621x; 1.0037x over previous
//
#include <hip/hip_runtime.h>

typedef unsigned long long ull;
typedef __bf16 bf16x8 __attribute__((ext_vector_type(8)));
typedef float f32x4 __attribute__((ext_vector_type(4)));

__device__ __forceinline__ float bf2f(unsigned short u) {
  union { unsigned int i; float f; } c; c.i = ((unsigned int)u) << 16; return c.f;
}
__device__ __forceinline__ unsigned short f2bf(float f) {
  union { float f; unsigned int i; } c; c.f = f;
  unsigned int u = c.i;
  u += 0x7fffu + ((u >> 16) & 1u);
  return (unsigned short)(u >> 16);
}

// ---- pack 4x [256,K] fp32 weights -> bf16 B-FRAGMENT-ORDER + bias concat --
__global__ __launch_bounds__(256) void pack_weights(
    const float* __restrict__ wq, const float* __restrict__ wk,
    const float* __restrict__ wv, const float* __restrict__ ws,
    const float* __restrict__ bq, const float* __restrict__ bk,
    const float* __restrict__ bv, const float* __restrict__ bs,
    unsigned short* __restrict__ Wcat, float* __restrict__ bcat, int logK) {
  int idx = blockIdx.x * 256 + threadIdx.x;
  if (idx < 1024) {
    int rr = idx >> 8, cc = idx & 255;
    const float* bp = (rr == 0) ? bq : (rr == 1) ? bk : (rr == 2) ? bv : bs;
    bcat[idx] = bp[cc];
  }
  int K = 1 << logK;
  if (idx >= (1024 << logK)) return;
  int kj = idx & 7;
  int lane = (idx >> 3) & 63;
  int rg = (idx >> 9) & 3;
  int ksbits = logK - 5;
  int ks = (idx >> 11) & ((1 << ksbits) - 1);
  int colt = idx >> (11 + ksbits);
  int quad = lane >> 4, lm = lane & 15;
  int o = colt * 64 + rg * 16 + lm;
  int k = ks * 32 + quad * 8 + kj;
  int rr = o >> 8, oo = o & 255;
  const float* wp = (rr == 0) ? wq : (rr == 1) ? wk : (rr == 2) ? wv : ws;
  Wcat[idx] = f2bf(wp[oo * K + k]);
}

// ---- embedding gather -> A-FRAGMENT-ORDER xbf (K=512) ---------------------
__global__ __launch_bounds__(256) void embed_gather(
    const int* __restrict__ x_idx, const float* __restrict__ emb,
    unsigned short* __restrict__ xbf, int total) {
  int idx = blockIdx.x * 256 + threadIdx.x;
  if (idx >= total) return;
  int n = idx >> 9, d = idx & 511, f = d >> 6, j = d & 63;
  int vi = x_idx[n * 8 + f];
  int n32 = n >> 5, lm = n & 15, half = (n >> 4) & 1;
  int ks = d >> 5, quad = (d >> 3) & 3, kj = d & 7;
  size_t a = (((size_t)(n32 * 16 + ks)) * 2 + half) * 512 + (quad * 16 + lm) * 8 + kj;
  xbf[a] = f2bf(emb[vi * 64 + j]);
}

// ---- CSR build ------------------------------------------------------------
__global__ __launch_bounds__(256) void count_dst(const int* __restrict__ dst,
                                                 int* __restrict__ counts, int E_) {
  int i = blockIdx.x * 256 + threadIdx.x;
  if (i < E_) atomicAdd(&counts[dst[i]], 1);
}

// NOTE: bases assigned by atomicAdd in arbitrary wave order -> row_start is
// a VALID CSR (disjoint, correct offsets) but NOT sorted by node index.
// No consumer may assume monotonicity (R11 bug).
__global__ __launch_bounds__(256) void alloc_rows(const int* __restrict__ counts,
                                                  int* __restrict__ row_start,
                                                  int* __restrict__ cursor,
                                                  int* __restrict__ total, int n) {
  int i = blockIdx.x * 256 + threadIdx.x;
  int lane = threadIdx.x & 63;
  int c = (i < n) ? counts[i] : 0;
  int incl = c;
#pragma unroll
  for (int off = 1; off < 64; off <<= 1) {
    int t = __shfl_up(incl, off, 64);
    if (lane >= off) incl += t;
  }
  int base = 0;
  if (lane == 63) base = atomicAdd(total, incl);
  base = __shfl(base, 63, 64);
  int st = base + incl - c;
  if (i < n) { row_start[i] = st; cursor[i] = st; }
}

// scatter edges into CSR order; materialize permuted src ids and attrs
__global__ __launch_bounds__(256) void scatter_edges(
    const int* __restrict__ dst, const int* __restrict__ srcA,
    const float* __restrict__ eattr, int* __restrict__ cursor,
    int* __restrict__ srcs, float* __restrict__ ea_perm, int E_) {
  int i = blockIdx.x * 256 + threadIdx.x;
  if (i >= E_) return;
  int d = dst[i];
  int p = atomicAdd(&cursor[d], 1);
  srcs[p] = srcA[i];
  const float* ea = eattr + (size_t)i * 6;
  float* eo = ea_perm + (size_t)p * 6;
  eo[0] = ea[0]; eo[1] = ea[1]; eo[2] = ea[2];
  eo[3] = ea[3]; eo[4] = ea[4]; eo[5] = ea[5];
}

// ---- fused QKVS GEMM: LDS-staged B, 8KB chunks double-buffered ------------
// (R16-proven: 128-row blocks, 32x64/wave, 16KB LDS, XCD remap.)
template <int K>
__global__ __launch_bounds__(256) void gemm_qkvs(
    const unsigned short* __restrict__ X, const unsigned short* __restrict__ W,
    const float* __restrict__ bcat,
    unsigned short* __restrict__ qout, unsigned short* __restrict__ kout,
    unsigned short* __restrict__ vout, float* __restrict__ sout,
    int Nn, int nrb) {
  __shared__ unsigned short Bs[2][4096];   // 2 x 8KB
  const int l = blockIdx.x;
  const int xcd = l & 7, j = l >> 3;
  const int q = nrb >> 3, r = nrb & 7;
  const int cnt = q + (xcd < r ? 1 : 0);
  const int lrb = j >> 4, colt = j & 15;
  if (lrb >= cnt) return;
  const int m_blk = xcd * q + min(xcd, r) + lrb;

  const int tid = threadIdx.x;
  const int wid = tid >> 6;
  const int lane = tid & 63;
  const int quad = lane >> 4, lm = lane & 15;
  const int m_base = m_blk * 128 + wid * 32;
  const int n_base = colt * 64;
  const size_t abase = (size_t)(m_blk * 4 + wid) * (K >> 5) * 1024 + lane * 8;
  const unsigned short* wchunk = W + (size_t)colt * (K >> 5) * 2048;
  const int nc = (K >> 5) >> 1;            // 64-k chunks (2 k-steps)
  f32x4 acc[2][4] = {};

  {
    bf16x8 st0 = *(const bf16x8*)(wchunk + 0 * 2048 + tid * 8);
    bf16x8 st1 = *(const bf16x8*)(wchunk + 1 * 2048 + tid * 8);
    *(bf16x8*)(&Bs[0][0 * 2048 + tid * 8]) = st0;
    *(bf16x8*)(&Bs[0][1 * 2048 + tid * 8]) = st1;
  }
  __syncthreads();

  for (int c = 0; c < nc; c++) {
    bf16x8 st0, st1;
    const bool pf = (c + 1 < nc);
    if (pf) {
      const unsigned short* wp = wchunk + (size_t)(c + 1) * 4096;
      st0 = *(const bf16x8*)(wp + 0 * 2048 + tid * 8);
      st1 = *(const bf16x8*)(wp + 1 * 2048 + tid * 8);
    }
    const unsigned short* bs = &Bs[c & 1][0];
#pragma unroll
    for (int s = 0; s < 2; s++) {
      const int ks = c * 2 + s;
      const unsigned short* ap = X + abase + (size_t)ks * 1024;
      const unsigned short* bp = bs + s * 2048 + lane * 8;
      bf16x8 a0 = *(const bf16x8*)(ap);
      bf16x8 a1 = *(const bf16x8*)(ap + 512);
      bf16x8 b0 = *(const bf16x8*)(bp);
      bf16x8 b1 = *(const bf16x8*)(bp + 512);
      bf16x8 b2 = *(const bf16x8*)(bp + 1024);
      bf16x8 b3 = *(const bf16x8*)(bp + 1536);
      acc[0][0] = __builtin_amdgcn_mfma_f32_16x16x32_bf16(a0, b0, acc[0][0], 0, 0, 0);
      acc[0][1] = __builtin_amdgcn_mfma_f32_16x16x32_bf16(a0, b1, acc[0][1], 0, 0, 0);
      acc[0][2] = __builtin_amdgcn_mfma_f32_16x16x32_bf16(a0, b2, acc[0][2], 0, 0, 0);
      acc[0][3] = __builtin_amdgcn_mfma_f32_16x16x32_bf16(a0, b3, acc[0][3], 0, 0, 0);
      acc[1][0] = __builtin_amdgcn_mfma_f32_16x16x32_bf16(a1, b0, acc[1][0], 0, 0, 0);
      acc[1][1] = __builtin_amdgcn_mfma_f32_16x16x32_bf16(a1, b1, acc[1][1], 0, 0, 0);
      acc[1][2] = __builtin_amdgcn_mfma_f32_16x16x32_bf16(a1, b2, acc[1][2], 0, 0, 0);
      acc[1][3] = __builtin_amdgcn_mfma_f32_16x16x32_bf16(a1, b3, acc[1][3], 0, 0, 0);
    }
    if (pf) {
      unsigned short* bw = &Bs[(c + 1) & 1][0];
      *(bf16x8*)(bw + 0 * 2048 + tid * 8) = st0;
      *(bf16x8*)(bw + 1 * 2048 + tid * 8) = st1;
    }
    __syncthreads();
  }
#pragma unroll
  for (int mi = 0; mi < 2; mi++) {
#pragma unroll
    for (int r2 = 0; r2 < 4; r2++) {
      int row = m_base + mi * 16 + quad * 4 + r2;
      if (row >= Nn) continue;
      size_t rb = (size_t)row * 256;
#pragma unroll
      for (int ni = 0; ni < 4; ni++) {
        int col = n_base + ni * 16 + lm;
        float v = acc[mi][ni][r2] + bcat[col];
        int reg = col >> 8, c2 = col & 255;
        if (reg == 0)       qout[rb + c2] = f2bf(v * 0.0625f);
        else if (reg == 1)  kout[rb + c2] = f2bf(v);
        else if (reg == 2)  vout[rb + c2] = f2bf(v);
        else                sout[rb + c2] = v;
      }
    }
  }
}

__device__ __forceinline__ float dot4(ull uq, ull uk) {
  return bf2f((unsigned short)uq) * bf2f((unsigned short)uk)
       + bf2f((unsigned short)(uq >> 16)) * bf2f((unsigned short)(uk >> 16))
       + bf2f((unsigned short)(uq >> 32)) * bf2f((unsigned short)(uk >> 32))
       + bf2f((unsigned short)(uq >> 48)) * bf2f((unsigned short)(uk >> 48));
}

#define SEL8_F(a, t) ((t)==0?(a)[0]:(t)==1?(a)[1]:(t)==2?(a)[2]:(t)==3?(a)[3]:(t)==4?(a)[4]:(t)==5?(a)[5]:(t)==6?(a)[6]:(a)[7])

// ---- FULLY-FUSED TransformerConv aggregation ------------------------------
// Wave w owns nodes [8w, 8w+8) by NODE INDEX. Per owned node:
//   0) q[n] -> registers; z = We^T q, c = q.be in-register (butterfly)
//   1) pass 1: gather k[src] 8-deep, logit = q.k + z.u + c -> per-wave LDS
//   2) softmax stats (max, sum-exp) over LDS logits
//   3) pass 2: gather v[src] 8-deep, inline weights, ubar in-register
//   4) epilogue h = relu(sum + We*ubar + be*[cnt>0] + skip), ONE store
// Replaces node_prep + edge_logits + node_agg2 (4 launches/iter saved);
// zc and logits buffers eliminated. LDS logit cap 128 (max degree ~30
// for this fixed multinomial graph; mean 6).
// mode 0: write h bf16 in A-FRAGMENT-ORDER (gemm2 input).
// mode 1: write h fp32 to h_acc (pool_reduce input). All n<Nn written.
#define NPW 8
__global__ __launch_bounds__(256) void tconv_fused(
    const int* __restrict__ srcs, const int* __restrict__ row_start,
    const int* __restrict__ counts,
    const unsigned short* __restrict__ qv, const unsigned short* __restrict__ kv,
    const unsigned short* __restrict__ vv, const float* __restrict__ ea_perm,
    const float* __restrict__ skipv,
    const float* __restrict__ we, const float* __restrict__ be,
    int Nn, int mode,
    unsigned short* __restrict__ hout, float* __restrict__ h_acc) {
  __shared__ float we_s[1536];
  __shared__ float be_s[256];
  __shared__ float lgt[4][128];
  for (int i = threadIdx.x; i < 1536; i += 256) we_s[i] = we[i];
  be_s[threadIdx.x] = be[threadIdx.x];
  __syncthreads();
  int wid = threadIdx.x >> 6;
  int lane = threadIdx.x & 63;
  int wave = blockIdx.x * 4 + wid;
  int n0 = wave * NPW;
  if (n0 >= Nn) return;
  int n1 = min(n0 + NPW, Nn);
  int j0 = lane * 4;
  float* mylgt = lgt[wid];
  for (int n = n0; n < n1; n++) {
    int cnt = counts[n];
    float a0 = 0.f, a1 = 0.f, a2 = 0.f, a3 = 0.f;
    float e[4] = {0.f, 0.f, 0.f, 0.f};
    if (cnt > 0) {
      int beg = row_start[n];
      // q row -> registers; z = We^T q (6) + c = q.be, butterfly-reduced
      ull uqr = *(const ull*)(qv + (size_t)n * 256 + j0);
      float q0 = bf2f((unsigned short)uqr), q1 = bf2f((unsigned short)(uqr >> 16));
      float q2 = bf2f((unsigned short)(uqr >> 32)), q3 = bf2f((unsigned short)(uqr >> 48));
      float z[7];
#pragma unroll
      for (int t = 0; t < 6; t++) {
        z[t] = we_s[(j0 + 0) * 6 + t] * q0 + we_s[(j0 + 1) * 6 + t] * q1
             + we_s[(j0 + 2) * 6 + t] * q2 + we_s[(j0 + 3) * 6 + t] * q3;
      }
      z[6] = be_s[j0] * q0 + be_s[j0 + 1] * q1 + be_s[j0 + 2] * q2 + be_s[j0 + 3] * q3;
#pragma unroll
      for (int off = 32; off > 0; off >>= 1) {
#pragma unroll
        for (int t = 0; t < 7; t++) z[t] += __shfl_xor(z[t], off, 64);
      }
      // pass 1: logits -> LDS
      for (int i0 = 0; i0 < cnt; i0 += 8) {
        int m = cnt - i0; if (m > 8) m = 8;
        int s8[8];
#pragma unroll
        for (int t = 0; t < 8; t++) {
          int pp = beg + i0 + ((t < m) ? t : (m - 1));
          s8[t] = srcs[pp];
        }
        ull uk[8];
#pragma unroll
        for (int t = 0; t < 8; t++)
          uk[t] = *(const ull*)(kv + (size_t)s8[t] * 256 + j0);
        float pv[8];
#pragma unroll
        for (int t = 0; t < 8; t++) pv[t] = dot4(uqr, uk[t]);
#pragma unroll
        for (int off = 32; off > 0; off >>= 1) {
#pragma unroll
          for (int t = 0; t < 8; t++) pv[t] += __shfl_xor(pv[t], off, 64);
        }
        if (lane < m) {
          int myp = beg + i0 + lane;
          const float* u = ea_perm + (size_t)myp * 6;
          float zd = z[0] * u[0] + z[1] * u[1] + z[2] * u[2]
                   + z[3] * u[3] + z[4] * u[4] + z[5] * u[5] + z[6];
          mylgt[i0 + lane] = SEL8_F(pv, lane) + zd;
        }
      }
      // softmax stats over LDS logits
      float lmx = -INFINITY;
      for (int b = lane; b < cnt; b += 64) lmx = fmaxf(lmx, mylgt[b]);
#pragma unroll
      for (int off = 32; off > 0; off >>= 1) lmx = fmaxf(lmx, __shfl_xor(lmx, off, 64));
      float se = 0.f;
      for (int b = lane; b < cnt; b += 64) se += __expf(mylgt[b] - lmx);
#pragma unroll
      for (int off = 32; off > 0; off >>= 1) se += __shfl_xor(se, off, 64);
      float inv = 1.f / se;
      // pass 2: weighted v gather + ubar
      float ub0 = 0.f, ub1 = 0.f, ub2 = 0.f, ub3 = 0.f, ub4 = 0.f, ub5 = 0.f;
      for (int i0 = 0; i0 < cnt; i0 += 8) {
        int m = cnt - i0; if (m > 8) m = 8;
        float wlane = 0.f;
        if (lane < m) {
          int myp = beg + i0 + lane;
          wlane = __expf(mylgt[i0 + lane] - lmx) * inv;
          const float* up = ea_perm + (size_t)myp * 6;
          ub0 += wlane * up[0]; ub1 += wlane * up[1]; ub2 += wlane * up[2];
          ub3 += wlane * up[3]; ub4 += wlane * up[4]; ub5 += wlane * up[5];
        }
        float w8[8];
        int s8[8];
#pragma unroll
        for (int t = 0; t < 8; t++) {
          w8[t] = __shfl(wlane, t, 64);
          int pp = beg + i0 + ((t < m) ? t : (m - 1));
          s8[t] = srcs[pp];
        }
        ull uv[8];
#pragma unroll
        for (int t = 0; t < 8; t++)
          uv[t] = *(const ull*)(vv + (size_t)s8[t] * 256 + j0);
#pragma unroll
        for (int t = 0; t < 8; t++) {
          float ww = w8[t];
          a0 += ww * bf2f((unsigned short)uv[t]);
          a1 += ww * bf2f((unsigned short)(uv[t] >> 16));
          a2 += ww * bf2f((unsigned short)(uv[t] >> 32));
          a3 += ww * bf2f((unsigned short)(uv[t] >> 48));
        }
      }
#pragma unroll
      for (int off = 1; off < 8; off <<= 1) {
        ub0 += __shfl_xor(ub0, off, 64); ub1 += __shfl_xor(ub1, off, 64);
        ub2 += __shfl_xor(ub2, off, 64); ub3 += __shfl_xor(ub3, off, 64);
        ub4 += __shfl_xor(ub4, off, 64); ub5 += __shfl_xor(ub5, off, 64);
      }
      ub0 = __shfl(ub0, 0, 64); ub1 = __shfl(ub1, 0, 64);
      ub2 = __shfl(ub2, 0, 64); ub3 = __shfl(ub3, 0, 64);
      ub4 = __shfl(ub4, 0, 64); ub5 = __shfl(ub5, 0, 64);
#pragma unroll
      for (int r = 0; r < 4; r++) {
        int d = j0 + r;
        e[r] = be_s[d]
             + we_s[d * 6 + 0] * ub0 + we_s[d * 6 + 1] * ub1 + we_s[d * 6 + 2] * ub2
             + we_s[d * 6 + 3] * ub3 + we_s[d * 6 + 4] * ub4 + we_s[d * 6 + 5] * ub5;
      }
    }
    float4 skv = *(const float4*)(skipv + (size_t)n * 256 + j0);
    float h0 = fmaxf(a0 + e[0] + skv.x, 0.f);
    float h1 = fmaxf(a1 + e[1] + skv.y, 0.f);
    float h2 = fmaxf(a2 + e[2] + skv.z, 0.f);
    float h3 = fmaxf(a3 + e[3] + skv.w, 0.f);
    if (mode == 0) {
      ull hv = (ull)f2bf(h0) | ((ull)f2bf(h1) << 16) | ((ull)f2bf(h2) << 32) | ((ull)f2bf(h3) << 48);
      // A-frag-order address (K=256): d=lane*4 -> ks=lane>>3, quad=(lane>>1)&3,
      // kj=(lane&1)*4; layout [n32][ks][half][lane'][kj]
      int n32 = n >> 5, lmn = n & 15, halfn = (n >> 4) & 1;
      int ks = lane >> 3, quadc = (lane >> 1) & 3, kjc = (lane & 1) * 4;
      size_t a = (((size_t)(n32 * 8 + ks)) * 2 + halfn) * 512 + (quadc * 16 + lmn) * 8 + kjc;
      *(ull*)(hout + a) = hv;
    } else {
      float4 o; o.x = h0; o.y = h1; o.z = h2; o.w = h3;
      *(float4*)(h_acc + (size_t)n * 256 + j0) = o;
    }
  }
}

// ---- P5: segmented pooling over sorted batch (contiguous node ranges) -----
__global__ __launch_bounds__(256) void pool_reduce(
    const float* __restrict__ hfin, const int* __restrict__ batch, int Nn,
    float* __restrict__ gap, unsigned int* __restrict__ gmp) {
  int g = blockIdx.x, s = blockIdx.y, t = threadIdx.x;
  __shared__ int st_s, en_s;
  if (t == 0) {
    int lo = 0, hi = Nn;
    while (lo < hi) { int mid = (lo + hi) >> 1; if (batch[mid] < g) lo = mid + 1; else hi = mid; }
    st_s = lo;
    lo = 0; hi = Nn;
    while (lo < hi) { int mid = (lo + hi) >> 1; if (batch[mid] < g + 1) lo = mid + 1; else hi = mid; }
    en_s = lo;
  }
  __syncthreads();
  int st = st_s, en = en_s;
  int len = en - st;
  if (len <= 0) return;
  int nsplit = gridDim.y;
  int chunk = (len + nsplit - 1) / nsplit;
  int a = st + s * chunk;
  int b = min(a + chunk, en);
  if (a >= b) return;
  float acc = 0.f, mx = 0.f;  // h >= 0 (relu)
  for (int n = a; n < b; n++) {
    float v = hfin[(size_t)n * 256 + t];
    acc += v;
    mx = fmaxf(mx, v);
  }
  atomicAdd(&gap[(size_t)g * 256 + t], acc);
  atomicMax(&gmp[(size_t)g * 256 + t], __float_as_uint(mx));
}

// ---- per-graph pooling finalize + 3-layer MLP + sigmoid -------------------
__global__ __launch_bounds__(256) void pool_mlp(
    const float* __restrict__ gap, const unsigned int* __restrict__ gmp,
    const int* __restrict__ batch, int Nn,
    const float* __restrict__ w1, const float* __restrict__ b1,
    const float* __restrict__ w2, const float* __restrict__ b2,
    const float* __restrict__ w3, const float* __restrict__ b3,
    float* __restrict__ out) {
  int g = blockIdx.x, t = threadIdx.x;
  __shared__ float r[512];
  __shared__ float o1[256];
  __shared__ float o2[128];
  __shared__ float red[256];
  __shared__ int cnt_s;
  if (t == 0) {
    int lo = 0, hi = Nn;
    while (lo < hi) { int mid = (lo + hi) >> 1; if (batch[mid] < g) lo = mid + 1; else hi = mid; }
    int st = lo;
    lo = 0; hi = Nn;
    while (lo < hi) { int mid = (lo + hi) >> 1; if (batch[mid] < g + 1) lo = mid + 1; else hi = mid; }
    cnt_s = lo - st;
  }
  __syncthreads();
  float inv = 1.f / fmaxf((float)cnt_s, 1.f);
  r[t] = gap[(size_t)g * 256 + t] * inv;
  r[256 + t] = __uint_as_float(gmp[(size_t)g * 256 + t]);
  __syncthreads();
  {
    float a = b1[t];
    const float* wr = w1 + (size_t)t * 512;
    for (int k = 0; k < 512; k++) a += wr[k] * r[k];
    o1[t] = fmaxf(a, 0.f);
  }
  __syncthreads();
  if (t < 128) {
    float a = b2[t];
    const float* wr = w2 + (size_t)t * 256;
    for (int k = 0; k < 256; k++) a += wr[k] * o1[k];
    o2[t] = fmaxf(a, 0.f);
  }
  __syncthreads();
  red[t] = (t < 128) ? w3[t] * o2[t] : 0.f;
  __syncthreads();
  for (int s = 128; s > 0; s >>= 1) {
    if (t < s) red[t] += red[t + s];
    __syncthreads();
  }
  if (t == 0) out[g] = 1.f / (1.f + expf(-(red[0] + b3[0])));
}

// ---------------------------------------------------------------------------
extern "C" void kernel_launch(void* const* d_in, const int* in_sizes, int n_in,
                              void* d_out, int out_size, void* d_ws, size_t ws_size,
                              hipStream_t stream) {
  const int* x_idx      = (const int*)d_in[0];
  const int* edge_index = (const int*)d_in[1];
  const float* eattr    = (const float*)d_in[2];
  const int* batch      = (const int*)d_in[3];
  const float* emb      = (const float*)d_in[4];
  const float* c1_wq = (const float*)d_in[5],  *c1_bq = (const float*)d_in[6];
  const float* c1_wk = (const float*)d_in[7],  *c1_bk = (const float*)d_in[8];
  const float* c1_wv = (const float*)d_in[9],  *c1_bv = (const float*)d_in[10];
  const float* c1_we = (const float*)d_in[11], *c1_be = (const float*)d_in[12];
  const float* c1_ws = (const float*)d_in[13], *c1_bs = (const float*)d_in[14];
  const float* c2_wq = (const float*)d_in[15], *c2_bq = (const float*)d_in[16];
  const float* c2_wk = (const float*)d_in[17], *c2_bk = (const float*)d_in[18];
  const float* c2_wv = (const float*)d_in[19], *c2_bv = (const float*)d_in[20];
  const float* c2_we = (const float*)d_in[21], *c2_be = (const float*)d_in[22];
  const float* c2_ws = (const float*)d_in[23], *c2_bs = (const float*)d_in[24];
  const float* w1 = (const float*)d_in[25], *b1 = (const float*)d_in[26];
  const float* w2 = (const float*)d_in[27], *b2 = (const float*)d_in[28];
  const float* w3 = (const float*)d_in[29], *b3 = (const float*)d_in[30];

  const int Nn = in_sizes[3];        // 50000
  const int Ee = in_sizes[1] / 2;    // 300000
  const int nrb = (Nn + 127) / 128;  // 391 row-blocks (gemm grid + padding)

  char* ws = (char*)d_ws;
  size_t off = 0;
  auto alloc = [&](size_t bytes) -> void* {
    void* p = ws + off;
    off += (bytes + 255) & ~(size_t)255;
    return p;
  };
  // xbf/h1bf padded to whole 128-row blocks (frag-order reads go to nrb*128)
  unsigned short* xbf   = (unsigned short*)alloc((size_t)nrb * 128 * 512 * 2);
  unsigned short* qbf   = (unsigned short*)alloc((size_t)Nn * 256 * 2);
  unsigned short* kbf   = (unsigned short*)alloc((size_t)Nn * 256 * 2);
  unsigned short* vbf   = (unsigned short*)alloc((size_t)Nn * 256 * 2);
  float*          skipf = (float*)alloc((size_t)Nn * 256 * 4);
  unsigned short* h1bf  = (unsigned short*)alloc((size_t)nrb * 128 * 256 * 2);
  unsigned short* Wcat1 = (unsigned short*)alloc((size_t)1024 * 512 * 2);
  float*          bcat1 = (float*)alloc(1024 * 4);
  unsigned short* Wcat2 = (unsigned short*)alloc((size_t)1024 * 256 * 2);
  float*          bcat2 = (float*)alloc(1024 * 4);
  int*            counts    = (int*)alloc((size_t)Nn * 4);
  int*            row_start = (int*)alloc((size_t)Nn * 4);
  int*            cursor    = (int*)alloc((size_t)Nn * 4);
  int*            srcs      = (int*)alloc((size_t)Ee * 4);
  float*          ea_perm   = (float*)alloc((size_t)Ee * 6 * 4);
  int*            total     = (int*)alloc(256);
  float*          gap       = (float*)alloc((size_t)64 * 256 * 4);
  unsigned int*   gmp       = (unsigned int*)alloc((size_t)64 * 256 * 4);
  // h_acc (50k x 256 fp32 = 51.2 MB) ALIASES xbf (51.25 MB padded): xbf is
  // dead after gemm1; h_acc first touched by tconv_fused mode 1.
  float* h_acc = (float*)xbf;

  const int* srcA = edge_index;
  const int* dstA = edge_index + Ee;

  hipMemsetAsync(counts, 0, (size_t)Nn * 4, stream);
  hipMemsetAsync(total, 0, 4, stream);
  hipMemsetAsync(gap, 0, (size_t)64 * 256 * 4, stream);
  hipMemsetAsync(gmp, 0, (size_t)64 * 256 * 4, stream);

  pack_weights<<<(1024 * 512 + 255) / 256, 256, 0, stream>>>(
      c1_wq, c1_wk, c1_wv, c1_ws, c1_bq, c1_bk, c1_bv, c1_bs, Wcat1, bcat1, 9);
  pack_weights<<<(1024 * 256 + 255) / 256, 256, 0, stream>>>(
      c2_wq, c2_wk, c2_wv, c2_ws, c2_bq, c2_bk, c2_bv, c2_bs, Wcat2, bcat2, 8);
  embed_gather<<<((Nn * 512) + 255) / 256, 256, 0, stream>>>(x_idx, emb, xbf, Nn * 512);
  count_dst<<<(Ee + 255) / 256, 256, 0, stream>>>(dstA, counts, Ee);
  alloc_rows<<<(Nn + 255) / 256, 256, 0, stream>>>(counts, row_start, cursor, total, Nn);
  scatter_edges<<<(Ee + 255) / 256, 256, 0, stream>>>(dstA, srcA, eattr, cursor,
                                                      srcs, ea_perm, Ee);

  // XCD-aware gemm grid: 8 XCD groups x max-row-blocks-per-XCD x 16 col-tiles
  const int rbmax = nrb / 8 + ((nrb % 8) ? 1 : 0);
  const int ggrid = 8 * rbmax * 16;
  const int sgrid = (Nn + NPW * 4 - 1) / (NPW * 4);  // node-owned fused waves

  // layer 1
  gemm_qkvs<512><<<ggrid, 256, 0, stream>>>(xbf, Wcat1, bcat1, qbf, kbf, vbf,
                                            skipf, Nn, nrb);
  tconv_fused<<<sgrid, 256, 0, stream>>>(srcs, row_start, counts, qbf, kbf, vbf,
                                         ea_perm, skipf, c1_we, c1_be, Nn, 0,
                                         h1bf, nullptr);

  // layer 2
  gemm_qkvs<256><<<ggrid, 256, 0, stream>>>(h1bf, Wcat2, bcat2, qbf, kbf, vbf,
                                            skipf, Nn, nrb);
  tconv_fused<<<sgrid, 256, 0, stream>>>(srcs, row_start, counts, qbf, kbf, vbf,
                                         ea_perm, skipf, c2_we, c2_be, Nn, 1,
                                         nullptr, h_acc);

  // segmented pooling (batch sorted -> contiguous ranges), then MLP
  dim3 pg(64, 16);
  pool_reduce<<<pg, 256, 0, stream>>>(h_acc, batch, Nn, gap, gmp);
  pool_mlp<<<64, 256, 0, stream>>>(gap, gmp, batch, Nn, w1, b1, w2, b2, w3, b3,
                                   (float*)d_out);
}

// Round 18
// 699.352 us; speedup vs baseline: 1.1788x; 1.0144x over previous
//
#include <hip/hip_runtime.h>

typedef unsigned long long ull;
typedef __bf16 bf16x8 __attribute__((ext_vector_type(8)));
typedef float f32x4 __attribute__((ext_vector_type(4)));

__device__ __forceinline__ float bf2f(unsigned short u) {
  union { unsigned int i; float f; } c; c.i = ((unsigned int)u) << 16; return c.f;
}
__device__ __forceinline__ unsigned short f2bf(float f) {
  union { float f; unsigned int i; } c; c.f = f;
  unsigned int u = c.i;
  u += 0x7fffu + ((u >> 16) & 1u);
  return (unsigned short)(u >> 16);
}

// ---- pack 4x [256,K] fp32 weights -> bf16 B-FRAGMENT-ORDER + bias concat --
__global__ __launch_bounds__(256) void pack_weights(
    const float* __restrict__ wq, const float* __restrict__ wk,
    const float* __restrict__ wv, const float* __restrict__ ws,
    const float* __restrict__ bq, const float* __restrict__ bk,
    const float* __restrict__ bv, const float* __restrict__ bs,
    unsigned short* __restrict__ Wcat, float* __restrict__ bcat, int logK) {
  int idx = blockIdx.x * 256 + threadIdx.x;
  if (idx < 1024) {
    int rr = idx >> 8, cc = idx & 255;
    const float* bp = (rr == 0) ? bq : (rr == 1) ? bk : (rr == 2) ? bv : bs;
    bcat[idx] = bp[cc];
  }
  int K = 1 << logK;
  if (idx >= (1024 << logK)) return;
  int kj = idx & 7;
  int lane = (idx >> 3) & 63;
  int rg = (idx >> 9) & 3;
  int ksbits = logK - 5;
  int ks = (idx >> 11) & ((1 << ksbits) - 1);
  int colt = idx >> (11 + ksbits);
  int quad = lane >> 4, lm = lane & 15;
  int o = colt * 64 + rg * 16 + lm;
  int k = ks * 32 + quad * 8 + kj;
  int rr = o >> 8, oo = o & 255;
  const float* wp = (rr == 0) ? wq : (rr == 1) ? wk : (rr == 2) ? wv : ws;
  Wcat[idx] = f2bf(wp[oo * K + k]);
}

// ---- embedding gather -> A-FRAGMENT-ORDER xbf (K=512) ---------------------
__global__ __launch_bounds__(256) void embed_gather(
    const int* __restrict__ x_idx, const float* __restrict__ emb,
    unsigned short* __restrict__ xbf, int total) {
  int idx = blockIdx.x * 256 + threadIdx.x;
  if (idx >= total) return;
  int n = idx >> 9, d = idx & 511, f = d >> 6, j = d & 63;
  int vi = x_idx[n * 8 + f];
  int n32 = n >> 5, lm = n & 15, half = (n >> 4) & 1;
  int ks = d >> 5, quad = (d >> 3) & 3, kj = d & 7;
  size_t a = (((size_t)(n32 * 16 + ks)) * 2 + half) * 512 + (quad * 16 + lm) * 8 + kj;
  xbf[a] = f2bf(emb[vi * 64 + j]);
}

// ---- CSR build ------------------------------------------------------------
__global__ __launch_bounds__(256) void count_dst(const int* __restrict__ dst,
                                                 int* __restrict__ counts, int E_) {
  int i = blockIdx.x * 256 + threadIdx.x;
  if (i < E_) atomicAdd(&counts[dst[i]], 1);
}

// NOTE: bases assigned by atomicAdd in arbitrary wave order -> row_start is
// a VALID CSR (disjoint, correct offsets) but NOT sorted by node index.
// No consumer may assume monotonicity (R11 bug).
__global__ __launch_bounds__(256) void alloc_rows(const int* __restrict__ counts,
                                                  int* __restrict__ row_start,
                                                  int* __restrict__ cursor,
                                                  int* __restrict__ total, int n) {
  int i = blockIdx.x * 256 + threadIdx.x;
  int lane = threadIdx.x & 63;
  int c = (i < n) ? counts[i] : 0;
  int incl = c;
#pragma unroll
  for (int off = 1; off < 64; off <<= 1) {
    int t = __shfl_up(incl, off, 64);
    if (lane >= off) incl += t;
  }
  int base = 0;
  if (lane == 63) base = atomicAdd(total, incl);
  base = __shfl(base, 63, 64);
  int st = base + incl - c;
  if (i < n) { row_start[i] = st; cursor[i] = st; }
}

// scatter edges into CSR order; materialize permuted src ids and attrs
__global__ __launch_bounds__(256) void scatter_edges(
    const int* __restrict__ dst, const int* __restrict__ srcA,
    const float* __restrict__ eattr, int* __restrict__ cursor,
    int* __restrict__ srcs, float* __restrict__ ea_perm, int E_) {
  int i = blockIdx.x * 256 + threadIdx.x;
  if (i >= E_) return;
  int d = dst[i];
  int p = atomicAdd(&cursor[d], 1);
  srcs[p] = srcA[i];
  const float* ea = eattr + (size_t)i * 6;
  float* eo = ea_perm + (size_t)p * 6;
  eo[0] = ea[0]; eo[1] = ea[1]; eo[2] = ea[2];
  eo[3] = ea[3]; eo[4] = ea[4]; eo[5] = ea[5];
}

// ---- fused QKVS GEMM: LDS-staged B, 8KB chunks double-buffered ------------
// (R16-proven: 128-row blocks, 32x64/wave, 16KB LDS, XCD remap.)
template <int K>
__global__ __launch_bounds__(256) void gemm_qkvs(
    const unsigned short* __restrict__ X, const unsigned short* __restrict__ W,
    const float* __restrict__ bcat,
    unsigned short* __restrict__ qout, unsigned short* __restrict__ kout,
    unsigned short* __restrict__ vout, float* __restrict__ sout,
    int Nn, int nrb) {
  __shared__ unsigned short Bs[2][4096];   // 2 x 8KB
  const int l = blockIdx.x;
  const int xcd = l & 7, j = l >> 3;
  const int q = nrb >> 3, r = nrb & 7;
  const int cnt = q + (xcd < r ? 1 : 0);
  const int lrb = j >> 4, colt = j & 15;
  if (lrb >= cnt) return;
  const int m_blk = xcd * q + min(xcd, r) + lrb;

  const int tid = threadIdx.x;
  const int wid = tid >> 6;
  const int lane = tid & 63;
  const int quad = lane >> 4, lm = lane & 15;
  const int m_base = m_blk * 128 + wid * 32;
  const int n_base = colt * 64;
  const size_t abase = (size_t)(m_blk * 4 + wid) * (K >> 5) * 1024 + lane * 8;
  const unsigned short* wchunk = W + (size_t)colt * (K >> 5) * 2048;
  const int nc = (K >> 5) >> 1;            // 64-k chunks (2 k-steps)
  f32x4 acc[2][4] = {};

  {
    bf16x8 st0 = *(const bf16x8*)(wchunk + 0 * 2048 + tid * 8);
    bf16x8 st1 = *(const bf16x8*)(wchunk + 1 * 2048 + tid * 8);
    *(bf16x8*)(&Bs[0][0 * 2048 + tid * 8]) = st0;
    *(bf16x8*)(&Bs[0][1 * 2048 + tid * 8]) = st1;
  }
  __syncthreads();

  for (int c = 0; c < nc; c++) {
    bf16x8 st0, st1;
    const bool pf = (c + 1 < nc);
    if (pf) {
      const unsigned short* wp = wchunk + (size_t)(c + 1) * 4096;
      st0 = *(const bf16x8*)(wp + 0 * 2048 + tid * 8);
      st1 = *(const bf16x8*)(wp + 1 * 2048 + tid * 8);
    }
    const unsigned short* bs = &Bs[c & 1][0];
#pragma unroll
    for (int s = 0; s < 2; s++) {
      const int ks = c * 2 + s;
      const unsigned short* ap = X + abase + (size_t)ks * 1024;
      const unsigned short* bp = bs + s * 2048 + lane * 8;
      bf16x8 a0 = *(const bf16x8*)(ap);
      bf16x8 a1 = *(const bf16x8*)(ap + 512);
      bf16x8 b0 = *(const bf16x8*)(bp);
      bf16x8 b1 = *(const bf16x8*)(bp + 512);
      bf16x8 b2 = *(const bf16x8*)(bp + 1024);
      bf16x8 b3 = *(const bf16x8*)(bp + 1536);
      acc[0][0] = __builtin_amdgcn_mfma_f32_16x16x32_bf16(a0, b0, acc[0][0], 0, 0, 0);
      acc[0][1] = __builtin_amdgcn_mfma_f32_16x16x32_bf16(a0, b1, acc[0][1], 0, 0, 0);
      acc[0][2] = __builtin_amdgcn_mfma_f32_16x16x32_bf16(a0, b2, acc[0][2], 0, 0, 0);
      acc[0][3] = __builtin_amdgcn_mfma_f32_16x16x32_bf16(a0, b3, acc[0][3], 0, 0, 0);
      acc[1][0] = __builtin_amdgcn_mfma_f32_16x16x32_bf16(a1, b0, acc[1][0], 0, 0, 0);
      acc[1][1] = __builtin_amdgcn_mfma_f32_16x16x32_bf16(a1, b1, acc[1][1], 0, 0, 0);
      acc[1][2] = __builtin_amdgcn_mfma_f32_16x16x32_bf16(a1, b2, acc[1][2], 0, 0, 0);
      acc[1][3] = __builtin_amdgcn_mfma_f32_16x16x32_bf16(a1, b3, acc[1][3], 0, 0, 0);
    }
    if (pf) {
      unsigned short* bw = &Bs[(c + 1) & 1][0];
      *(bf16x8*)(bw + 0 * 2048 + tid * 8) = st0;
      *(bf16x8*)(bw + 1 * 2048 + tid * 8) = st1;
    }
    __syncthreads();
  }
#pragma unroll
  for (int mi = 0; mi < 2; mi++) {
#pragma unroll
    for (int r2 = 0; r2 < 4; r2++) {
      int row = m_base + mi * 16 + quad * 4 + r2;
      if (row >= Nn) continue;
      size_t rb = (size_t)row * 256;
#pragma unroll
      for (int ni = 0; ni < 4; ni++) {
        int col = n_base + ni * 16 + lm;
        float v = acc[mi][ni][r2] + bcat[col];
        int reg = col >> 8, c2 = col & 255;
        if (reg == 0)       qout[rb + c2] = f2bf(v * 0.0625f);
        else if (reg == 1)  kout[rb + c2] = f2bf(v);
        else if (reg == 2)  vout[rb + c2] = f2bf(v);
        else                sout[rb + c2] = v;
      }
    }
  }
}

__device__ __forceinline__ float dot4(ull uq, ull uk) {
  return bf2f((unsigned short)uq) * bf2f((unsigned short)uk)
       + bf2f((unsigned short)(uq >> 16)) * bf2f((unsigned short)(uk >> 16))
       + bf2f((unsigned short)(uq >> 32)) * bf2f((unsigned short)(uk >> 32))
       + bf2f((unsigned short)(uq >> 48)) * bf2f((unsigned short)(uk >> 48));
}

#define SEL8_F(a, t) ((t)==0?(a)[0]:(t)==1?(a)[1]:(t)==2?(a)[2]:(t)==3?(a)[3]:(t)==4?(a)[4]:(t)==5?(a)[5]:(t)==6?(a)[6]:(a)[7])

// ---- FULLY-FUSED TransformerConv, SINGLE-PASS online softmax --------------
// Wave w owns nodes [4w, 4w+4) by NODE INDEX. Per owned node:
//   0) q[n] -> registers; z = We^T q, c = q.be in-register (butterfly)
//   1) ONE pass over edges, 8 at a time: gather k AND v together (16 loads
//      in flight), logits via butterfly, ONLINE softmax rescale of the
//      running v-sum / weight-sum / ubar partials. No LDS logits, no
//      second pass, no bank conflicts.
//   2) epilogue h = relu(sum/S + We*(ubar/S) + be*[cnt>0] + skip), ONE store
// mode 0: write h bf16 in A-FRAGMENT-ORDER (gemm2 input).
// mode 1: write h fp32 to h_acc (pool_reduce input). All n<Nn written.
#define NPW 4
__global__ __launch_bounds__(256) void tconv_fused(
    const int* __restrict__ srcs, const int* __restrict__ row_start,
    const int* __restrict__ counts,
    const unsigned short* __restrict__ qv, const unsigned short* __restrict__ kv,
    const unsigned short* __restrict__ vv, const float* __restrict__ ea_perm,
    const float* __restrict__ skipv,
    const float* __restrict__ we, const float* __restrict__ be,
    int Nn, int mode,
    unsigned short* __restrict__ hout, float* __restrict__ h_acc) {
  __shared__ float we_s[1536];
  __shared__ float be_s[256];
  for (int i = threadIdx.x; i < 1536; i += 256) we_s[i] = we[i];
  be_s[threadIdx.x] = be[threadIdx.x];
  __syncthreads();
  int wid = threadIdx.x >> 6;
  int lane = threadIdx.x & 63;
  int wave = blockIdx.x * 4 + wid;
  int n0 = wave * NPW;
  if (n0 >= Nn) return;
  int n1 = min(n0 + NPW, Nn);
  int j0 = lane * 4;
  for (int n = n0; n < n1; n++) {
    int cnt = counts[n];
    float a0 = 0.f, a1 = 0.f, a2 = 0.f, a3 = 0.f;
    float e[4] = {0.f, 0.f, 0.f, 0.f};
    if (cnt > 0) {
      int beg = row_start[n];
      // q row -> registers; z = We^T q (6) + c = q.be, butterfly-reduced
      ull uqr = *(const ull*)(qv + (size_t)n * 256 + j0);
      float q0 = bf2f((unsigned short)uqr), q1 = bf2f((unsigned short)(uqr >> 16));
      float q2 = bf2f((unsigned short)(uqr >> 32)), q3 = bf2f((unsigned short)(uqr >> 48));
      float z[7];
#pragma unroll
      for (int t = 0; t < 6; t++) {
        z[t] = we_s[(j0 + 0) * 6 + t] * q0 + we_s[(j0 + 1) * 6 + t] * q1
             + we_s[(j0 + 2) * 6 + t] * q2 + we_s[(j0 + 3) * 6 + t] * q3;
      }
      z[6] = be_s[j0] * q0 + be_s[j0 + 1] * q1 + be_s[j0 + 2] * q2 + be_s[j0 + 3] * q3;
#pragma unroll
      for (int off = 32; off > 0; off >>= 1) {
#pragma unroll
        for (int t = 0; t < 7; t++) z[t] += __shfl_xor(z[t], off, 64);
      }
      // ONLINE single pass
      float mrun = -INFINITY, ssum = 0.f;
      float ub0 = 0.f, ub1 = 0.f, ub2 = 0.f, ub3 = 0.f, ub4 = 0.f, ub5 = 0.f;
      for (int i0 = 0; i0 < cnt; i0 += 8) {
        int m8 = cnt - i0; if (m8 > 8) m8 = 8;
        int s8[8];
#pragma unroll
        for (int t = 0; t < 8; t++) {
          int pp = beg + i0 + ((t < m8) ? t : (m8 - 1));
          s8[t] = srcs[pp];
        }
        ull uk8[8], uv8[8];
#pragma unroll
        for (int t = 0; t < 8; t++)
          uk8[t] = *(const ull*)(kv + (size_t)s8[t] * 256 + j0);
#pragma unroll
        for (int t = 0; t < 8; t++)
          uv8[t] = *(const ull*)(vv + (size_t)s8[t] * 256 + j0);
        float pv[8];
#pragma unroll
        for (int t = 0; t < 8; t++) pv[t] = dot4(uqr, uk8[t]);
#pragma unroll
        for (int off = 32; off > 0; off >>= 1) {
#pragma unroll
          for (int t = 0; t < 8; t++) pv[t] += __shfl_xor(pv[t], off, 64);
        }
        // per-lane edge term (lane < m8 owns edge i0+lane)
        float zd = 0.f, uu0 = 0.f, uu1 = 0.f, uu2 = 0.f, uu3 = 0.f, uu4 = 0.f, uu5 = 0.f;
        if (lane < m8) {
          int myp = beg + i0 + lane;
          const float* u = ea_perm + (size_t)myp * 6;
          uu0 = u[0]; uu1 = u[1]; uu2 = u[2]; uu3 = u[3]; uu4 = u[4]; uu5 = u[5];
          zd = z[0] * uu0 + z[1] * uu1 + z[2] * uu2
             + z[3] * uu3 + z[4] * uu4 + z[5] * uu5 + z[6];
        }
        float l8[8];
#pragma unroll
        for (int t = 0; t < 8; t++)
          l8[t] = (t < m8) ? (pv[t] + __shfl(zd, t, 64)) : -INFINITY;
        float bmax = l8[0];
#pragma unroll
        for (int t = 1; t < 8; t++) bmax = fmaxf(bmax, l8[t]);
        float nm = fmaxf(mrun, bmax);
        float sc = __expf(mrun - nm);           // exp(-inf)=0 on first batch
        float w8[8];
#pragma unroll
        for (int t = 0; t < 8; t++) w8[t] = (t < m8) ? __expf(l8[t] - nm) : 0.f;
        ssum = ssum * sc + ((w8[0] + w8[1]) + (w8[2] + w8[3]))
                         + ((w8[4] + w8[5]) + (w8[6] + w8[7]));
        a0 *= sc; a1 *= sc; a2 *= sc; a3 *= sc;
#pragma unroll
        for (int t = 0; t < 8; t++) {
          float ww = w8[t];
          a0 += ww * bf2f((unsigned short)uv8[t]);
          a1 += ww * bf2f((unsigned short)(uv8[t] >> 16));
          a2 += ww * bf2f((unsigned short)(uv8[t] >> 32));
          a3 += ww * bf2f((unsigned short)(uv8[t] >> 48));
        }
        // ubar online: all lanes rescale; lane<m8 adds its own weight*u
        float wl = 0.f;
        if (lane < m8) wl = __expf((SEL8_F(pv, lane) + zd) - nm);
        ub0 = ub0 * sc + wl * uu0; ub1 = ub1 * sc + wl * uu1;
        ub2 = ub2 * sc + wl * uu2; ub3 = ub3 * sc + wl * uu3;
        ub4 = ub4 * sc + wl * uu4; ub5 = ub5 * sc + wl * uu5;
        mrun = nm;
      }
      float inv = 1.f / ssum;
      a0 *= inv; a1 *= inv; a2 *= inv; a3 *= inv;
      // reduce ubar partials (nonzero only in lanes 0-7) and normalize
#pragma unroll
      for (int off = 1; off < 8; off <<= 1) {
        ub0 += __shfl_xor(ub0, off, 64); ub1 += __shfl_xor(ub1, off, 64);
        ub2 += __shfl_xor(ub2, off, 64); ub3 += __shfl_xor(ub3, off, 64);
        ub4 += __shfl_xor(ub4, off, 64); ub5 += __shfl_xor(ub5, off, 64);
      }
      ub0 = __shfl(ub0, 0, 64) * inv; ub1 = __shfl(ub1, 0, 64) * inv;
      ub2 = __shfl(ub2, 0, 64) * inv; ub3 = __shfl(ub3, 0, 64) * inv;
      ub4 = __shfl(ub4, 0, 64) * inv; ub5 = __shfl(ub5, 0, 64) * inv;
#pragma unroll
      for (int r = 0; r < 4; r++) {
        int d = j0 + r;
        e[r] = be_s[d]
             + we_s[d * 6 + 0] * ub0 + we_s[d * 6 + 1] * ub1 + we_s[d * 6 + 2] * ub2
             + we_s[d * 6 + 3] * ub3 + we_s[d * 6 + 4] * ub4 + we_s[d * 6 + 5] * ub5;
      }
    }
    float4 skv = *(const float4*)(skipv + (size_t)n * 256 + j0);
    float h0 = fmaxf(a0 + e[0] + skv.x, 0.f);
    float h1 = fmaxf(a1 + e[1] + skv.y, 0.f);
    float h2 = fmaxf(a2 + e[2] + skv.z, 0.f);
    float h3 = fmaxf(a3 + e[3] + skv.w, 0.f);
    if (mode == 0) {
      ull hv = (ull)f2bf(h0) | ((ull)f2bf(h1) << 16) | ((ull)f2bf(h2) << 32) | ((ull)f2bf(h3) << 48);
      // A-frag-order address (K=256): d=lane*4 -> ks=lane>>3, quad=(lane>>1)&3,
      // kj=(lane&1)*4; layout [n32][ks][half][lane'][kj]
      int n32 = n >> 5, lmn = n & 15, halfn = (n >> 4) & 1;
      int ks = lane >> 3, quadc = (lane >> 1) & 3, kjc = (lane & 1) * 4;
      size_t a = (((size_t)(n32 * 8 + ks)) * 2 + halfn) * 512 + (quadc * 16 + lmn) * 8 + kjc;
      *(ull*)(hout + a) = hv;
    } else {
      float4 o; o.x = h0; o.y = h1; o.z = h2; o.w = h3;
      *(float4*)(h_acc + (size_t)n * 256 + j0) = o;
    }
  }
}

// ---- P5: segmented pooling over sorted batch (contiguous node ranges) -----
__global__ __launch_bounds__(256) void pool_reduce(
    const float* __restrict__ hfin, const int* __restrict__ batch, int Nn,
    float* __restrict__ gap, unsigned int* __restrict__ gmp) {
  int g = blockIdx.x, s = blockIdx.y, t = threadIdx.x;
  __shared__ int st_s, en_s;
  if (t == 0) {
    int lo = 0, hi = Nn;
    while (lo < hi) { int mid = (lo + hi) >> 1; if (batch[mid] < g) lo = mid + 1; else hi = mid; }
    st_s = lo;
    lo = 0; hi = Nn;
    while (lo < hi) { int mid = (lo + hi) >> 1; if (batch[mid] < g + 1) lo = mid + 1; else hi = mid; }
    en_s = lo;
  }
  __syncthreads();
  int st = st_s, en = en_s;
  int len = en - st;
  if (len <= 0) return;
  int nsplit = gridDim.y;
  int chunk = (len + nsplit - 1) / nsplit;
  int a = st + s * chunk;
  int b = min(a + chunk, en);
  if (a >= b) return;
  float acc = 0.f, mx = 0.f;  // h >= 0 (relu)
  for (int n = a; n < b; n++) {
    float v = hfin[(size_t)n * 256 + t];
    acc += v;
    mx = fmaxf(mx, v);
  }
  atomicAdd(&gap[(size_t)g * 256 + t], acc);
  atomicMax(&gmp[(size_t)g * 256 + t], __float_as_uint(mx));
}

// ---- per-graph pooling finalize + 3-layer MLP + sigmoid -------------------
__global__ __launch_bounds__(256) void pool_mlp(
    const float* __restrict__ gap, const unsigned int* __restrict__ gmp,
    const int* __restrict__ batch, int Nn,
    const float* __restrict__ w1, const float* __restrict__ b1,
    const float* __restrict__ w2, const float* __restrict__ b2,
    const float* __restrict__ w3, const float* __restrict__ b3,
    float* __restrict__ out) {
  int g = blockIdx.x, t = threadIdx.x;
  __shared__ float r[512];
  __shared__ float o1[256];
  __shared__ float o2[128];
  __shared__ float red[256];
  __shared__ int cnt_s;
  if (t == 0) {
    int lo = 0, hi = Nn;
    while (lo < hi) { int mid = (lo + hi) >> 1; if (batch[mid] < g) lo = mid + 1; else hi = mid; }
    int st = lo;
    lo = 0; hi = Nn;
    while (lo < hi) { int mid = (lo + hi) >> 1; if (batch[mid] < g + 1) lo = mid + 1; else hi = mid; }
    cnt_s = lo - st;
  }
  __syncthreads();
  float inv = 1.f / fmaxf((float)cnt_s, 1.f);
  r[t] = gap[(size_t)g * 256 + t] * inv;
  r[256 + t] = __uint_as_float(gmp[(size_t)g * 256 + t]);
  __syncthreads();
  {
    float a = b1[t];
    const float* wr = w1 + (size_t)t * 512;
    for (int k = 0; k < 512; k++) a += wr[k] * r[k];
    o1[t] = fmaxf(a, 0.f);
  }
  __syncthreads();
  if (t < 128) {
    float a = b2[t];
    const float* wr = w2 + (size_t)t * 256;
    for (int k = 0; k < 256; k++) a += wr[k] * o1[k];
    o2[t] = fmaxf(a, 0.f);
  }
  __syncthreads();
  red[t] = (t < 128) ? w3[t] * o2[t] : 0.f;
  __syncthreads();
  for (int s = 128; s > 0; s >>= 1) {
    if (t < s) red[t] += red[t + s];
    __syncthreads();
  }
  if (t == 0) out[g] = 1.f / (1.f + expf(-(red[0] + b3[0])));
}

// ---------------------------------------------------------------------------
extern "C" void kernel_launch(void* const* d_in, const int* in_sizes, int n_in,
                              void* d_out, int out_size, void* d_ws, size_t ws_size,
                              hipStream_t stream) {
  const int* x_idx      = (const int*)d_in[0];
  const int* edge_index = (const int*)d_in[1];
  const float* eattr    = (const float*)d_in[2];
  const int* batch      = (const int*)d_in[3];
  const float* emb      = (const float*)d_in[4];
  const float* c1_wq = (const float*)d_in[5],  *c1_bq = (const float*)d_in[6];
  const float* c1_wk = (const float*)d_in[7],  *c1_bk = (const float*)d_in[8];
  const float* c1_wv = (const float*)d_in[9],  *c1_bv = (const float*)d_in[10];
  const float* c1_we = (const float*)d_in[11], *c1_be = (const float*)d_in[12];
  const float* c1_ws = (const float*)d_in[13], *c1_bs = (const float*)d_in[14];
  const float* c2_wq = (const float*)d_in[15], *c2_bq = (const float*)d_in[16];
  const float* c2_wk = (const float*)d_in[17], *c2_bk = (const float*)d_in[18];
  const float* c2_wv = (const float*)d_in[19], *c2_bv = (const float*)d_in[20];
  const float* c2_we = (const float*)d_in[21], *c2_be = (const float*)d_in[22];
  const float* c2_ws = (const float*)d_in[23], *c2_bs = (const float*)d_in[24];
  const float* w1 = (const float*)d_in[25], *b1 = (const float*)d_in[26];
  const float* w2 = (const float*)d_in[27], *b2 = (const float*)d_in[28];
  const float* w3 = (const float*)d_in[29], *b3 = (const float*)d_in[30];

  const int Nn = in_sizes[3];        // 50000
  const int Ee = in_sizes[1] / 2;    // 300000
  const int nrb = (Nn + 127) / 128;  // 391 row-blocks (gemm grid + padding)

  char* ws = (char*)d_ws;
  size_t off = 0;
  auto alloc = [&](size_t bytes) -> void* {
    void* p = ws + off;
    off += (bytes + 255) & ~(size_t)255;
    return p;
  };
  // xbf/h1bf padded to whole 128-row blocks (frag-order reads go to nrb*128)
  unsigned short* xbf   = (unsigned short*)alloc((size_t)nrb * 128 * 512 * 2);
  unsigned short* qbf   = (unsigned short*)alloc((size_t)Nn * 256 * 2);
  unsigned short* kbf   = (unsigned short*)alloc((size_t)Nn * 256 * 2);
  unsigned short* vbf   = (unsigned short*)alloc((size_t)Nn * 256 * 2);
  float*          skipf = (float*)alloc((size_t)Nn * 256 * 4);
  unsigned short* h1bf  = (unsigned short*)alloc((size_t)nrb * 128 * 256 * 2);
  unsigned short* Wcat1 = (unsigned short*)alloc((size_t)1024 * 512 * 2);
  float*          bcat1 = (float*)alloc(1024 * 4);
  unsigned short* Wcat2 = (unsigned short*)alloc((size_t)1024 * 256 * 2);
  float*          bcat2 = (float*)alloc(1024 * 4);
  int*            counts    = (int*)alloc((size_t)Nn * 4);
  int*            row_start = (int*)alloc((size_t)Nn * 4);
  int*            cursor    = (int*)alloc((size_t)Nn * 4);
  int*            srcs      = (int*)alloc((size_t)Ee * 4);
  float*          ea_perm   = (float*)alloc((size_t)Ee * 6 * 4);
  int*            total     = (int*)alloc(256);
  float*          gap       = (float*)alloc((size_t)64 * 256 * 4);
  unsigned int*   gmp       = (unsigned int*)alloc((size_t)64 * 256 * 4);
  // h_acc (50k x 256 fp32 = 51.2 MB) ALIASES xbf (51.25 MB padded): xbf is
  // dead after gemm1; h_acc first touched by tconv_fused mode 1.
  float* h_acc = (float*)xbf;

  const int* srcA = edge_index;
  const int* dstA = edge_index + Ee;

  hipMemsetAsync(counts, 0, (size_t)Nn * 4, stream);
  hipMemsetAsync(total, 0, 4, stream);
  hipMemsetAsync(gap, 0, (size_t)64 * 256 * 4, stream);
  hipMemsetAsync(gmp, 0, (size_t)64 * 256 * 4, stream);

  pack_weights<<<(1024 * 512 + 255) / 256, 256, 0, stream>>>(
      c1_wq, c1_wk, c1_wv, c1_ws, c1_bq, c1_bk, c1_bv, c1_bs, Wcat1, bcat1, 9);
  pack_weights<<<(1024 * 256 + 255) / 256, 256, 0, stream>>>(
      c2_wq, c2_wk, c2_wv, c2_ws, c2_bq, c2_bk, c2_bv, c2_bs, Wcat2, bcat2, 8);
  embed_gather<<<((Nn * 512) + 255) / 256, 256, 0, stream>>>(x_idx, emb, xbf, Nn * 512);
  count_dst<<<(Ee + 255) / 256, 256, 0, stream>>>(dstA, counts, Ee);
  alloc_rows<<<(Nn + 255) / 256, 256, 0, stream>>>(counts, row_start, cursor, total, Nn);
  scatter_edges<<<(Ee + 255) / 256, 256, 0, stream>>>(dstA, srcA, eattr, cursor,
                                                      srcs, ea_perm, Ee);

  // XCD-aware gemm grid: 8 XCD groups x max-row-blocks-per-XCD x 16 col-tiles
  const int rbmax = nrb / 8 + ((nrb % 8) ? 1 : 0);
  const int ggrid = 8 * rbmax * 16;
  const int sgrid = (Nn + NPW * 4 - 1) / (NPW * 4);  // node-owned fused waves

  // layer 1
  gemm_qkvs<512><<<ggrid, 256, 0, stream>>>(xbf, Wcat1, bcat1, qbf, kbf, vbf,
                                            skipf, Nn, nrb);
  tconv_fused<<<sgrid, 256, 0, stream>>>(srcs, row_start, counts, qbf, kbf, vbf,
                                         ea_perm, skipf, c1_we, c1_be, Nn, 0,
                                         h1bf, nullptr);

  // layer 2
  gemm_qkvs<256><<<ggrid, 256, 0, stream>>>(h1bf, Wcat2, bcat2, qbf, kbf, vbf,
                                            skipf, Nn, nrb);
  tconv_fused<<<sgrid, 256, 0, stream>>>(srcs, row_start, counts, qbf, kbf, vbf,
                                         ea_perm, skipf, c2_we, c2_be, Nn, 1,
                                         nullptr, h_acc);

  // segmented pooling (batch sorted -> contiguous ranges), then MLP
  dim3 pg(64, 16);
  pool_reduce<<<pg, 256, 0, stream>>>(h_acc, batch, Nn, gap, gmp);
  pool_mlp<<<64, 256, 0, stream>>>(gap, gmp, batch, Nn, w1, b1, w2, b2, w3, b3,
                                   (float*)d_out);
}